// Round 3
// baseline (21434.581 us; speedup 1.0000x reference)
//
#include <hip/hip_runtime.h>
#include <hip/hip_bf16.h>
#include <cmath>

typedef __hip_bfloat16 bf16;

__device__ __forceinline__ float b2f(bf16 v) { return __bfloat162float(v); }
__device__ __forceinline__ bf16  f2b(float v) { return __float2bfloat16(v); }
__device__ __forceinline__ float bfr(unsigned int u) { union { float f; unsigned int i; } c; c.i = u << 16; return c.f; }
// 4-element loads into float regs
__device__ __forceinline__ void ld4(const float* p, float* o) {
    float4 q = *(const float4*)p; o[0]=q.x; o[1]=q.y; o[2]=q.z; o[3]=q.w;
}
__device__ __forceinline__ void ld4(const bf16* p, float* o) {
    const uint2 q = *(const uint2*)p;
    o[0] = bfr(q.x & 0xffffu); o[1] = bfr(q.x >> 16);
    o[2] = bfr(q.y & 0xffffu); o[3] = bfr(q.y >> 16);
}
__device__ __forceinline__ float ldv(const float* p) { return *p; }
__device__ __forceinline__ float ldv(const bf16* p)  { return b2f(*p); }
__device__ __forceinline__ void  stv(float* p, float v) { *p = v; }
__device__ __forceinline__ void  stv(bf16* p, float v)  { *p = f2b(v); }

__device__ __forceinline__ float siluf(float x) { return x / (1.f + expf(-x)); }
__device__ __forceinline__ float geluf(float x) { return 0.5f * x * (1.f + erff(x * 0.70710678118654752f)); }

// LN of 64 rows (pitch 193) held in LDS; 4 threads/row; params fp32.
__device__ __forceinline__ void ln_rows193(float (*L)[193], const float* g, const float* b, int tid) {
    const int i = tid >> 2, jg = tid & 3;
    float s = 0.f, sq = 0.f;
    #pragma unroll
    for (int k2 = 0; k2 < 48; ++k2) { float v = L[i][jg * 48 + k2]; s += v; sq += v * v; }
    s  += __shfl_xor(s, 1);  s  += __shfl_xor(s, 2);
    sq += __shfl_xor(sq, 1); sq += __shfl_xor(sq, 2);
    const float m  = s * (1.f / 192.f);
    const float var = sq * (1.f / 192.f) - m * m;
    const float rs = rsqrtf(var + 1e-5f);
    #pragma unroll
    for (int k2 = 0; k2 < 48; ++k2) {
        int d = jg * 48 + k2;
        L[i][d] = (L[i][d] - m) * rs * g[d] + b[d];
    }
}

// ---------------- conv3x3 (+optional concat input of type T2) + BN + SiLU ----------------
// grid (4, Cout, B), block 256: 64 cols x 4 rowgroups x 4 rows/thread
template <typename T2>
__global__ __launch_bounds__(256) void k_conv3x3(
    const float* __restrict__ in1, int C1,
    const T2* __restrict__ in2, int C2,
    const float* __restrict__ w,
    const float* __restrict__ gamma, const float* __restrict__ beta,
    float* __restrict__ out, int Cout)
{
    __shared__ float wl[2304];
    const int tid = threadIdx.x;
    const int col = tid & 63;
    const int r0  = blockIdx.x * 16 + (tid >> 6) * 4;
    const int oc  = blockIdx.y;
    const int b   = blockIdx.z;
    const int Cin = C1 + C2;
    for (int i = tid; i < Cin * 9; i += 256) wl[i] = w[(size_t)oc * Cin * 9 + i];
    __syncthreads();
    float a0 = 0.f, a1 = 0.f, a2 = 0.f, a3 = 0.f;
    // source 0: fp32 input
    {
        const float* bb = in1 + (size_t)b * C1 * 4096;
        for (int ic = 0; ic < C1; ++ic) {
            const float* p  = bb + ic * 4096;
            const float* wr = &wl[ic * 9];
            #pragma unroll
            for (int iy = 0; iy < 6; ++iy) {
                int ry = r0 - 1 + iy;
                float v0 = 0.f, v1 = 0.f, v2 = 0.f;
                if (ry >= 0 && ry < 64) {
                    const float* rp = p + ry * 64 + col;
                    v1 = rp[0];
                    v0 = (col > 0)  ? rp[-1] : 0.f;
                    v2 = (col < 63) ? rp[1]  : 0.f;
                }
                #pragma unroll
                for (int ky = 0; ky < 3; ++ky) {
                    int o = iy - ky;
                    if (o >= 0 && o < 4) {
                        float s = v0 * wr[ky*3] + v1 * wr[ky*3+1] + v2 * wr[ky*3+2];
                        if      (o == 0) a0 += s;
                        else if (o == 1) a1 += s;
                        else if (o == 2) a2 += s;
                        else             a3 += s;
                    }
                }
            }
        }
    }
    // source 1: T2 input (concat)
    if (C2 > 0) {
        const T2* bb = in2 + (size_t)b * C2 * 4096;
        for (int ic = 0; ic < C2; ++ic) {
            const T2* p  = bb + ic * 4096;
            const float* wr = &wl[C1 * 9 + ic * 9];
            #pragma unroll
            for (int iy = 0; iy < 6; ++iy) {
                int ry = r0 - 1 + iy;
                float v0 = 0.f, v1 = 0.f, v2 = 0.f;
                if (ry >= 0 && ry < 64) {
                    const T2* rp = p + ry * 64 + col;
                    v1 = ldv(rp);
                    v0 = (col > 0)  ? ldv(rp - 1) : 0.f;
                    v2 = (col < 63) ? ldv(rp + 1) : 0.f;
                }
                #pragma unroll
                for (int ky = 0; ky < 3; ++ky) {
                    int o = iy - ky;
                    if (o >= 0 && o < 4) {
                        float s = v0 * wr[ky*3] + v1 * wr[ky*3+1] + v2 * wr[ky*3+2];
                        if      (o == 0) a0 += s;
                        else if (o == 1) a1 += s;
                        else if (o == 2) a2 += s;
                        else             a3 += s;
                    }
                }
            }
        }
    }
    const float g = gamma[oc], be = beta[oc];
    float accs[4] = {a0, a1, a2, a3};
    #pragma unroll
    for (int o = 0; o < 4; ++o) {
        float v = g * accs[o] + be;
        out[(((size_t)b * Cout + oc) * 64 + (r0 + o)) * 64 + col] = siluf(v);
    }
}

// ---------------- patchify + 1x1 (128 -> 192), tok bf16 ----------------
// grid (64 patches, 32 b), block 256
__global__ __launch_bounds__(256) void k_patch1x1(
    const float* __restrict__ h1, const float* __restrict__ w, bf16* __restrict__ tok)
{
    const int np = blockIdx.x, b = blockIdx.y;
    const int pi = np >> 3, pj = np & 7;
    __shared__ float hp[128][65];
    __shared__ float outL[64][193];
    for (int idx = threadIdx.x; idx < 128 * 64; idx += 256) {
        int c = idx >> 6, pa = idx & 63;
        int y = pi * 8 + (pa >> 3), x = pj * 8 + (pa & 7);
        hp[c][pa] = h1[(((size_t)b * 128 + c) * 64 + y) * 64 + x];
    }
    __syncthreads();
    const int pa = threadIdx.x & 63;
    const int wv = threadIdx.x >> 6;
    for (int dd = 0; dd < 48; ++dd) {
        int d = wv * 48 + dd;
        float acc = 0.f;
        for (int c4 = 0; c4 < 32; ++c4) {
            float wq[4]; ld4(w + (size_t)d * 128 + c4 * 4, wq);
            acc += hp[c4*4+0][pa] * wq[0] + hp[c4*4+1][pa] * wq[1]
                 + hp[c4*4+2][pa] * wq[2] + hp[c4*4+3][pa] * wq[3];
        }
        outL[pa][d] = acc;
    }
    __syncthreads();
    for (int idx = threadIdx.x; idx < 64 * 192; idx += 256) {
        int pa2 = idx / 192, d2 = idx % 192;
        tok[((size_t)(b * 64 + pa2) * 64 + np) * 192 + d2] = f2b(outL[pa2][d2]);
    }
}

// ---------------- gating ----------------
// grid 512, block 256 (one thread per token)
__global__ __launch_bounds__(256) void k_gate(
    const bf16* __restrict__ tok, const float* __restrict__ gate_w_all,
    const int* __restrict__ task, float* __restrict__ dense,
    float* __restrict__ part)
{
    __shared__ float gwL[768];
    for (int i = threadIdx.x; i < 768; i += 256) gwL[i] = gate_w_all[(size_t)task[0] * 768 + i];
    __syncthreads();
    const int r = blockIdx.x * 256 + threadIdx.x;
    const bf16* tb = tok + (size_t)r * 192;
    float L0 = 0.f, L1 = 0.f, L2 = 0.f, L3 = 0.f;
    for (int c4 = 0; c4 < 48; ++c4) {
        float xv[4]; ld4(tb + c4 * 4, xv);
        #pragma unroll
        for (int j = 0; j < 4; ++j) {
            int c = c4 * 4 + j;
            L0 += xv[j] * gwL[c*4+0]; L1 += xv[j] * gwL[c*4+1];
            L2 += xv[j] * gwL[c*4+2]; L3 += xv[j] * gwL[c*4+3];
        }
    }
    float m = fmaxf(fmaxf(L0, L1), fmaxf(L2, L3));
    float e0 = expf(L0 - m), e1 = expf(L1 - m), e2 = expf(L2 - m), e3 = expf(L3 - m);
    float s = e0 + e1 + e2 + e3;
    float p[4] = {e0 / s, e1 / s, e2 / s, e3 / s};
    int i1 = 0; float v1 = p[0];
    #pragma unroll
    for (int e = 1; e < 4; ++e) if (p[e] > v1) { v1 = p[e]; i1 = e; }
    int i2 = -1; float v2 = -1.f;
    #pragma unroll
    for (int e = 0; e < 4; ++e) if (e != i1 && p[e] > v2) { v2 = p[e]; i2 = e; }
    float gs = v1 + v2;
    float d[4] = {0.f, 0.f, 0.f, 0.f};
    d[i1] = v1 / gs; d[i2] = v2 / gs;
    ((float4*)dense)[r] = make_float4(d[0], d[1], d[2], d[3]);

    float vals[8] = {p[0], p[1], p[2], p[3],
                     d[0] > 0.f ? 1.f : 0.f, d[1] > 0.f ? 1.f : 0.f,
                     d[2] > 0.f ? 1.f : 0.f, d[3] > 0.f ? 1.f : 0.f};
    #pragma unroll
    for (int off = 32; off; off >>= 1)
        #pragma unroll
        for (int i = 0; i < 8; ++i) vals[i] += __shfl_down(vals[i], off);
    __shared__ float sm[4][8];
    const int lane = threadIdx.x & 63, wv = threadIdx.x >> 6;
    if (lane == 0)
        #pragma unroll
        for (int i = 0; i < 8; ++i) sm[wv][i] = vals[i];
    __syncthreads();
    if (threadIdx.x < 8)
        part[blockIdx.x * 8 + threadIdx.x] =
            sm[0][threadIdx.x] + sm[1][threadIdx.x] + sm[2][threadIdx.x] + sm[3][threadIdx.x];
}

// ---------------- MoE ----------------
// grid 2048 (64-token tiles), block 256
template <typename TT>
__global__ __launch_bounds__(256) void k_moe(
    const bf16* __restrict__ tok, const float* __restrict__ dense,
    const float* __restrict__ w1, const float* __restrict__ b1,
    const float* __restrict__ w2, const float* __restrict__ b2,
    TT* __restrict__ tout)
{
    __shared__ float tokL[64][193];
    __shared__ float heL[64][193];
    __shared__ float dL[64][4];
    const int rbase = blockIdx.x * 64;
    for (int idx = threadIdx.x * 4; idx < 64 * 192; idx += 1024) {
        float tmp[4]; ld4(tok + (size_t)rbase * 192 + idx, tmp);
        int r = idx / 192, d = idx % 192;
        tokL[r][d] = tmp[0]; tokL[r][d+1] = tmp[1]; tokL[r][d+2] = tmp[2]; tokL[r][d+3] = tmp[3];
    }
    {
        int r = threadIdx.x >> 2, e = threadIdx.x & 3;
        dL[r][e] = dense[(size_t)(rbase + r) * 4 + e];
    }
    __syncthreads();
    const int lane = threadIdx.x & 63, wv = threadIdx.x >> 6;
    const int c0 = wv * 48;
    float acc[48];
    #pragma unroll
    for (int i = 0; i < 48; ++i) acc[i] = 0.f;
    for (int e = 0; e < 4; ++e) {
        const float* W1 = w1 + (size_t)e * 36864;
        const float* B1 = b1 + e * 192;
        float h[48];
        #pragma unroll
        for (int i = 0; i < 48; ++i) h[i] = B1[c0 + i];
        for (int k = 0; k < 192; ++k) {
            float x = tokL[lane][k];
            const float* Wr = W1 + (size_t)k * 192 + c0;
            #pragma unroll
            for (int q = 0; q < 12; ++q) {
                float wq[4]; ld4(Wr + q * 4, wq);
                h[q*4+0] += x * wq[0]; h[q*4+1] += x * wq[1];
                h[q*4+2] += x * wq[2]; h[q*4+3] += x * wq[3];
            }
        }
        #pragma unroll
        for (int i = 0; i < 48; ++i) heL[lane][c0 + i] = geluf(h[i]);
        __syncthreads();
        const float gate = dL[lane][e];
        const float* W2 = w2 + (size_t)e * 36864;
        const float* B2 = b2 + e * 192;
        #pragma unroll
        for (int i = 0; i < 48; ++i) acc[i] += gate * B2[c0 + i];
        for (int k = 0; k < 192; ++k) {
            float x = gate * heL[lane][k];
            const float* Wr = W2 + (size_t)k * 192 + c0;
            #pragma unroll
            for (int q = 0; q < 12; ++q) {
                float wq[4]; ld4(Wr + q * 4, wq);
                acc[q*4+0] += x * wq[0]; acc[q*4+1] += x * wq[1];
                acc[q*4+2] += x * wq[2]; acc[q*4+3] += x * wq[3];
            }
        }
        __syncthreads();
    }
    #pragma unroll
    for (int i = 0; i < 48; ++i) heL[lane][c0 + i] = acc[i];
    __syncthreads();
    for (int idx = threadIdx.x; idx < 64 * 192; idx += 256) {
        int r = idx / 192, d = idx % 192;
        stv(&tout[(size_t)(rbase + r) * 192 + d], heL[r][d]);
    }
}

// ---------------- fused LN1 + attention per (seq, head) ----------------
// grid (2048, 4), block 256
template <typename TT>
__global__ __launch_bounds__(256) void k_attn(
    const TT* __restrict__ t, const float* __restrict__ lg, const float* __restrict__ lb,
    const float* __restrict__ qkvw, const float* __restrict__ qkvb, bf16* __restrict__ y2)
{
    const int n = blockIdx.x, h = blockIdx.y;
    __shared__ float yL[64][193];
    __shared__ float qL[64][49], kL[64][49], vL[64][49];
    __shared__ float pL[64][65];
    for (int idx = threadIdx.x * 4; idx < 64 * 192; idx += 1024) {
        float tmp[4]; ld4(t + (size_t)n * 12288 + idx, tmp);
        int r = idx / 192, d = idx % 192;
        yL[r][d] = tmp[0]; yL[r][d+1] = tmp[1]; yL[r][d+2] = tmp[2]; yL[r][d+3] = tmp[3];
    }
    __syncthreads();
    ln_rows193(yL, lg, lb, threadIdx.x);
    __syncthreads();
    const int lane = threadIdx.x & 63, wv = threadIdx.x >> 6;
    const float scale = rsqrtf(48.f);
    {
        int cols[9], whichs[9], dqs[9];
        #pragma unroll
        for (int q = 0; q < 9; ++q) {
            int qq = wv * 9 + q;
            whichs[q] = qq / 12; dqs[q] = (qq % 12) * 4;
            cols[q] = whichs[q] * 192 + h * 48 + dqs[q];
        }
        float a[36];
        #pragma unroll
        for (int q = 0; q < 9; ++q) {
            float bq[4]; ld4(qkvb + cols[q], bq);
            a[q*4+0] = bq[0]; a[q*4+1] = bq[1]; a[q*4+2] = bq[2]; a[q*4+3] = bq[3];
        }
        for (int k = 0; k < 192; ++k) {
            float x = yL[lane][k];
            const float* wr = qkvw + (size_t)k * 576;
            #pragma unroll
            for (int q = 0; q < 9; ++q) {
                float wq[4]; ld4(wr + cols[q], wq);
                a[q*4+0] += x * wq[0]; a[q*4+1] += x * wq[1];
                a[q*4+2] += x * wq[2]; a[q*4+3] += x * wq[3];
            }
        }
        #pragma unroll
        for (int q = 0; q < 9; ++q) {
            int wch = whichs[q], dq = dqs[q];
            if (wch == 0) {
                #pragma unroll
                for (int u = 0; u < 4; ++u) qL[lane][dq + u] = a[q*4+u] * scale;
            } else if (wch == 1) {
                #pragma unroll
                for (int u = 0; u < 4; ++u) kL[lane][dq + u] = a[q*4+u];
            } else {
                #pragma unroll
                for (int u = 0; u < 4; ++u) vL[lane][dq + u] = a[q*4+u];
            }
        }
    }
    __syncthreads();
    {
        const int i = threadIdx.x >> 2, jg = threadIdx.x & 3;
        float sc[16];
        #pragma unroll
        for (int jj = 0; jj < 16; ++jj) {
            int j = jg * 16 + jj;
            float sv = 0.f;
            #pragma unroll 12
            for (int d = 0; d < 48; ++d) sv += qL[i][d] * kL[j][d];
            sc[jj] = sv;
        }
        float m = sc[0];
        #pragma unroll
        for (int jj = 1; jj < 16; ++jj) m = fmaxf(m, sc[jj]);
        m = fmaxf(m, __shfl_xor(m, 1)); m = fmaxf(m, __shfl_xor(m, 2));
        float ssum = 0.f;
        #pragma unroll
        for (int jj = 0; jj < 16; ++jj) { sc[jj] = expf(sc[jj] - m); ssum += sc[jj]; }
        ssum += __shfl_xor(ssum, 1); ssum += __shfl_xor(ssum, 2);
        float inv = 1.f / ssum;
        #pragma unroll
        for (int jj = 0; jj < 16; ++jj) pL[i][jg * 16 + jj] = sc[jj] * inv;
    }
    __syncthreads();
    {
        float oacc[12];
        #pragma unroll
        for (int u = 0; u < 12; ++u) oacc[u] = 0.f;
        for (int j = 0; j < 64; ++j) {
            float pv = pL[lane][j];
            #pragma unroll
            for (int u = 0; u < 12; ++u) oacc[u] += pv * vL[j][wv * 12 + u];
        }
        #pragma unroll
        for (int u = 0; u < 12; ++u) kL[lane][wv * 12 + u] = oacc[u];
    }
    __syncthreads();
    for (int idx = threadIdx.x; idx < 64 * 48; idx += 256) {
        int s = idx / 48, d = idx % 48;
        y2[((size_t)n * 64 + s) * 192 + h * 48 + d] = f2b(kL[s][d]);
    }
}

// ---------------- t += y2 @ proj_w + proj_b ----------------
template <typename TT>
__global__ __launch_bounds__(256) void k_proj(
    const bf16* __restrict__ a, const float* __restrict__ pw,
    const float* __restrict__ pb, TT* __restrict__ t)
{
    __shared__ float aL[64][193];
    __shared__ float oL[64][193];
    const int rbase = blockIdx.x * 64;
    for (int idx = threadIdx.x * 4; idx < 64 * 192; idx += 1024) {
        float tmp[4]; ld4(a + (size_t)rbase * 192 + idx, tmp);
        int r = idx / 192, d = idx % 192;
        aL[r][d] = tmp[0]; aL[r][d+1] = tmp[1]; aL[r][d+2] = tmp[2]; aL[r][d+3] = tmp[3];
    }
    __syncthreads();
    const int lane = threadIdx.x & 63, wv = threadIdx.x >> 6;
    const int c0 = wv * 48;
    float acc[48];
    #pragma unroll
    for (int i = 0; i < 48; ++i) acc[i] = pb[c0 + i];
    for (int k = 0; k < 192; ++k) {
        float x = aL[lane][k];
        const float* Wr = pw + (size_t)k * 192 + c0;
        #pragma unroll
        for (int q = 0; q < 12; ++q) {
            float wq[4]; ld4(Wr + q * 4, wq);
            acc[q*4+0] += x * wq[0]; acc[q*4+1] += x * wq[1];
            acc[q*4+2] += x * wq[2]; acc[q*4+3] += x * wq[3];
        }
    }
    #pragma unroll
    for (int i = 0; i < 48; ++i) oL[lane][c0 + i] = acc[i];
    __syncthreads();
    for (int idx = threadIdx.x; idx < 64 * 192; idx += 256) {
        int r = idx / 192, d = idx % 192;
        TT* p = &t[(size_t)(rbase + r) * 192 + d];
        stv(p, ldv(p) + oL[r][d]);
    }
}

// ---------------- fused LN2 + MLP: t += gelu(ln(t)@fc1+b1)@fc2+b2 ----------------
template <typename TT>
__global__ __launch_bounds__(256) void k_mlp(
    TT* __restrict__ t, const float* __restrict__ lg, const float* __restrict__ lb,
    const float* __restrict__ w1, const float* __restrict__ b1,
    const float* __restrict__ w2, const float* __restrict__ b2)
{
    __shared__ float yL[64][193];
    __shared__ float hL[64][193];
    const int rbase = blockIdx.x * 64;
    for (int idx = threadIdx.x * 4; idx < 64 * 192; idx += 1024) {
        float tmp[4]; ld4((const TT*)t + (size_t)rbase * 192 + idx, tmp);
        int r = idx / 192, d = idx % 192;
        yL[r][d] = tmp[0]; yL[r][d+1] = tmp[1]; yL[r][d+2] = tmp[2]; yL[r][d+3] = tmp[3];
    }
    __syncthreads();
    ln_rows193(yL, lg, lb, threadIdx.x);
    __syncthreads();
    const int lane = threadIdx.x & 63, wv = threadIdx.x >> 6;
    const int c0 = wv * 48;
    float acc[48];
    #pragma unroll
    for (int i = 0; i < 48; ++i) acc[i] = 0.f;
    for (int ch = 0; ch < 2; ++ch) {
        float h[48];
        #pragma unroll
        for (int i = 0; i < 48; ++i) h[i] = b1[ch * 192 + c0 + i];
        for (int k = 0; k < 192; ++k) {
            float x = yL[lane][k];
            const float* Wr = w1 + (size_t)k * 384 + ch * 192 + c0;
            #pragma unroll
            for (int q = 0; q < 12; ++q) {
                float wq[4]; ld4(Wr + q * 4, wq);
                h[q*4+0] += x * wq[0]; h[q*4+1] += x * wq[1];
                h[q*4+2] += x * wq[2]; h[q*4+3] += x * wq[3];
            }
        }
        #pragma unroll
        for (int i = 0; i < 48; ++i) hL[lane][c0 + i] = geluf(h[i]);
        __syncthreads();
        for (int k = 0; k < 192; ++k) {
            float x = hL[lane][k];
            const float* Wr = w2 + (size_t)(ch * 192 + k) * 192 + c0;
            #pragma unroll
            for (int q = 0; q < 12; ++q) {
                float wq[4]; ld4(Wr + q * 4, wq);
                acc[q*4+0] += x * wq[0]; acc[q*4+1] += x * wq[1];
                acc[q*4+2] += x * wq[2]; acc[q*4+3] += x * wq[3];
            }
        }
        __syncthreads();
    }
    #pragma unroll
    for (int i = 0; i < 48; ++i) hL[lane][c0 + i] = acc[i] + b2[c0 + i];
    __syncthreads();
    for (int idx = threadIdx.x; idx < 64 * 192; idx += 256) {
        int r = idx / 192, d = idx % 192;
        TT* p = &t[(size_t)(rbase + r) * 192 + d];
        stv(p, ldv(p) + hL[r][d]);
    }
}

// ---------------- fused final LN + unpatchify + 1x1 (192->128) + BN + SiLU ----------------
// grid (64, 32), block 256; p bf16
template <typename TT>
__global__ __launch_bounds__(256) void k_unpatch(
    const TT* __restrict__ t, const float* __restrict__ ng, const float* __restrict__ nb,
    const float* __restrict__ wp, const float* __restrict__ gamma, const float* __restrict__ beta,
    bf16* __restrict__ p)
{
    const int np = blockIdx.x, b = blockIdx.y;
    const int pi = np >> 3, pj = np & 7;
    __shared__ float tL[64][193];
    __shared__ float oL[64][129];
    for (int idx = threadIdx.x * 4; idx < 64 * 192; idx += 1024) {
        int pa = idx / 192, d = idx % 192;
        float tmp[4]; ld4(t + ((size_t)(b * 64 + pa) * 64 + np) * 192 + d, tmp);
        tL[pa][d] = tmp[0]; tL[pa][d+1] = tmp[1]; tL[pa][d+2] = tmp[2]; tL[pa][d+3] = tmp[3];
    }
    __syncthreads();
    ln_rows193(tL, ng, nb, threadIdx.x);
    __syncthreads();
    const int lane = threadIdx.x & 63, wv = threadIdx.x >> 6;
    for (int k = 0; k < 32; ++k) {
        int o = wv * 32 + k;
        float acc = 0.f;
        for (int d4 = 0; d4 < 48; ++d4) {
            float wq[4]; ld4(wp + (size_t)o * 192 + d4 * 4, wq);
            acc += tL[lane][d4*4+0] * wq[0] + tL[lane][d4*4+1] * wq[1]
                 + tL[lane][d4*4+2] * wq[2] + tL[lane][d4*4+3] * wq[3];
        }
        float v = gamma[o] * acc + beta[o];
        oL[lane][o] = siluf(v);
    }
    __syncthreads();
    for (int idx = threadIdx.x; idx < 64 * 128; idx += 256) {
        int o = idx >> 6, pa = idx & 63;
        p[(((size_t)b * 128 + o) * 64 + (pi * 8 + (pa >> 3))) * 64 + pj * 8 + (pa & 7)] = f2b(oL[pa][o]);
    }
}

// ---------------- moe loss ----------------
__global__ void k_loss(const float* __restrict__ part, float* __restrict__ out)
{
    if (threadIdx.x == 0 && blockIdx.x == 0) {
        float L = 0.f;
        for (int e = 0; e < 4; ++e) {
            float imp = 0.f, ld = 0.f;
            for (int i = 0; i < 512; ++i) { imp += part[i * 8 + e]; ld += part[i * 8 + 4 + e]; }
            L += (imp / 131072.f) * (ld / 131072.f);
        }
        out[16777216] = 4.f * L;
    }
}

template <typename TT>
static void run_pipeline(const float* x, const float* w_kxk, const float* bn1_g, const float* bn1_b,
                         const float* w_1x1, const float* gate_w,
                         const float* moe_w1, const float* moe_b1, const float* moe_w2, const float* moe_b2,
                         const float* ln1_g, const float* ln1_b, const float* qkv_w, const float* qkv_b,
                         const float* proj_w, const float* proj_b, const float* ln2_g, const float* ln2_b,
                         const float* fc1_w, const float* fc1_b, const float* fc2_w, const float* fc2_b,
                         const float* nrm_g, const float* nrm_b, const float* w_proj, const float* bn2_g,
                         const float* bn2_b, const float* w_fus, const float* bn3_g, const float* bn3_b,
                         const int* task, float* out, bf16* tok, TT* t, float* dense, float* part,
                         hipStream_t stream)
{
    float* h1 = out;  // d_out used as early fp32 scratch; fully rewritten by final conv
    hipLaunchKernelGGL(k_conv3x3<float>, dim3(4, 128, 32), dim3(256), 0, stream,
                       x, 128, (const float*)nullptr, 0, w_kxk, bn1_g, bn1_b, h1, 128);
    hipLaunchKernelGGL(k_patch1x1, dim3(64, 32), dim3(256), 0, stream, h1, w_1x1, tok);
    hipLaunchKernelGGL(k_gate, dim3(512), dim3(256), 0, stream, tok, gate_w, task, dense, part);
    hipLaunchKernelGGL(k_moe<TT>, dim3(2048), dim3(256), 0, stream,
                       tok, dense, moe_w1, moe_b1, moe_w2, moe_b2, t);
    bf16* y2 = tok;  // tok dead after MoE
    for (int l = 0; l < 2; ++l) {
        hipLaunchKernelGGL(k_attn<TT>, dim3(2048, 4), dim3(256), 0, stream,
                           t, ln1_g + l * 192, ln1_b + l * 192,
                           qkv_w + (size_t)l * 110592, qkv_b + l * 576, y2);
        hipLaunchKernelGGL(k_proj<TT>, dim3(2048), dim3(256), 0, stream,
                           y2, proj_w + (size_t)l * 36864, proj_b + l * 192, t);
        hipLaunchKernelGGL(k_mlp<TT>, dim3(2048), dim3(256), 0, stream,
                           t, ln2_g + l * 192, ln2_b + l * 192,
                           fc1_w + (size_t)l * 73728, fc1_b + l * 384,
                           fc2_w + (size_t)l * 73728, fc2_b + l * 192);
    }
    bf16* p = tok;  // y2 dead after last proj
    hipLaunchKernelGGL(k_unpatch<TT>, dim3(64, 32), dim3(256), 0, stream,
                       t, nrm_g, nrm_b, w_proj, bn2_g, bn2_b, p);
    hipLaunchKernelGGL(k_conv3x3<bf16>, dim3(4, 128, 32), dim3(256), 0, stream,
                       x, 128, (const bf16*)p, 128, w_fus, bn3_g, bn3_b, out, 128);
    hipLaunchKernelGGL(k_loss, dim3(1), dim3(64), 0, stream, part, out);
}

extern "C" void kernel_launch(void* const* d_in, const int* in_sizes, int n_in,
                              void* d_out, int out_size, void* d_ws, size_t ws_size,
                              hipStream_t stream) {
    const float* x      = (const float*)d_in[0];
    const float* w_kxk  = (const float*)d_in[1];
    const float* bn1_g  = (const float*)d_in[2];
    const float* bn1_b  = (const float*)d_in[3];
    const float* w_1x1  = (const float*)d_in[4];
    const float* gate_w = (const float*)d_in[5];
    const float* moe_w1 = (const float*)d_in[6];
    const float* moe_b1 = (const float*)d_in[7];
    const float* moe_w2 = (const float*)d_in[8];
    const float* moe_b2 = (const float*)d_in[9];
    const float* ln1_g  = (const float*)d_in[10];
    const float* ln1_b  = (const float*)d_in[11];
    const float* qkv_w  = (const float*)d_in[12];
    const float* qkv_b  = (const float*)d_in[13];
    const float* proj_w = (const float*)d_in[14];
    const float* proj_b = (const float*)d_in[15];
    const float* ln2_g  = (const float*)d_in[16];
    const float* ln2_b  = (const float*)d_in[17];
    const float* fc1_w  = (const float*)d_in[18];
    const float* fc1_b  = (const float*)d_in[19];
    const float* fc2_w  = (const float*)d_in[20];
    const float* fc2_b  = (const float*)d_in[21];
    const float* nrm_g  = (const float*)d_in[22];
    const float* nrm_b  = (const float*)d_in[23];
    const float* w_proj = (const float*)d_in[24];
    const float* bn2_g  = (const float*)d_in[25];
    const float* bn2_b  = (const float*)d_in[26];
    const float* w_fus  = (const float*)d_in[27];
    const float* bn3_g  = (const float*)d_in[28];
    const float* bn3_b  = (const float*)d_in[29];
    const int*  task    = (const int*)d_in[30];

    char* wsb = (char*)d_ws;
    const size_t tok_bytes = 50331648ull;              // bf16 tok / y2 / p region
    const size_t t32_bytes = 100663296ull;
    const size_t t16_bytes = 50331648ull;
    const size_t tail      = 2097152ull + 16384ull;
    bf16* tok = (bf16*)wsb;
    float* out = (float*)d_out;

    if (ws_size >= tok_bytes + t32_bytes + tail) {
        float* t     = (float*)(wsb + tok_bytes);
        float* dense = (float*)(wsb + tok_bytes + t32_bytes);
        float* part  = dense + 524288;
        run_pipeline<float>(x, w_kxk, bn1_g, bn1_b, w_1x1, gate_w, moe_w1, moe_b1, moe_w2, moe_b2,
                            ln1_g, ln1_b, qkv_w, qkv_b, proj_w, proj_b, ln2_g, ln2_b,
                            fc1_w, fc1_b, fc2_w, fc2_b, nrm_g, nrm_b, w_proj, bn2_g, bn2_b,
                            w_fus, bn3_g, bn3_b, task, out, tok, t, dense, part, stream);
    } else {
        bf16* t      = (bf16*)(wsb + tok_bytes);
        float* dense = (float*)(wsb + tok_bytes + t16_bytes);
        float* part  = dense + 524288;
        run_pipeline<bf16>(x, w_kxk, bn1_g, bn1_b, w_1x1, gate_w, moe_w1, moe_b1, moe_w2, moe_b2,
                           ln1_g, ln1_b, qkv_w, qkv_b, proj_w, proj_b, ln2_g, ln2_b,
                           fc1_w, fc1_b, fc2_w, fc2_b, nrm_g, nrm_b, w_proj, bn2_g, bn2_b,
                           w_fus, bn3_g, bn3_b, task, out, tok, t, dense, part, stream);
    }
}

// Round 4
// 11432.809 us; speedup vs baseline: 1.8748x; 1.8748x over previous
//
#include <hip/hip_runtime.h>
#include <hip/hip_bf16.h>
#include <cmath>

typedef __hip_bfloat16 bf16;
typedef __attribute__((ext_vector_type(8))) short short8;
typedef __attribute__((ext_vector_type(4))) float float4v;

__device__ __forceinline__ float b2f(bf16 v) { return __bfloat162float(v); }
__device__ __forceinline__ bf16  f2b(float v) { return __float2bfloat16(v); }
__device__ __forceinline__ float bfr(unsigned int u) { union { float f; unsigned int i; } c; c.i = u << 16; return c.f; }
__device__ __forceinline__ void ld4(const float* p, float* o) {
    float4 q = *(const float4*)p; o[0]=q.x; o[1]=q.y; o[2]=q.z; o[3]=q.w;
}
__device__ __forceinline__ void ld4(const bf16* p, float* o) {
    const uint2 q = *(const uint2*)p;
    o[0] = bfr(q.x & 0xffffu); o[1] = bfr(q.x >> 16);
    o[2] = bfr(q.y & 0xffffu); o[3] = bfr(q.y >> 16);
}
__device__ __forceinline__ float ldv(const float* p) { return *p; }
__device__ __forceinline__ float ldv(const bf16* p)  { return b2f(*p); }
__device__ __forceinline__ void  stv(float* p, float v) { *p = v; }
__device__ __forceinline__ void  stv(bf16* p, float v)  { *p = f2b(v); }

__device__ __forceinline__ float siluf(float x) { return x / (1.f + expf(-x)); }
__device__ __forceinline__ float geluf(float x) { return 0.5f * x * (1.f + erff(x * 0.70710678118654752f)); }

// LN of 64 rows (pitch 193) held in LDS; 4 threads/row; params fp32.
__device__ __forceinline__ void ln_rows193(float (*L)[193], const float* g, const float* b, int tid) {
    const int i = tid >> 2, jg = tid & 3;
    float s = 0.f, sq = 0.f;
    #pragma unroll
    for (int k2 = 0; k2 < 48; ++k2) { float v = L[i][jg * 48 + k2]; s += v; sq += v * v; }
    s  += __shfl_xor(s, 1);  s  += __shfl_xor(s, 2);
    sq += __shfl_xor(sq, 1); sq += __shfl_xor(sq, 2);
    const float m  = s * (1.f / 192.f);
    const float var = sq * (1.f / 192.f) - m * m;
    const float rs = rsqrtf(var + 1e-5f);
    #pragma unroll
    for (int k2 = 0; k2 < 48; ++k2) {
        int d = jg * 48 + k2;
        L[i][d] = (L[i][d] - m) * rs * g[d] + b[d];
    }
}

// ---------------- weight prep: fp32 [k][n] -> bf16 MFMA-fragment order ----------------
// frag addr: ((k>>5)*NT + (n>>4))*512 + (((k>>3)&3)*16 + (n&15))*8 + (k&7)
__global__ __launch_bounds__(256) void k_prep(
    const float* __restrict__ src, bf16* __restrict__ dst, int K, int N, int nmat)
{
    const int per = K * N;
    const int total = per * nmat;
    const int NT = N >> 4;
    for (int idx = blockIdx.x * 256 + threadIdx.x; idx < total; idx += gridDim.x * 256) {
        int m = idx / per;
        int rem = idx - m * per;
        int k = rem / N, n = rem - k * N;
        int off = ((k >> 5) * NT + (n >> 4)) * 512 + (((k >> 3) & 3) * 16 + (n & 15)) * 8 + (k & 7);
        dst[(size_t)m * per + off] = f2b(src[idx]);
    }
}

// ---------------- conv3x3 (+optional concat input of type T2) + BN + SiLU ----------------
template <typename T2>
__global__ __launch_bounds__(256) void k_conv3x3(
    const float* __restrict__ in1, int C1,
    const T2* __restrict__ in2, int C2,
    const float* __restrict__ w,
    const float* __restrict__ gamma, const float* __restrict__ beta,
    float* __restrict__ out, int Cout)
{
    __shared__ float wl[2304];
    const int tid = threadIdx.x;
    const int col = tid & 63;
    const int r0  = blockIdx.x * 16 + (tid >> 6) * 4;
    const int oc  = blockIdx.y;
    const int b   = blockIdx.z;
    const int Cin = C1 + C2;
    for (int i = tid; i < Cin * 9; i += 256) wl[i] = w[(size_t)oc * Cin * 9 + i];
    __syncthreads();
    float a0 = 0.f, a1 = 0.f, a2 = 0.f, a3 = 0.f;
    {
        const float* bb = in1 + (size_t)b * C1 * 4096;
        for (int ic = 0; ic < C1; ++ic) {
            const float* p  = bb + ic * 4096;
            const float* wr = &wl[ic * 9];
            #pragma unroll
            for (int iy = 0; iy < 6; ++iy) {
                int ry = r0 - 1 + iy;
                float v0 = 0.f, v1 = 0.f, v2 = 0.f;
                if (ry >= 0 && ry < 64) {
                    const float* rp = p + ry * 64 + col;
                    v1 = rp[0];
                    v0 = (col > 0)  ? rp[-1] : 0.f;
                    v2 = (col < 63) ? rp[1]  : 0.f;
                }
                #pragma unroll
                for (int ky = 0; ky < 3; ++ky) {
                    int o = iy - ky;
                    if (o >= 0 && o < 4) {
                        float s = v0 * wr[ky*3] + v1 * wr[ky*3+1] + v2 * wr[ky*3+2];
                        if      (o == 0) a0 += s;
                        else if (o == 1) a1 += s;
                        else if (o == 2) a2 += s;
                        else             a3 += s;
                    }
                }
            }
        }
    }
    if (C2 > 0) {
        const T2* bb = in2 + (size_t)b * C2 * 4096;
        for (int ic = 0; ic < C2; ++ic) {
            const T2* p  = bb + ic * 4096;
            const float* wr = &wl[C1 * 9 + ic * 9];
            #pragma unroll
            for (int iy = 0; iy < 6; ++iy) {
                int ry = r0 - 1 + iy;
                float v0 = 0.f, v1 = 0.f, v2 = 0.f;
                if (ry >= 0 && ry < 64) {
                    const T2* rp = p + ry * 64 + col;
                    v1 = ldv(rp);
                    v0 = (col > 0)  ? ldv(rp - 1) : 0.f;
                    v2 = (col < 63) ? ldv(rp + 1) : 0.f;
                }
                #pragma unroll
                for (int ky = 0; ky < 3; ++ky) {
                    int o = iy - ky;
                    if (o >= 0 && o < 4) {
                        float s = v0 * wr[ky*3] + v1 * wr[ky*3+1] + v2 * wr[ky*3+2];
                        if      (o == 0) a0 += s;
                        else if (o == 1) a1 += s;
                        else if (o == 2) a2 += s;
                        else             a3 += s;
                    }
                }
            }
        }
    }
    const float g = gamma[oc], be = beta[oc];
    float accs[4] = {a0, a1, a2, a3};
    #pragma unroll
    for (int o = 0; o < 4; ++o) {
        float v = g * accs[o] + be;
        out[(((size_t)b * Cout + oc) * 64 + (r0 + o)) * 64 + col] = siluf(v);
    }
}

// ---------------- patchify + 1x1 (128 -> 192), tok bf16 ----------------
__global__ __launch_bounds__(256) void k_patch1x1(
    const float* __restrict__ h1, const float* __restrict__ w, bf16* __restrict__ tok)
{
    const int np = blockIdx.x, b = blockIdx.y;
    const int pi = np >> 3, pj = np & 7;
    __shared__ float hp[128][65];
    __shared__ float outL[64][193];
    for (int idx = threadIdx.x; idx < 128 * 64; idx += 256) {
        int c = idx >> 6, pa = idx & 63;
        int y = pi * 8 + (pa >> 3), x = pj * 8 + (pa & 7);
        hp[c][pa] = h1[(((size_t)b * 128 + c) * 64 + y) * 64 + x];
    }
    __syncthreads();
    const int pa = threadIdx.x & 63;
    const int wv = threadIdx.x >> 6;
    for (int dd = 0; dd < 48; ++dd) {
        int d = wv * 48 + dd;
        float acc = 0.f;
        for (int c4 = 0; c4 < 32; ++c4) {
            float wq[4]; ld4(w + (size_t)d * 128 + c4 * 4, wq);
            acc += hp[c4*4+0][pa] * wq[0] + hp[c4*4+1][pa] * wq[1]
                 + hp[c4*4+2][pa] * wq[2] + hp[c4*4+3][pa] * wq[3];
        }
        outL[pa][d] = acc;
    }
    __syncthreads();
    for (int idx = threadIdx.x; idx < 64 * 192; idx += 256) {
        int pa2 = idx / 192, d2 = idx % 192;
        tok[((size_t)(b * 64 + pa2) * 64 + np) * 192 + d2] = f2b(outL[pa2][d2]);
    }
}

// ---------------- gating ----------------
__global__ __launch_bounds__(256) void k_gate(
    const bf16* __restrict__ tok, const float* __restrict__ gate_w_all,
    const int* __restrict__ task, float* __restrict__ dense,
    float* __restrict__ part)
{
    __shared__ float gwL[768];
    for (int i = threadIdx.x; i < 768; i += 256) gwL[i] = gate_w_all[(size_t)task[0] * 768 + i];
    __syncthreads();
    const int r = blockIdx.x * 256 + threadIdx.x;
    const bf16* tb = tok + (size_t)r * 192;
    float L0 = 0.f, L1 = 0.f, L2 = 0.f, L3 = 0.f;
    for (int c4 = 0; c4 < 48; ++c4) {
        float xv[4]; ld4(tb + c4 * 4, xv);
        #pragma unroll
        for (int j = 0; j < 4; ++j) {
            int c = c4 * 4 + j;
            L0 += xv[j] * gwL[c*4+0]; L1 += xv[j] * gwL[c*4+1];
            L2 += xv[j] * gwL[c*4+2]; L3 += xv[j] * gwL[c*4+3];
        }
    }
    float m = fmaxf(fmaxf(L0, L1), fmaxf(L2, L3));
    float e0 = expf(L0 - m), e1 = expf(L1 - m), e2 = expf(L2 - m), e3 = expf(L3 - m);
    float s = e0 + e1 + e2 + e3;
    float p[4] = {e0 / s, e1 / s, e2 / s, e3 / s};
    int i1 = 0; float v1 = p[0];
    #pragma unroll
    for (int e = 1; e < 4; ++e) if (p[e] > v1) { v1 = p[e]; i1 = e; }
    int i2 = -1; float v2 = -1.f;
    #pragma unroll
    for (int e = 0; e < 4; ++e) if (e != i1 && p[e] > v2) { v2 = p[e]; i2 = e; }
    float gs = v1 + v2;
    float d[4] = {0.f, 0.f, 0.f, 0.f};
    d[i1] = v1 / gs; d[i2] = v2 / gs;
    ((float4*)dense)[r] = make_float4(d[0], d[1], d[2], d[3]);

    float vals[8] = {p[0], p[1], p[2], p[3],
                     d[0] > 0.f ? 1.f : 0.f, d[1] > 0.f ? 1.f : 0.f,
                     d[2] > 0.f ? 1.f : 0.f, d[3] > 0.f ? 1.f : 0.f};
    #pragma unroll
    for (int off = 32; off; off >>= 1)
        #pragma unroll
        for (int i = 0; i < 8; ++i) vals[i] += __shfl_down(vals[i], off);
    __shared__ float sm[4][8];
    const int lane = threadIdx.x & 63, wv = threadIdx.x >> 6;
    if (lane == 0)
        #pragma unroll
        for (int i = 0; i < 8; ++i) sm[wv][i] = vals[i];
    __syncthreads();
    if (threadIdx.x < 8)
        part[blockIdx.x * 8 + threadIdx.x] =
            sm[0][threadIdx.x] + sm[1][threadIdx.x] + sm[2][threadIdx.x] + sm[3][threadIdx.x];
}

// ---------------- MoE via MFMA: t = sum_e dense_e * (gelu(tok@w1+b1)@w2 + b2) ----------------
// grid 2048 (64 tokens), 256 thr (4 waves x 16 rows). Weights pre-fragmented bf16.
template <typename TT>
__global__ __launch_bounds__(256) void k_moe_mfma(
    const bf16* __restrict__ tok, const float* __restrict__ dense,
    const bf16* __restrict__ w1f, const float* __restrict__ b1,
    const bf16* __restrict__ w2f, const float* __restrict__ b2,
    TT* __restrict__ tout)
{
    __shared__ __align__(16) bf16 hL[64][200];
    const int rbase = blockIdx.x * 64;
    const int lane = threadIdx.x & 63, w = threadIdx.x >> 6;
    const int m0 = w * 16;
    const int kg = lane >> 4;          // k-group / D-row group
    const int ln16 = lane & 15;
    const int arow = rbase + m0 + ln16;

    float4v accT[12];
    #pragma unroll
    for (int i = 0; i < 12; ++i) accT[i] = (float4v)0.f;

    for (int e = 0; e < 4; ++e) {
        float g4[4];
        #pragma unroll
        for (int r = 0; r < 4; ++r)
            g4[r] = dense[(size_t)(rbase + m0 + kg * 4 + r) * 4 + e];

        float4v acc[12];
        #pragma unroll
        for (int i = 0; i < 12; ++i) acc[i] = (float4v)0.f;
        for (int kc = 0; kc < 6; ++kc) {
            short8 a = *(const short8*)(const void*)(tok + (size_t)arow * 192 + kc * 32 + kg * 8);
            const bf16* wb = w1f + (size_t)e * 36864 + (kc * 12) * 512 + lane * 8;
            #pragma unroll
            for (int nt = 0; nt < 12; ++nt) {
                short8 bfrag = *(const short8*)(const void*)(wb + nt * 512);
                acc[nt] = __builtin_amdgcn_mfma_f32_16x16x32_bf16(a, bfrag, acc[nt], 0, 0, 0);
            }
        }
        #pragma unroll
        for (int nt = 0; nt < 12; ++nt) {
            int c = nt * 16 + ln16;
            float bias = b1[e * 192 + c];
            #pragma unroll
            for (int r = 0; r < 4; ++r)
                hL[m0 + kg * 4 + r][c] = f2b(geluf(acc[nt][r] + bias));
        }
        __syncthreads();
        #pragma unroll
        for (int i = 0; i < 12; ++i) acc[i] = (float4v)0.f;
        for (int kc = 0; kc < 6; ++kc) {
            short8 a = *(const short8*)(const void*)(&hL[m0 + ln16][kc * 32 + kg * 8]);
            const bf16* wb = w2f + (size_t)e * 36864 + (kc * 12) * 512 + lane * 8;
            #pragma unroll
            for (int nt = 0; nt < 12; ++nt) {
                short8 bfrag = *(const short8*)(const void*)(wb + nt * 512);
                acc[nt] = __builtin_amdgcn_mfma_f32_16x16x32_bf16(a, bfrag, acc[nt], 0, 0, 0);
            }
        }
        #pragma unroll
        for (int nt = 0; nt < 12; ++nt) {
            int c = nt * 16 + ln16;
            float bias = b2[e * 192 + c];
            #pragma unroll
            for (int r = 0; r < 4; ++r)
                accT[nt][r] += g4[r] * (acc[nt][r] + bias);
        }
        __syncthreads();
    }
    #pragma unroll
    for (int nt = 0; nt < 12; ++nt) {
        int c = nt * 16 + ln16;
        #pragma unroll
        for (int r = 0; r < 4; ++r)
            stv(&tout[(size_t)(rbase + m0 + kg * 4 + r) * 192 + c], accT[nt][r]);
    }
}

// ---------------- proj via MFMA: t += y2 @ proj_w + pb ----------------
template <typename TT>
__global__ __launch_bounds__(256) void k_proj_mfma(
    const bf16* __restrict__ y2, const bf16* __restrict__ pwf,
    const float* __restrict__ pb, TT* __restrict__ t)
{
    const int rbase = blockIdx.x * 64;
    const int lane = threadIdx.x & 63, w = threadIdx.x >> 6;
    const int m0 = w * 16;
    const int kg = lane >> 4, ln16 = lane & 15;
    const int arow = rbase + m0 + ln16;
    float4v acc[12];
    #pragma unroll
    for (int i = 0; i < 12; ++i) acc[i] = (float4v)0.f;
    for (int kc = 0; kc < 6; ++kc) {
        short8 a = *(const short8*)(const void*)(y2 + (size_t)arow * 192 + kc * 32 + kg * 8);
        const bf16* wb = pwf + (kc * 12) * 512 + lane * 8;
        #pragma unroll
        for (int nt = 0; nt < 12; ++nt) {
            short8 bfrag = *(const short8*)(const void*)(wb + nt * 512);
            acc[nt] = __builtin_amdgcn_mfma_f32_16x16x32_bf16(a, bfrag, acc[nt], 0, 0, 0);
        }
    }
    #pragma unroll
    for (int nt = 0; nt < 12; ++nt) {
        int c = nt * 16 + ln16;
        float bias = pb[c];
        #pragma unroll
        for (int r = 0; r < 4; ++r) {
            TT* p = &t[(size_t)(rbase + m0 + kg * 4 + r) * 192 + c];
            stv(p, ldv(p) + acc[nt][r] + bias);
        }
    }
}

// ---------------- fused LN2 + MLP via MFMA: t += gelu(ln(t)@fc1+b1)@fc2+b2 ----------------
template <typename TT>
__global__ __launch_bounds__(256) void k_mlp_mfma(
    TT* __restrict__ t, const float* __restrict__ lg, const float* __restrict__ lb,
    const bf16* __restrict__ w1f, const float* __restrict__ b1,
    const bf16* __restrict__ w2f, const float* __restrict__ b2)
{
    __shared__ __align__(16) bf16 yL[64][200];
    __shared__ __align__(16) bf16 hL[64][200];
    const int rbase = blockIdx.x * 64;
    const int tid = threadIdx.x;
    // LN: 4 threads per row
    {
        const int row = tid >> 2, qg = tid & 3;
        float v[48];
        const TT* tr_ = t + (size_t)(rbase + row) * 192 + qg * 48;
        float s = 0.f, sq = 0.f;
        #pragma unroll
        for (int i = 0; i < 12; ++i) {
            float tmp[4]; ld4(tr_ + i * 4, tmp);
            #pragma unroll
            for (int j = 0; j < 4; ++j) { v[i*4+j] = tmp[j]; s += tmp[j]; sq += tmp[j]*tmp[j]; }
        }
        s  += __shfl_xor(s, 1);  s  += __shfl_xor(s, 2);
        sq += __shfl_xor(sq, 1); sq += __shfl_xor(sq, 2);
        float m = s * (1.f/192.f), var = sq * (1.f/192.f) - m*m;
        float rs = rsqrtf(var + 1e-5f);
        #pragma unroll
        for (int i = 0; i < 48; ++i) {
            int d = qg * 48 + i;
            yL[row][d] = f2b((v[i] - m) * rs * lg[d] + lb[d]);
        }
    }
    __syncthreads();
    const int lane = tid & 63, w = tid >> 6;
    const int m0 = w * 16;
    const int kg = lane >> 4, ln16 = lane & 15;
    float4v accT[12];
    #pragma unroll
    for (int i = 0; i < 12; ++i) accT[i] = (float4v)0.f;
    for (int ch = 0; ch < 2; ++ch) {
        float4v acc[12];
        #pragma unroll
        for (int i = 0; i < 12; ++i) acc[i] = (float4v)0.f;
        for (int kc = 0; kc < 6; ++kc) {
            short8 a = *(const short8*)(const void*)(&yL[m0 + ln16][kc * 32 + kg * 8]);
            const bf16* wb = w1f + (size_t)(kc * 24 + ch * 12) * 512 + lane * 8;
            #pragma unroll
            for (int nt = 0; nt < 12; ++nt) {
                short8 bfrag = *(const short8*)(const void*)(wb + nt * 512);
                acc[nt] = __builtin_amdgcn_mfma_f32_16x16x32_bf16(a, bfrag, acc[nt], 0, 0, 0);
            }
        }
        #pragma unroll
        for (int nt = 0; nt < 12; ++nt) {
            int c = nt * 16 + ln16;
            float bias = b1[ch * 192 + c];
            #pragma unroll
            for (int r = 0; r < 4; ++r)
                hL[m0 + kg * 4 + r][c] = f2b(geluf(acc[nt][r] + bias));
        }
        __syncthreads();
        for (int kc = 0; kc < 6; ++kc) {
            short8 a = *(const short8*)(const void*)(&hL[m0 + ln16][kc * 32 + kg * 8]);
            const bf16* wb = w2f + (size_t)((ch * 6 + kc) * 12) * 512 + lane * 8;
            #pragma unroll
            for (int nt = 0; nt < 12; ++nt) {
                short8 bfrag = *(const short8*)(const void*)(wb + nt * 512);
                accT[nt] = __builtin_amdgcn_mfma_f32_16x16x32_bf16(a, bfrag, accT[nt], 0, 0, 0);
            }
        }
        __syncthreads();
    }
    #pragma unroll
    for (int nt = 0; nt < 12; ++nt) {
        int c = nt * 16 + ln16;
        float bias = b2[c];
        #pragma unroll
        for (int r = 0; r < 4; ++r) {
            TT* p = &t[(size_t)(rbase + m0 + kg * 4 + r) * 192 + c];
            stv(p, ldv(p) + accT[nt][r] + bias);
        }
    }
}

// ---------------- fused LN1 + attention per (seq, head) ----------------
template <typename TT>
__global__ __launch_bounds__(256) void k_attn(
    const TT* __restrict__ t, const float* __restrict__ lg, const float* __restrict__ lb,
    const float* __restrict__ qkvw, const float* __restrict__ qkvb, bf16* __restrict__ y2)
{
    const int n = blockIdx.x, h = blockIdx.y;
    __shared__ float yL[64][193];
    __shared__ float qL[64][49], kL[64][49], vL[64][49];
    __shared__ float pL[64][65];
    for (int idx = threadIdx.x * 4; idx < 64 * 192; idx += 1024) {
        float tmp[4]; ld4(t + (size_t)n * 12288 + idx, tmp);
        int r = idx / 192, d = idx % 192;
        yL[r][d] = tmp[0]; yL[r][d+1] = tmp[1]; yL[r][d+2] = tmp[2]; yL[r][d+3] = tmp[3];
    }
    __syncthreads();
    ln_rows193(yL, lg, lb, threadIdx.x);
    __syncthreads();
    const int lane = threadIdx.x & 63, wv = threadIdx.x >> 6;
    const float scale = rsqrtf(48.f);
    {
        int cols[9], whichs[9], dqs[9];
        #pragma unroll
        for (int q = 0; q < 9; ++q) {
            int qq = wv * 9 + q;
            whichs[q] = qq / 12; dqs[q] = (qq % 12) * 4;
            cols[q] = whichs[q] * 192 + h * 48 + dqs[q];
        }
        float a[36];
        #pragma unroll
        for (int q = 0; q < 9; ++q) {
            float bq[4]; ld4(qkvb + cols[q], bq);
            a[q*4+0] = bq[0]; a[q*4+1] = bq[1]; a[q*4+2] = bq[2]; a[q*4+3] = bq[3];
        }
        for (int k = 0; k < 192; ++k) {
            float x = yL[lane][k];
            const float* wr = qkvw + (size_t)k * 576;
            #pragma unroll
            for (int q = 0; q < 9; ++q) {
                float wq[4]; ld4(wr + cols[q], wq);
                a[q*4+0] += x * wq[0]; a[q*4+1] += x * wq[1];
                a[q*4+2] += x * wq[2]; a[q*4+3] += x * wq[3];
            }
        }
        #pragma unroll
        for (int q = 0; q < 9; ++q) {
            int wch = whichs[q], dq = dqs[q];
            if (wch == 0) {
                #pragma unroll
                for (int u = 0; u < 4; ++u) qL[lane][dq + u] = a[q*4+u] * scale;
            } else if (wch == 1) {
                #pragma unroll
                for (int u = 0; u < 4; ++u) kL[lane][dq + u] = a[q*4+u];
            } else {
                #pragma unroll
                for (int u = 0; u < 4; ++u) vL[lane][dq + u] = a[q*4+u];
            }
        }
    }
    __syncthreads();
    {
        const int i = threadIdx.x >> 2, jg = threadIdx.x & 3;
        float sc[16];
        #pragma unroll
        for (int jj = 0; jj < 16; ++jj) {
            int j = jg * 16 + jj;
            float sv = 0.f;
            #pragma unroll 12
            for (int d = 0; d < 48; ++d) sv += qL[i][d] * kL[j][d];
            sc[jj] = sv;
        }
        float m = sc[0];
        #pragma unroll
        for (int jj = 1; jj < 16; ++jj) m = fmaxf(m, sc[jj]);
        m = fmaxf(m, __shfl_xor(m, 1)); m = fmaxf(m, __shfl_xor(m, 2));
        float ssum = 0.f;
        #pragma unroll
        for (int jj = 0; jj < 16; ++jj) { sc[jj] = expf(sc[jj] - m); ssum += sc[jj]; }
        ssum += __shfl_xor(ssum, 1); ssum += __shfl_xor(ssum, 2);
        float inv = 1.f / ssum;
        #pragma unroll
        for (int jj = 0; jj < 16; ++jj) pL[i][jg * 16 + jj] = sc[jj] * inv;
    }
    __syncthreads();
    {
        float oacc[12];
        #pragma unroll
        for (int u = 0; u < 12; ++u) oacc[u] = 0.f;
        for (int j = 0; j < 64; ++j) {
            float pv = pL[lane][j];
            #pragma unroll
            for (int u = 0; u < 12; ++u) oacc[u] += pv * vL[j][wv * 12 + u];
        }
        #pragma unroll
        for (int u = 0; u < 12; ++u) kL[lane][wv * 12 + u] = oacc[u];
    }
    __syncthreads();
    for (int idx = threadIdx.x; idx < 64 * 48; idx += 256) {
        int s = idx / 48, d = idx % 48;
        y2[((size_t)n * 64 + s) * 192 + h * 48 + d] = f2b(kL[s][d]);
    }
}

// ---------------- fused final LN + unpatchify + 1x1 (192->128) + BN + SiLU ----------------
template <typename TT>
__global__ __launch_bounds__(256) void k_unpatch(
    const TT* __restrict__ t, const float* __restrict__ ng, const float* __restrict__ nb,
    const float* __restrict__ wp, const float* __restrict__ gamma, const float* __restrict__ beta,
    bf16* __restrict__ p)
{
    const int np = blockIdx.x, b = blockIdx.y;
    const int pi = np >> 3, pj = np & 7;
    __shared__ float tL[64][193];
    __shared__ float oL[64][129];
    for (int idx = threadIdx.x * 4; idx < 64 * 192; idx += 1024) {
        int pa = idx / 192, d = idx % 192;
        float tmp[4]; ld4(t + ((size_t)(b * 64 + pa) * 64 + np) * 192 + d, tmp);
        tL[pa][d] = tmp[0]; tL[pa][d+1] = tmp[1]; tL[pa][d+2] = tmp[2]; tL[pa][d+3] = tmp[3];
    }
    __syncthreads();
    ln_rows193(tL, ng, nb, threadIdx.x);
    __syncthreads();
    const int lane = threadIdx.x & 63, wv = threadIdx.x >> 6;
    for (int k = 0; k < 32; ++k) {
        int o = wv * 32 + k;
        float acc = 0.f;
        for (int d4 = 0; d4 < 48; ++d4) {
            float wq[4]; ld4(wp + (size_t)o * 192 + d4 * 4, wq);
            acc += tL[lane][d4*4+0] * wq[0] + tL[lane][d4*4+1] * wq[1]
                 + tL[lane][d4*4+2] * wq[2] + tL[lane][d4*4+3] * wq[3];
        }
        float v = gamma[o] * acc + beta[o];
        oL[lane][o] = siluf(v);
    }
    __syncthreads();
    for (int idx = threadIdx.x; idx < 64 * 128; idx += 256) {
        int o = idx >> 6, pa = idx & 63;
        p[(((size_t)b * 128 + o) * 64 + (pi * 8 + (pa >> 3))) * 64 + pj * 8 + (pa & 7)] = f2b(oL[pa][o]);
    }
}

// ---------------- moe loss ----------------
__global__ void k_loss(const float* __restrict__ part, float* __restrict__ out)
{
    if (threadIdx.x == 0 && blockIdx.x == 0) {
        float L = 0.f;
        for (int e = 0; e < 4; ++e) {
            float imp = 0.f, ld = 0.f;
            for (int i = 0; i < 512; ++i) { imp += part[i * 8 + e]; ld += part[i * 8 + 4 + e]; }
            L += (imp / 131072.f) * (ld / 131072.f);
        }
        out[16777216] = 4.f * L;
    }
}

template <typename TT>
static void run_pipeline(const float* x, const float* w_kxk, const float* bn1_g, const float* bn1_b,
                         const float* w_1x1, const float* gate_w,
                         const float* moe_w1, const float* moe_b1, const float* moe_w2, const float* moe_b2,
                         const float* ln1_g, const float* ln1_b, const float* qkv_w, const float* qkv_b,
                         const float* proj_w, const float* proj_b, const float* ln2_g, const float* ln2_b,
                         const float* fc1_w, const float* fc1_b, const float* fc2_w, const float* fc2_b,
                         const float* nrm_g, const float* nrm_b, const float* w_proj, const float* bn2_g,
                         const float* bn2_b, const float* w_fus, const float* bn3_g, const float* bn3_b,
                         const int* task, float* out, bf16* tok, TT* t, float* dense, float* part,
                         bf16* wprep, hipStream_t stream)
{
    // prep fragments: moeW1 | moeW2 | fc1 | fc2 | projW
    bf16* moeW1f = wprep;
    bf16* moeW2f = wprep + 147456;
    bf16* fc1f   = wprep + 294912;
    bf16* fc2f   = wprep + 442368;
    bf16* projWf = wprep + 589824;
    hipLaunchKernelGGL(k_prep, dim3(576), dim3(256), 0, stream, moe_w1, moeW1f, 192, 192, 4);
    hipLaunchKernelGGL(k_prep, dim3(576), dim3(256), 0, stream, moe_w2, moeW2f, 192, 192, 4);
    hipLaunchKernelGGL(k_prep, dim3(576), dim3(256), 0, stream, fc1_w, fc1f, 192, 384, 2);
    hipLaunchKernelGGL(k_prep, dim3(576), dim3(256), 0, stream, fc2_w, fc2f, 384, 192, 2);
    hipLaunchKernelGGL(k_prep, dim3(288), dim3(256), 0, stream, proj_w, projWf, 192, 192, 2);

    float* h1 = out;  // d_out used as early fp32 scratch; fully rewritten by final conv
    hipLaunchKernelGGL(k_conv3x3<float>, dim3(4, 128, 32), dim3(256), 0, stream,
                       x, 128, (const float*)nullptr, 0, w_kxk, bn1_g, bn1_b, h1, 128);
    hipLaunchKernelGGL(k_patch1x1, dim3(64, 32), dim3(256), 0, stream, h1, w_1x1, tok);
    hipLaunchKernelGGL(k_gate, dim3(512), dim3(256), 0, stream, tok, gate_w, task, dense, part);
    hipLaunchKernelGGL(k_moe_mfma<TT>, dim3(2048), dim3(256), 0, stream,
                       tok, dense, moeW1f, moe_b1, moeW2f, moe_b2, t);
    bf16* y2 = tok;  // tok dead after MoE
    for (int l = 0; l < 2; ++l) {
        hipLaunchKernelGGL(k_attn<TT>, dim3(2048, 4), dim3(256), 0, stream,
                           t, ln1_g + l * 192, ln1_b + l * 192,
                           qkv_w + (size_t)l * 110592, qkv_b + l * 576, y2);
        hipLaunchKernelGGL(k_proj_mfma<TT>, dim3(2048), dim3(256), 0, stream,
                           y2, projWf + (size_t)l * 36864, proj_b + l * 192, t);
        hipLaunchKernelGGL(k_mlp_mfma<TT>, dim3(2048), dim3(256), 0, stream,
                           t, ln2_g + l * 192, ln2_b + l * 192,
                           fc1f + (size_t)l * 73728, fc1_b + l * 384,
                           fc2f + (size_t)l * 73728, fc2_b + l * 192);
    }
    bf16* p = tok;  // y2 dead after last proj
    hipLaunchKernelGGL(k_unpatch<TT>, dim3(64, 32), dim3(256), 0, stream,
                       t, nrm_g, nrm_b, w_proj, bn2_g, bn2_b, p);
    hipLaunchKernelGGL(k_conv3x3<bf16>, dim3(4, 128, 32), dim3(256), 0, stream,
                       x, 128, (const bf16*)p, 128, w_fus, bn3_g, bn3_b, out, 128);
    hipLaunchKernelGGL(k_loss, dim3(1), dim3(64), 0, stream, part, out);
}

extern "C" void kernel_launch(void* const* d_in, const int* in_sizes, int n_in,
                              void* d_out, int out_size, void* d_ws, size_t ws_size,
                              hipStream_t stream) {
    const float* x      = (const float*)d_in[0];
    const float* w_kxk  = (const float*)d_in[1];
    const float* bn1_g  = (const float*)d_in[2];
    const float* bn1_b  = (const float*)d_in[3];
    const float* w_1x1  = (const float*)d_in[4];
    const float* gate_w = (const float*)d_in[5];
    const float* moe_w1 = (const float*)d_in[6];
    const float* moe_b1 = (const float*)d_in[7];
    const float* moe_w2 = (const float*)d_in[8];
    const float* moe_b2 = (const float*)d_in[9];
    const float* ln1_g  = (const float*)d_in[10];
    const float* ln1_b  = (const float*)d_in[11];
    const float* qkv_w  = (const float*)d_in[12];
    const float* qkv_b  = (const float*)d_in[13];
    const float* proj_w = (const float*)d_in[14];
    const float* proj_b = (const float*)d_in[15];
    const float* ln2_g  = (const float*)d_in[16];
    const float* ln2_b  = (const float*)d_in[17];
    const float* fc1_w  = (const float*)d_in[18];
    const float* fc1_b  = (const float*)d_in[19];
    const float* fc2_w  = (const float*)d_in[20];
    const float* fc2_b  = (const float*)d_in[21];
    const float* nrm_g  = (const float*)d_in[22];
    const float* nrm_b  = (const float*)d_in[23];
    const float* w_proj = (const float*)d_in[24];
    const float* bn2_g  = (const float*)d_in[25];
    const float* bn2_b  = (const float*)d_in[26];
    const float* w_fus  = (const float*)d_in[27];
    const float* bn3_g  = (const float*)d_in[28];
    const float* bn3_b  = (const float*)d_in[29];
    const int*  task    = (const int*)d_in[30];

    char* wsb = (char*)d_ws;
    const size_t TOKB   = 50331648ull;   // bf16 tok / y2 / p region
    const size_t T32B   = 100663296ull;
    const size_t T16B   = 50331648ull;
    const size_t DENSEB = 2097152ull;
    const size_t PARTB  = 16384ull;
    const size_t WPREPB = 1327104ull;
    bf16* tok = (bf16*)wsb;
    float* out = (float*)d_out;

    if (ws_size >= TOKB + T32B + DENSEB + PARTB + WPREPB) {
        float* t     = (float*)(wsb + TOKB);
        float* dense = (float*)(wsb + TOKB + T32B);
        float* part  = (float*)(wsb + TOKB + T32B + DENSEB);
        bf16*  wprep = (bf16*)(wsb + TOKB + T32B + DENSEB + PARTB);
        run_pipeline<float>(x, w_kxk, bn1_g, bn1_b, w_1x1, gate_w, moe_w1, moe_b1, moe_w2, moe_b2,
                            ln1_g, ln1_b, qkv_w, qkv_b, proj_w, proj_b, ln2_g, ln2_b,
                            fc1_w, fc1_b, fc2_w, fc2_b, nrm_g, nrm_b, w_proj, bn2_g, bn2_b,
                            w_fus, bn3_g, bn3_b, task, out, tok, t, dense, part, wprep, stream);
    } else {
        bf16*  t     = (bf16*)(wsb + TOKB);
        float* dense = (float*)(wsb + TOKB + T16B);
        float* part  = (float*)(wsb + TOKB + T16B + DENSEB);
        bf16*  wprep = (bf16*)(wsb + TOKB + T16B + DENSEB + PARTB);
        run_pipeline<bf16>(x, w_kxk, bn1_g, bn1_b, w_1x1, gate_w, moe_w1, moe_b1, moe_w2, moe_b2,
                           ln1_g, ln1_b, qkv_w, qkv_b, proj_w, proj_b, ln2_g, ln2_b,
                           fc1_w, fc1_b, fc2_w, fc2_b, nrm_g, nrm_b, w_proj, bn2_g, bn2_b,
                           w_fus, bn3_g, bn3_b, task, out, tok, t, dense, part, wprep, stream);
    }
}

// Round 5
// 6452.415 us; speedup vs baseline: 3.3219x; 1.7719x over previous
//
#include <hip/hip_runtime.h>
#include <hip/hip_bf16.h>
#include <cmath>

typedef __hip_bfloat16 bf16;
typedef __attribute__((ext_vector_type(8))) short short8;
typedef __attribute__((ext_vector_type(4))) float float4v;

__device__ __forceinline__ float b2f(bf16 v) { return __bfloat162float(v); }
__device__ __forceinline__ bf16  f2b(float v) { return __float2bfloat16(v); }
__device__ __forceinline__ float bfr(unsigned int u) { union { float f; unsigned int i; } c; c.i = u << 16; return c.f; }
__device__ __forceinline__ void ld4(const float* p, float* o) {
    float4 q = *(const float4*)p; o[0]=q.x; o[1]=q.y; o[2]=q.z; o[3]=q.w;
}
__device__ __forceinline__ void ld4(const bf16* p, float* o) {
    const uint2 q = *(const uint2*)p;
    o[0] = bfr(q.x & 0xffffu); o[1] = bfr(q.x >> 16);
    o[2] = bfr(q.y & 0xffffu); o[3] = bfr(q.y >> 16);
}
__device__ __forceinline__ float ldv(const float* p) { return *p; }
__device__ __forceinline__ float ldv(const bf16* p)  { return b2f(*p); }
__device__ __forceinline__ void  stv(float* p, float v) { *p = v; }
__device__ __forceinline__ void  stv(bf16* p, float v)  { *p = f2b(v); }

__device__ __forceinline__ float siluf(float x) { return x / (1.f + expf(-x)); }
__device__ __forceinline__ float geluf(float x) { return 0.5f * x * (1.f + erff(x * 0.70710678118654752f)); }

// LN of 64 rows (pitch 193) held in LDS; 4 threads/row; params fp32.
__device__ __forceinline__ void ln_rows193(float (*L)[193], const float* g, const float* b, int tid) {
    const int i = tid >> 2, jg = tid & 3;
    float s = 0.f, sq = 0.f;
    #pragma unroll
    for (int k2 = 0; k2 < 48; ++k2) { float v = L[i][jg * 48 + k2]; s += v; sq += v * v; }
    s  += __shfl_xor(s, 1);  s  += __shfl_xor(s, 2);
    sq += __shfl_xor(sq, 1); sq += __shfl_xor(sq, 2);
    const float m  = s * (1.f / 192.f);
    const float var = sq * (1.f / 192.f) - m * m;
    const float rs = rsqrtf(var + 1e-5f);
    #pragma unroll
    for (int k2 = 0; k2 < 48; ++k2) {
        int d = jg * 48 + k2;
        L[i][d] = (L[i][d] - m) * rs * g[d] + b[d];
    }
}

// ---------------- weight prep: fp32 [k][n] -> bf16 MFMA-fragment order ----------------
__global__ __launch_bounds__(256) void k_prep(
    const float* __restrict__ src, bf16* __restrict__ dst, int K, int N, int nmat)
{
    const int per = K * N;
    const int total = per * nmat;
    const int NT = N >> 4;
    for (int idx = blockIdx.x * 256 + threadIdx.x; idx < total; idx += gridDim.x * 256) {
        int m = idx / per;
        int rem = idx - m * per;
        int k = rem / N, n = rem - k * N;
        int off = ((k >> 5) * NT + (n >> 4)) * 512 + (((k >> 3) & 3) * 16 + (n & 15)) * 8 + (k & 7);
        dst[(size_t)m * per + off] = f2b(src[idx]);
    }
}

// src is [N][K] (row n, col k) -> fragged [K][N]
__global__ __launch_bounds__(256) void k_prep_t(
    const float* __restrict__ src, bf16* __restrict__ dst, int N, int K)
{
    const int total = N * K;
    const int NT = N >> 4;
    for (int idx = blockIdx.x * 256 + threadIdx.x; idx < total; idx += gridDim.x * 256) {
        int n = idx / K, k = idx - n * K;
        int off = ((k >> 5) * NT + (n >> 4)) * 512 + (((k >> 3) & 3) * 16 + (n & 15)) * 8 + (k & 7);
        dst[off] = f2b(src[idx]);
    }
}

// conv weights OIHW (Cout,Cin,3,3) -> 9 fragged [Cin][Cout] matrices (tap-major)
__global__ __launch_bounds__(256) void k_prep_conv(
    const float* __restrict__ src, bf16* __restrict__ dst, int Cin, int Cout)
{
    const int total = Cout * Cin * 9;
    const int NT = Cout >> 4;
    for (int idx = blockIdx.x * 256 + threadIdx.x; idx < total; idx += gridDim.x * 256) {
        int oc = idx / (Cin * 9);
        int rem = idx - oc * (Cin * 9);
        int ic = rem / 9, tap = rem - ic * 9;
        int off = tap * (Cin * Cout)
                + ((ic >> 5) * NT + (oc >> 4)) * 512
                + (((ic >> 3) & 3) * 16 + (oc & 15)) * 8 + (ic & 7);
        dst[off] = f2b(src[idx]);
    }
}

// ---------------- NCHW fp32 -> NHWC bf16 (one (b,y) row per block) ----------------
__global__ __launch_bounds__(256) void k_tohwc(const float* __restrict__ x, bf16* __restrict__ xh)
{
    __shared__ bf16 L[64][136];
    const int br = blockIdx.x;           // b*64 + y
    const int b = br >> 6, y = br & 63;
    for (int idx = threadIdx.x; idx < 8192; idx += 256) {
        int ch = idx >> 6, xc = idx & 63;
        L[xc][ch] = f2b(x[(((size_t)b * 128 + ch) * 64 + y) * 64 + xc]);
    }
    __syncthreads();
    for (int idx = threadIdx.x; idx < 1024; idx += 256) {
        int px = idx >> 4, q = idx & 15;
        *(short8*)(void*)(xh + ((size_t)br * 64 + px) * 128 + q * 8) =
            *(const short8*)(const void*)(&L[px][q * 8]);
    }
}

// ---------------- conv1 3x3 via MFMA (implicit GEMM, NHWC bf16 in/out) + BN + SiLU ----------------
// grid 2048 = B*64 rows; block 256 = 4 waves x 16 pixels
__global__ __launch_bounds__(256) void k_conv1_mfma(
    const bf16* __restrict__ xh, const bf16* __restrict__ wf,
    const float* __restrict__ gamma, const float* __restrict__ beta,
    bf16* __restrict__ h1h)
{
    __shared__ __align__(16) bf16 outL[64][136];
    const int br = blockIdx.x;
    const int b = br >> 6, y = br & 63;
    const int lane = threadIdx.x & 63, w = threadIdx.x >> 6;
    const int m0 = w * 16, kg = lane >> 4, ln16 = lane & 15;
    float4v acc[8];
    #pragma unroll
    for (int i = 0; i < 8; ++i) acc[i] = (float4v)0.f;
    #pragma unroll
    for (int tap = 0; tap < 9; ++tap) {
        const int ky = tap / 3 - 1, kx = tap % 3 - 1;
        const int yy = y + ky;
        if (yy < 0 || yy > 63) continue;
        const int px = m0 + ln16 + kx;
        const bool valid = (px >= 0) && (px < 64);
        const bf16* wt = wf + tap * 16384;
        #pragma unroll
        for (int kc = 0; kc < 4; ++kc) {
            short8 a = {0, 0, 0, 0, 0, 0, 0, 0};
            if (valid)
                a = *(const short8*)(const void*)(xh + (((size_t)(b * 64 + yy) * 64 + px) * 128) + kc * 32 + kg * 8);
            const bf16* wb = wt + (kc * 8) * 512 + lane * 8;
            #pragma unroll
            for (int nt = 0; nt < 8; ++nt) {
                short8 bfrag = *(const short8*)(const void*)(wb + nt * 512);
                acc[nt] = __builtin_amdgcn_mfma_f32_16x16x32_bf16(a, bfrag, acc[nt], 0, 0, 0);
            }
        }
    }
    #pragma unroll
    for (int nt = 0; nt < 8; ++nt) {
        int c = nt * 16 + ln16;
        float g = gamma[c], be = beta[c];
        #pragma unroll
        for (int r = 0; r < 4; ++r)
            outL[m0 + kg * 4 + r][c] = f2b(siluf(g * acc[nt][r] + be));
    }
    __syncthreads();
    for (int idx = threadIdx.x; idx < 1024; idx += 256) {
        int px = idx >> 4, q = idx & 15;
        *(short8*)(void*)(h1h + ((size_t)br * 64 + px) * 128 + q * 8) =
            *(const short8*)(const void*)(&outL[px][q * 8]);
    }
}

// ---------------- fusion conv 3x3 (K=256 from xh16 + ph) + BN + SiLU -> NCHW fp32 ----------------
__global__ __launch_bounds__(256) void k_convf_mfma(
    const bf16* __restrict__ xh, const bf16* __restrict__ ph,
    const bf16* __restrict__ wf,
    const float* __restrict__ gamma, const float* __restrict__ beta,
    float* __restrict__ out)
{
    __shared__ float outF[64][129];
    const int br = blockIdx.x;
    const int b = br >> 6, y = br & 63;
    const int lane = threadIdx.x & 63, w = threadIdx.x >> 6;
    const int m0 = w * 16, kg = lane >> 4, ln16 = lane & 15;
    float4v acc[8];
    #pragma unroll
    for (int i = 0; i < 8; ++i) acc[i] = (float4v)0.f;
    #pragma unroll
    for (int tap = 0; tap < 9; ++tap) {
        const int ky = tap / 3 - 1, kx = tap % 3 - 1;
        const int yy = y + ky;
        if (yy < 0 || yy > 63) continue;
        const int px = m0 + ln16 + kx;
        const bool valid = (px >= 0) && (px < 64);
        const size_t rowoff = ((size_t)(b * 64 + yy) * 64 + px) * 128;
        const bf16* wt = wf + tap * 32768;
        #pragma unroll
        for (int kc = 0; kc < 8; ++kc) {
            const bf16* src = (kc < 4) ? xh : ph;
            short8 a = {0, 0, 0, 0, 0, 0, 0, 0};
            if (valid)
                a = *(const short8*)(const void*)(src + rowoff + (kc & 3) * 32 + kg * 8);
            const bf16* wb = wt + (kc * 8) * 512 + lane * 8;
            #pragma unroll
            for (int nt = 0; nt < 8; ++nt) {
                short8 bfrag = *(const short8*)(const void*)(wb + nt * 512);
                acc[nt] = __builtin_amdgcn_mfma_f32_16x16x32_bf16(a, bfrag, acc[nt], 0, 0, 0);
            }
        }
    }
    #pragma unroll
    for (int nt = 0; nt < 8; ++nt) {
        int c = nt * 16 + ln16;
        float g = gamma[c], be = beta[c];
        #pragma unroll
        for (int r = 0; r < 4; ++r)
            outF[m0 + kg * 4 + r][c] = siluf(g * acc[nt][r] + be);
    }
    __syncthreads();
    for (int idx = threadIdx.x; idx < 8192; idx += 256) {
        int oc = idx >> 6, xcol = idx & 63;
        out[(((size_t)b * 128 + oc) * 64 + y) * 64 + xcol] = outF[xcol][oc];
    }
}

// ---------------- patchify + 1x1 (128->192) via MFMA, NHWC input ----------------
__global__ __launch_bounds__(256) void k_patch1x1_mfma(
    const bf16* __restrict__ h1h, const bf16* __restrict__ wf, bf16* __restrict__ tok)
{
    __shared__ __align__(16) bf16 outL[64][200];
    const int br = blockIdx.x;
    const int b = br >> 6, y = br & 63;
    const int lane = threadIdx.x & 63, w = threadIdx.x >> 6;
    const int m0 = w * 16, kg = lane >> 4, ln16 = lane & 15;
    float4v acc[12];
    #pragma unroll
    for (int i = 0; i < 12; ++i) acc[i] = (float4v)0.f;
    #pragma unroll
    for (int kc = 0; kc < 4; ++kc) {
        short8 a = *(const short8*)(const void*)(h1h + ((size_t)br * 64 + m0 + ln16) * 128 + kc * 32 + kg * 8);
        const bf16* wb = wf + (kc * 12) * 512 + lane * 8;
        #pragma unroll
        for (int nt = 0; nt < 12; ++nt) {
            short8 bfrag = *(const short8*)(const void*)(wb + nt * 512);
            acc[nt] = __builtin_amdgcn_mfma_f32_16x16x32_bf16(a, bfrag, acc[nt], 0, 0, 0);
        }
    }
    #pragma unroll
    for (int nt = 0; nt < 12; ++nt) {
        #pragma unroll
        for (int r = 0; r < 4; ++r)
            outL[m0 + kg * 4 + r][nt * 16 + ln16] = f2b(acc[nt][r]);
    }
    __syncthreads();
    const int pab = (y & 7) * 8, npb = (y >> 3) * 8;
    for (int idx = threadIdx.x; idx < 1536; idx += 256) {
        int x = idx / 24, q = idx - x * 24;
        int row = (b * 64 + pab + (x & 7)) * 64 + npb + (x >> 3);
        *(short8*)(void*)(tok + (size_t)row * 192 + q * 8) =
            *(const short8*)(const void*)(&outL[x][q * 8]);
    }
}

// ---------------- gating ----------------
__global__ __launch_bounds__(256) void k_gate(
    const bf16* __restrict__ tok, const float* __restrict__ gate_w_all,
    const int* __restrict__ task, float* __restrict__ dense,
    float* __restrict__ part)
{
    __shared__ float gwL[768];
    for (int i = threadIdx.x; i < 768; i += 256) gwL[i] = gate_w_all[(size_t)task[0] * 768 + i];
    __syncthreads();
    const int r = blockIdx.x * 256 + threadIdx.x;
    const bf16* tb = tok + (size_t)r * 192;
    float L0 = 0.f, L1 = 0.f, L2 = 0.f, L3 = 0.f;
    for (int c4 = 0; c4 < 48; ++c4) {
        float xv[4]; ld4(tb + c4 * 4, xv);
        #pragma unroll
        for (int j = 0; j < 4; ++j) {
            int c = c4 * 4 + j;
            L0 += xv[j] * gwL[c*4+0]; L1 += xv[j] * gwL[c*4+1];
            L2 += xv[j] * gwL[c*4+2]; L3 += xv[j] * gwL[c*4+3];
        }
    }
    float m = fmaxf(fmaxf(L0, L1), fmaxf(L2, L3));
    float e0 = expf(L0 - m), e1 = expf(L1 - m), e2 = expf(L2 - m), e3 = expf(L3 - m);
    float s = e0 + e1 + e2 + e3;
    float p[4] = {e0 / s, e1 / s, e2 / s, e3 / s};
    int i1 = 0; float v1 = p[0];
    #pragma unroll
    for (int e = 1; e < 4; ++e) if (p[e] > v1) { v1 = p[e]; i1 = e; }
    int i2 = -1; float v2 = -1.f;
    #pragma unroll
    for (int e = 0; e < 4; ++e) if (e != i1 && p[e] > v2) { v2 = p[e]; i2 = e; }
    float gs = v1 + v2;
    float d[4] = {0.f, 0.f, 0.f, 0.f};
    d[i1] = v1 / gs; d[i2] = v2 / gs;
    ((float4*)dense)[r] = make_float4(d[0], d[1], d[2], d[3]);

    float vals[8] = {p[0], p[1], p[2], p[3],
                     d[0] > 0.f ? 1.f : 0.f, d[1] > 0.f ? 1.f : 0.f,
                     d[2] > 0.f ? 1.f : 0.f, d[3] > 0.f ? 1.f : 0.f};
    #pragma unroll
    for (int off = 32; off; off >>= 1)
        #pragma unroll
        for (int i = 0; i < 8; ++i) vals[i] += __shfl_down(vals[i], off);
    __shared__ float sm[4][8];
    const int lane = threadIdx.x & 63, wv = threadIdx.x >> 6;
    if (lane == 0)
        #pragma unroll
        for (int i = 0; i < 8; ++i) sm[wv][i] = vals[i];
    __syncthreads();
    if (threadIdx.x < 8)
        part[blockIdx.x * 8 + threadIdx.x] =
            sm[0][threadIdx.x] + sm[1][threadIdx.x] + sm[2][threadIdx.x] + sm[3][threadIdx.x];
}

// ---------------- MoE via MFMA ----------------
template <typename TT>
__global__ __launch_bounds__(256) void k_moe_mfma(
    const bf16* __restrict__ tok, const float* __restrict__ dense,
    const bf16* __restrict__ w1f, const float* __restrict__ b1,
    const bf16* __restrict__ w2f, const float* __restrict__ b2,
    TT* __restrict__ tout)
{
    __shared__ __align__(16) bf16 hL[64][200];
    const int rbase = blockIdx.x * 64;
    const int lane = threadIdx.x & 63, w = threadIdx.x >> 6;
    const int m0 = w * 16;
    const int kg = lane >> 4;
    const int ln16 = lane & 15;
    const int arow = rbase + m0 + ln16;

    float4v accT[12];
    #pragma unroll
    for (int i = 0; i < 12; ++i) accT[i] = (float4v)0.f;

    for (int e = 0; e < 4; ++e) {
        float g4[4];
        #pragma unroll
        for (int r = 0; r < 4; ++r)
            g4[r] = dense[(size_t)(rbase + m0 + kg * 4 + r) * 4 + e];

        float4v acc[12];
        #pragma unroll
        for (int i = 0; i < 12; ++i) acc[i] = (float4v)0.f;
        for (int kc = 0; kc < 6; ++kc) {
            short8 a = *(const short8*)(const void*)(tok + (size_t)arow * 192 + kc * 32 + kg * 8);
            const bf16* wb = w1f + (size_t)e * 36864 + (kc * 12) * 512 + lane * 8;
            #pragma unroll
            for (int nt = 0; nt < 12; ++nt) {
                short8 bfrag = *(const short8*)(const void*)(wb + nt * 512);
                acc[nt] = __builtin_amdgcn_mfma_f32_16x16x32_bf16(a, bfrag, acc[nt], 0, 0, 0);
            }
        }
        #pragma unroll
        for (int nt = 0; nt < 12; ++nt) {
            int c = nt * 16 + ln16;
            float bias = b1[e * 192 + c];
            #pragma unroll
            for (int r = 0; r < 4; ++r)
                hL[m0 + kg * 4 + r][c] = f2b(geluf(acc[nt][r] + bias));
        }
        __syncthreads();
        #pragma unroll
        for (int i = 0; i < 12; ++i) acc[i] = (float4v)0.f;
        for (int kc = 0; kc < 6; ++kc) {
            short8 a = *(const short8*)(const void*)(&hL[m0 + ln16][kc * 32 + kg * 8]);
            const bf16* wb = w2f + (size_t)e * 36864 + (kc * 12) * 512 + lane * 8;
            #pragma unroll
            for (int nt = 0; nt < 12; ++nt) {
                short8 bfrag = *(const short8*)(const void*)(wb + nt * 512);
                acc[nt] = __builtin_amdgcn_mfma_f32_16x16x32_bf16(a, bfrag, acc[nt], 0, 0, 0);
            }
        }
        #pragma unroll
        for (int nt = 0; nt < 12; ++nt) {
            int c = nt * 16 + ln16;
            float bias = b2[e * 192 + c];
            #pragma unroll
            for (int r = 0; r < 4; ++r)
                accT[nt][r] += g4[r] * (acc[nt][r] + bias);
        }
        __syncthreads();
    }
    #pragma unroll
    for (int nt = 0; nt < 12; ++nt) {
        int c = nt * 16 + ln16;
        #pragma unroll
        for (int r = 0; r < 4; ++r)
            stv(&tout[(size_t)(rbase + m0 + kg * 4 + r) * 192 + c], accT[nt][r]);
    }
}

// ---------------- proj via MFMA ----------------
template <typename TT>
__global__ __launch_bounds__(256) void k_proj_mfma(
    const bf16* __restrict__ y2, const bf16* __restrict__ pwf,
    const float* __restrict__ pb, TT* __restrict__ t)
{
    const int rbase = blockIdx.x * 64;
    const int lane = threadIdx.x & 63, w = threadIdx.x >> 6;
    const int m0 = w * 16;
    const int kg = lane >> 4, ln16 = lane & 15;
    const int arow = rbase + m0 + ln16;
    float4v acc[12];
    #pragma unroll
    for (int i = 0; i < 12; ++i) acc[i] = (float4v)0.f;
    for (int kc = 0; kc < 6; ++kc) {
        short8 a = *(const short8*)(const void*)(y2 + (size_t)arow * 192 + kc * 32 + kg * 8);
        const bf16* wb = pwf + (kc * 12) * 512 + lane * 8;
        #pragma unroll
        for (int nt = 0; nt < 12; ++nt) {
            short8 bfrag = *(const short8*)(const void*)(wb + nt * 512);
            acc[nt] = __builtin_amdgcn_mfma_f32_16x16x32_bf16(a, bfrag, acc[nt], 0, 0, 0);
        }
    }
    #pragma unroll
    for (int nt = 0; nt < 12; ++nt) {
        int c = nt * 16 + ln16;
        float bias = pb[c];
        #pragma unroll
        for (int r = 0; r < 4; ++r) {
            TT* p = &t[(size_t)(rbase + m0 + kg * 4 + r) * 192 + c];
            stv(p, ldv(p) + acc[nt][r] + bias);
        }
    }
}

// ---------------- fused LN2 + MLP via MFMA ----------------
template <typename TT>
__global__ __launch_bounds__(256) void k_mlp_mfma(
    TT* __restrict__ t, const float* __restrict__ lg, const float* __restrict__ lb,
    const bf16* __restrict__ w1f, const float* __restrict__ b1,
    const bf16* __restrict__ w2f, const float* __restrict__ b2)
{
    __shared__ __align__(16) bf16 yL[64][200];
    __shared__ __align__(16) bf16 hL[64][200];
    const int rbase = blockIdx.x * 64;
    const int tid = threadIdx.x;
    {
        const int row = tid >> 2, qg = tid & 3;
        float v[48];
        const TT* tr_ = t + (size_t)(rbase + row) * 192 + qg * 48;
        float s = 0.f, sq = 0.f;
        #pragma unroll
        for (int i = 0; i < 12; ++i) {
            float tmp[4]; ld4(tr_ + i * 4, tmp);
            #pragma unroll
            for (int j = 0; j < 4; ++j) { v[i*4+j] = tmp[j]; s += tmp[j]; sq += tmp[j]*tmp[j]; }
        }
        s  += __shfl_xor(s, 1);  s  += __shfl_xor(s, 2);
        sq += __shfl_xor(sq, 1); sq += __shfl_xor(sq, 2);
        float m = s * (1.f/192.f), var = sq * (1.f/192.f) - m*m;
        float rs = rsqrtf(var + 1e-5f);
        #pragma unroll
        for (int i = 0; i < 48; ++i) {
            int d = qg * 48 + i;
            yL[row][d] = f2b((v[i] - m) * rs * lg[d] + lb[d]);
        }
    }
    __syncthreads();
    const int lane = tid & 63, w = tid >> 6;
    const int m0 = w * 16;
    const int kg = lane >> 4, ln16 = lane & 15;
    float4v accT[12];
    #pragma unroll
    for (int i = 0; i < 12; ++i) accT[i] = (float4v)0.f;
    for (int ch = 0; ch < 2; ++ch) {
        float4v acc[12];
        #pragma unroll
        for (int i = 0; i < 12; ++i) acc[i] = (float4v)0.f;
        for (int kc = 0; kc < 6; ++kc) {
            short8 a = *(const short8*)(const void*)(&yL[m0 + ln16][kc * 32 + kg * 8]);
            const bf16* wb = w1f + (size_t)(kc * 24 + ch * 12) * 512 + lane * 8;
            #pragma unroll
            for (int nt = 0; nt < 12; ++nt) {
                short8 bfrag = *(const short8*)(const void*)(wb + nt * 512);
                acc[nt] = __builtin_amdgcn_mfma_f32_16x16x32_bf16(a, bfrag, acc[nt], 0, 0, 0);
            }
        }
        #pragma unroll
        for (int nt = 0; nt < 12; ++nt) {
            int c = nt * 16 + ln16;
            float bias = b1[ch * 192 + c];
            #pragma unroll
            for (int r = 0; r < 4; ++r)
                hL[m0 + kg * 4 + r][c] = f2b(geluf(acc[nt][r] + bias));
        }
        __syncthreads();
        for (int kc = 0; kc < 6; ++kc) {
            short8 a = *(const short8*)(const void*)(&hL[m0 + ln16][kc * 32 + kg * 8]);
            const bf16* wb = w2f + (size_t)((ch * 6 + kc) * 12) * 512 + lane * 8;
            #pragma unroll
            for (int nt = 0; nt < 12; ++nt) {
                short8 bfrag = *(const short8*)(const void*)(wb + nt * 512);
                accT[nt] = __builtin_amdgcn_mfma_f32_16x16x32_bf16(a, bfrag, accT[nt], 0, 0, 0);
            }
        }
        __syncthreads();
    }
    #pragma unroll
    for (int nt = 0; nt < 12; ++nt) {
        int c = nt * 16 + ln16;
        float bias = b2[c];
        #pragma unroll
        for (int r = 0; r < 4; ++r) {
            TT* p = &t[(size_t)(rbase + m0 + kg * 4 + r) * 192 + c];
            stv(p, ldv(p) + accT[nt][r] + bias);
        }
    }
}

// ---------------- fused LN1 + attention per (seq, head) ----------------
template <typename TT>
__global__ __launch_bounds__(256) void k_attn(
    const TT* __restrict__ t, const float* __restrict__ lg, const float* __restrict__ lb,
    const float* __restrict__ qkvw, const float* __restrict__ qkvb, bf16* __restrict__ y2)
{
    const int n = blockIdx.x, h = blockIdx.y;
    __shared__ float yL[64][193];
    __shared__ float qL[64][49], kL[64][49], vL[64][49];
    __shared__ float pL[64][65];
    for (int idx = threadIdx.x * 4; idx < 64 * 192; idx += 1024) {
        float tmp[4]; ld4(t + (size_t)n * 12288 + idx, tmp);
        int r = idx / 192, d = idx % 192;
        yL[r][d] = tmp[0]; yL[r][d+1] = tmp[1]; yL[r][d+2] = tmp[2]; yL[r][d+3] = tmp[3];
    }
    __syncthreads();
    ln_rows193(yL, lg, lb, threadIdx.x);
    __syncthreads();
    const int lane = threadIdx.x & 63, wv = threadIdx.x >> 6;
    const float scale = rsqrtf(48.f);
    {
        int cols[9], whichs[9], dqs[9];
        #pragma unroll
        for (int q = 0; q < 9; ++q) {
            int qq = wv * 9 + q;
            whichs[q] = qq / 12; dqs[q] = (qq % 12) * 4;
            cols[q] = whichs[q] * 192 + h * 48 + dqs[q];
        }
        float a[36];
        #pragma unroll
        for (int q = 0; q < 9; ++q) {
            float bq[4]; ld4(qkvb + cols[q], bq);
            a[q*4+0] = bq[0]; a[q*4+1] = bq[1]; a[q*4+2] = bq[2]; a[q*4+3] = bq[3];
        }
        for (int k = 0; k < 192; ++k) {
            float x = yL[lane][k];
            const float* wr = qkvw + (size_t)k * 576;
            #pragma unroll
            for (int q = 0; q < 9; ++q) {
                float wq[4]; ld4(wr + cols[q], wq);
                a[q*4+0] += x * wq[0]; a[q*4+1] += x * wq[1];
                a[q*4+2] += x * wq[2]; a[q*4+3] += x * wq[3];
            }
        }
        #pragma unroll
        for (int q = 0; q < 9; ++q) {
            int wch = whichs[q], dq = dqs[q];
            if (wch == 0) {
                #pragma unroll
                for (int u = 0; u < 4; ++u) qL[lane][dq + u] = a[q*4+u] * scale;
            } else if (wch == 1) {
                #pragma unroll
                for (int u = 0; u < 4; ++u) kL[lane][dq + u] = a[q*4+u];
            } else {
                #pragma unroll
                for (int u = 0; u < 4; ++u) vL[lane][dq + u] = a[q*4+u];
            }
        }
    }
    __syncthreads();
    {
        const int i = threadIdx.x >> 2, jg = threadIdx.x & 3;
        float sc[16];
        #pragma unroll
        for (int jj = 0; jj < 16; ++jj) {
            int j = jg * 16 + jj;
            float sv = 0.f;
            #pragma unroll 12
            for (int d = 0; d < 48; ++d) sv += qL[i][d] * kL[j][d];
            sc[jj] = sv;
        }
        float m = sc[0];
        #pragma unroll
        for (int jj = 1; jj < 16; ++jj) m = fmaxf(m, sc[jj]);
        m = fmaxf(m, __shfl_xor(m, 1)); m = fmaxf(m, __shfl_xor(m, 2));
        float ssum = 0.f;
        #pragma unroll
        for (int jj = 0; jj < 16; ++jj) { sc[jj] = expf(sc[jj] - m); ssum += sc[jj]; }
        ssum += __shfl_xor(ssum, 1); ssum += __shfl_xor(ssum, 2);
        float inv = 1.f / ssum;
        #pragma unroll
        for (int jj = 0; jj < 16; ++jj) pL[i][jg * 16 + jj] = sc[jj] * inv;
    }
    __syncthreads();
    {
        float oacc[12];
        #pragma unroll
        for (int u = 0; u < 12; ++u) oacc[u] = 0.f;
        for (int j = 0; j < 64; ++j) {
            float pv = pL[lane][j];
            #pragma unroll
            for (int u = 0; u < 12; ++u) oacc[u] += pv * vL[j][wv * 12 + u];
        }
        #pragma unroll
        for (int u = 0; u < 12; ++u) kL[lane][wv * 12 + u] = oacc[u];
    }
    __syncthreads();
    for (int idx = threadIdx.x; idx < 64 * 48; idx += 256) {
        int s = idx / 48, d = idx % 48;
        y2[((size_t)n * 64 + s) * 192 + h * 48 + d] = f2b(kL[s][d]);
    }
}

// ---------------- fused final LN + unpatchify + 1x1 (192->128) + BN + SiLU -> ph NHWC bf16 ----------------
template <typename TT>
__global__ __launch_bounds__(256) void k_unpatch(
    const TT* __restrict__ t, const float* __restrict__ ng, const float* __restrict__ nb,
    const float* __restrict__ wp, const float* __restrict__ gamma, const float* __restrict__ beta,
    bf16* __restrict__ ph)
{
    const int np = blockIdx.x, b = blockIdx.y;
    const int pi = np >> 3, pj = np & 7;
    __shared__ float tL[64][193];
    __shared__ float oL[64][129];
    for (int idx = threadIdx.x * 4; idx < 64 * 192; idx += 1024) {
        int pa = idx / 192, d = idx % 192;
        float tmp[4]; ld4(t + ((size_t)(b * 64 + pa) * 64 + np) * 192 + d, tmp);
        tL[pa][d] = tmp[0]; tL[pa][d+1] = tmp[1]; tL[pa][d+2] = tmp[2]; tL[pa][d+3] = tmp[3];
    }
    __syncthreads();
    ln_rows193(tL, ng, nb, threadIdx.x);
    __syncthreads();
    const int lane = threadIdx.x & 63, wv = threadIdx.x >> 6;
    for (int k = 0; k < 32; ++k) {
        int o = wv * 32 + k;
        float acc = 0.f;
        for (int d4 = 0; d4 < 48; ++d4) {
            float wq[4]; ld4(wp + (size_t)o * 192 + d4 * 4, wq);
            acc += tL[lane][d4*4+0] * wq[0] + tL[lane][d4*4+1] * wq[1]
                 + tL[lane][d4*4+2] * wq[2] + tL[lane][d4*4+3] * wq[3];
        }
        float v = gamma[o] * acc + beta[o];
        oL[lane][o] = siluf(v);
    }
    __syncthreads();
    for (int idx = threadIdx.x; idx < 1024; idx += 256) {
        int pa = idx >> 4, q = idx & 15;
        int yy = pi * 8 + (pa >> 3), xx = pj * 8 + (pa & 7);
        bf16 tmp8[8];
        #pragma unroll
        for (int j = 0; j < 8; ++j) tmp8[j] = f2b(oL[pa][q * 8 + j]);
        *(short8*)(void*)(ph + ((size_t)(b * 64 + yy) * 64 + xx) * 128 + q * 8) =
            *(const short8*)(const void*)tmp8;
    }
}

// ---------------- moe loss ----------------
__global__ void k_loss(const float* __restrict__ part, float* __restrict__ out)
{
    if (threadIdx.x == 0 && blockIdx.x == 0) {
        float L = 0.f;
        for (int e = 0; e < 4; ++e) {
            float imp = 0.f, ld = 0.f;
            for (int i = 0; i < 512; ++i) { imp += part[i * 8 + e]; ld += part[i * 8 + 4 + e]; }
            L += (imp / 131072.f) * (ld / 131072.f);
        }
        out[16777216] = 4.f * L;
    }
}

template <typename TT>
static void run_pipeline(const float* x, const float* w_kxk, const float* bn1_g, const float* bn1_b,
                         const float* w_1x1, const float* gate_w,
                         const float* moe_w1, const float* moe_b1, const float* moe_w2, const float* moe_b2,
                         const float* ln1_g, const float* ln1_b, const float* qkv_w, const float* qkv_b,
                         const float* proj_w, const float* proj_b, const float* ln2_g, const float* ln2_b,
                         const float* fc1_w, const float* fc1_b, const float* fc2_w, const float* fc2_b,
                         const float* nrm_g, const float* nrm_b, const float* w_proj, const float* bn2_g,
                         const float* bn2_b, const float* w_fus, const float* bn3_g, const float* bn3_b,
                         const int* task, float* out, bf16* xh, bf16* tok, TT* t, float* dense, float* part,
                         bf16* wprep, hipStream_t stream)
{
    // prep fragments
    bf16* moeW1f = wprep;                 // 147456
    bf16* moeW2f = wprep + 147456;        // 147456
    bf16* fc1f   = wprep + 294912;        // 147456
    bf16* fc2f   = wprep + 442368;        // 147456
    bf16* projWf = wprep + 589824;        // 73728
    bf16* w1x1f  = wprep + 663552;        // 24576
    bf16* convW1f= wprep + 688128;        // 147456
    bf16* convWFf= wprep + 835584;        // 294912  -> total 1130496 elems
    hipLaunchKernelGGL(k_prep, dim3(576), dim3(256), 0, stream, moe_w1, moeW1f, 192, 192, 4);
    hipLaunchKernelGGL(k_prep, dim3(576), dim3(256), 0, stream, moe_w2, moeW2f, 192, 192, 4);
    hipLaunchKernelGGL(k_prep, dim3(576), dim3(256), 0, stream, fc1_w, fc1f, 192, 384, 2);
    hipLaunchKernelGGL(k_prep, dim3(576), dim3(256), 0, stream, fc2_w, fc2f, 384, 192, 2);
    hipLaunchKernelGGL(k_prep, dim3(288), dim3(256), 0, stream, proj_w, projWf, 192, 192, 2);
    hipLaunchKernelGGL(k_prep_t, dim3(96), dim3(256), 0, stream, w_1x1, w1x1f, 192, 128);
    hipLaunchKernelGGL(k_prep_conv, dim3(576), dim3(256), 0, stream, w_kxk, convW1f, 128, 128);
    hipLaunchKernelGGL(k_prep_conv, dim3(1152), dim3(256), 0, stream, w_fus, convWFf, 256, 128);

    bf16* h1h = (bf16*)out;  // d_out used as NHWC bf16 scratch; fully rewritten by final conv
    hipLaunchKernelGGL(k_tohwc, dim3(2048), dim3(256), 0, stream, x, xh);
    hipLaunchKernelGGL(k_conv1_mfma, dim3(2048), dim3(256), 0, stream, xh, convW1f, bn1_g, bn1_b, h1h);
    hipLaunchKernelGGL(k_patch1x1_mfma, dim3(2048), dim3(256), 0, stream, h1h, w1x1f, tok);
    hipLaunchKernelGGL(k_gate, dim3(512), dim3(256), 0, stream, tok, gate_w, task, dense, part);
    hipLaunchKernelGGL(k_moe_mfma<TT>, dim3(2048), dim3(256), 0, stream,
                       tok, dense, moeW1f, moe_b1, moeW2f, moe_b2, t);
    bf16* y2 = tok;  // tok dead after MoE
    for (int l = 0; l < 2; ++l) {
        hipLaunchKernelGGL(k_attn<TT>, dim3(2048, 4), dim3(256), 0, stream,
                           t, ln1_g + l * 192, ln1_b + l * 192,
                           qkv_w + (size_t)l * 110592, qkv_b + l * 576, y2);
        hipLaunchKernelGGL(k_proj_mfma<TT>, dim3(2048), dim3(256), 0, stream,
                           y2, projWf + (size_t)l * 36864, proj_b + l * 192, t);
        hipLaunchKernelGGL(k_mlp_mfma<TT>, dim3(2048), dim3(256), 0, stream,
                           t, ln2_g + l * 192, ln2_b + l * 192,
                           fc1f + (size_t)l * 73728, fc1_b + l * 384,
                           fc2f + (size_t)l * 73728, fc2_b + l * 192);
    }
    bf16* ph = tok;  // y2 dead after last proj; reuse region as NHWC p
    hipLaunchKernelGGL(k_unpatch<TT>, dim3(64, 32), dim3(256), 0, stream,
                       t, nrm_g, nrm_b, w_proj, bn2_g, bn2_b, ph);
    hipLaunchKernelGGL(k_convf_mfma, dim3(2048), dim3(256), 0, stream,
                       xh, ph, convWFf, bn3_g, bn3_b, out);
    hipLaunchKernelGGL(k_loss, dim3(1), dim3(64), 0, stream, part, out);
}

extern "C" void kernel_launch(void* const* d_in, const int* in_sizes, int n_in,
                              void* d_out, int out_size, void* d_ws, size_t ws_size,
                              hipStream_t stream) {
    const float* x      = (const float*)d_in[0];
    const float* w_kxk  = (const float*)d_in[1];
    const float* bn1_g  = (const float*)d_in[2];
    const float* bn1_b  = (const float*)d_in[3];
    const float* w_1x1  = (const float*)d_in[4];
    const float* gate_w = (const float*)d_in[5];
    const float* moe_w1 = (const float*)d_in[6];
    const float* moe_b1 = (const float*)d_in[7];
    const float* moe_w2 = (const float*)d_in[8];
    const float* moe_b2 = (const float*)d_in[9];
    const float* ln1_g  = (const float*)d_in[10];
    const float* ln1_b  = (const float*)d_in[11];
    const float* qkv_w  = (const float*)d_in[12];
    const float* qkv_b  = (const float*)d_in[13];
    const float* proj_w = (const float*)d_in[14];
    const float* proj_b = (const float*)d_in[15];
    const float* ln2_g  = (const float*)d_in[16];
    const float* ln2_b  = (const float*)d_in[17];
    const float* fc1_w  = (const float*)d_in[18];
    const float* fc1_b  = (const float*)d_in[19];
    const float* fc2_w  = (const float*)d_in[20];
    const float* fc2_b  = (const float*)d_in[21];
    const float* nrm_g  = (const float*)d_in[22];
    const float* nrm_b  = (const float*)d_in[23];
    const float* w_proj = (const float*)d_in[24];
    const float* bn2_g  = (const float*)d_in[25];
    const float* bn2_b  = (const float*)d_in[26];
    const float* w_fus  = (const float*)d_in[27];
    const float* bn3_g  = (const float*)d_in[28];
    const float* bn3_b  = (const float*)d_in[29];
    const int*  task    = (const int*)d_in[30];

    char* wsb = (char*)d_ws;
    const size_t XHB   = 33554432ull;    // NHWC bf16 x
    const size_t TOKB  = 50331648ull;    // tok / y2 / ph region
    const size_t T32B  = 100663296ull;
    const size_t T16B  = 50331648ull;
    const size_t DENB  = 2097152ull;
    const size_t PARB  = 16384ull;
    const size_t WPB   = 2260992ull;
    bf16* xh  = (bf16*)wsb;
    bf16* tok = (bf16*)(wsb + XHB);
    float* out = (float*)d_out;

    if (ws_size >= XHB + TOKB + T32B + DENB + PARB + WPB) {
        float* t     = (float*)(wsb + XHB + TOKB);
        float* dense = (float*)(wsb + XHB + TOKB + T32B);
        float* part  = (float*)(wsb + XHB + TOKB + T32B + DENB);
        bf16*  wprep = (bf16*)(wsb + XHB + TOKB + T32B + DENB + PARB);
        run_pipeline<float>(x, w_kxk, bn1_g, bn1_b, w_1x1, gate_w, moe_w1, moe_b1, moe_w2, moe_b2,
                            ln1_g, ln1_b, qkv_w, qkv_b, proj_w, proj_b, ln2_g, ln2_b,
                            fc1_w, fc1_b, fc2_w, fc2_b, nrm_g, nrm_b, w_proj, bn2_g, bn2_b,
                            w_fus, bn3_g, bn3_b, task, out, xh, tok, t, dense, part, wprep, stream);
    } else {
        bf16*  t     = (bf16*)(wsb + XHB + TOKB);
        float* dense = (float*)(wsb + XHB + TOKB + T16B);
        float* part  = (float*)(wsb + XHB + TOKB + T16B + DENB);
        bf16*  wprep = (bf16*)(wsb + XHB + TOKB + T16B + DENB + PARB);
        run_pipeline<bf16>(x, w_kxk, bn1_g, bn1_b, w_1x1, gate_w, moe_w1, moe_b1, moe_w2, moe_b2,
                           ln1_g, ln1_b, qkv_w, qkv_b, proj_w, proj_b, ln2_g, ln2_b,
                           fc1_w, fc1_b, fc2_w, fc2_b, nrm_g, nrm_b, w_proj, bn2_g, bn2_b,
                           w_fus, bn3_g, bn3_b, task, out, xh, tok, t, dense, part, wprep, stream);
    }
}

// Round 6
// 2000.001 us; speedup vs baseline: 10.7173x; 3.2262x over previous
//
#include <hip/hip_runtime.h>
#include <hip/hip_bf16.h>
#include <cmath>

typedef __hip_bfloat16 bf16;
typedef __attribute__((ext_vector_type(8))) short short8;
typedef __attribute__((ext_vector_type(4))) float float4v;

__device__ __forceinline__ float b2f(bf16 v) { return __bfloat162float(v); }
__device__ __forceinline__ bf16  f2b(float v) { return __float2bfloat16(v); }
__device__ __forceinline__ float bfr(unsigned int u) { union { float f; unsigned int i; } c; c.i = u << 16; return c.f; }
__device__ __forceinline__ void ld4(const float* p, float* o) {
    float4 q = *(const float4*)p; o[0]=q.x; o[1]=q.y; o[2]=q.z; o[3]=q.w;
}
__device__ __forceinline__ void ld4(const bf16* p, float* o) {
    const uint2 q = *(const uint2*)p;
    o[0] = bfr(q.x & 0xffffu); o[1] = bfr(q.x >> 16);
    o[2] = bfr(q.y & 0xffffu); o[3] = bfr(q.y >> 16);
}
template <typename T>
__device__ __forceinline__ void ld8(const T* p, float* o) { ld4(p, o); ld4(p + 4, o + 4); }
__device__ __forceinline__ float ldv(const float* p) { return *p; }
__device__ __forceinline__ float ldv(const bf16* p)  { return b2f(*p); }
__device__ __forceinline__ void  stv(float* p, float v) { *p = v; }
__device__ __forceinline__ void  stv(bf16* p, float v)  { *p = f2b(v); }

__device__ __forceinline__ float siluf(float x) { return x / (1.f + expf(-x)); }
__device__ __forceinline__ float geluf(float x) { return 0.5f * x * (1.f + erff(x * 0.70710678118654752f)); }

// LN of 64 rows (pitch 193) held in LDS; 4 threads/row; params fp32.
__device__ __forceinline__ void ln_rows193(float (*L)[193], const float* g, const float* b, int tid) {
    const int i = tid >> 2, jg = tid & 3;
    float s = 0.f, sq = 0.f;
    #pragma unroll
    for (int k2 = 0; k2 < 48; ++k2) { float v = L[i][jg * 48 + k2]; s += v; sq += v * v; }
    s  += __shfl_xor(s, 1);  s  += __shfl_xor(s, 2);
    sq += __shfl_xor(sq, 1); sq += __shfl_xor(sq, 2);
    const float m  = s * (1.f / 192.f);
    const float var = sq * (1.f / 192.f) - m * m;
    const float rs = rsqrtf(var + 1e-5f);
    #pragma unroll
    for (int k2 = 0; k2 < 48; ++k2) {
        int d = jg * 48 + k2;
        L[i][d] = (L[i][d] - m) * rs * g[d] + b[d];
    }
}

// ---------------- weight prep: fp32 [k][n] -> bf16 MFMA-fragment order ----------------
__global__ __launch_bounds__(256) void k_prep(
    const float* __restrict__ src, bf16* __restrict__ dst, int K, int N, int nmat)
{
    const int per = K * N;
    const int total = per * nmat;
    const int NT = N >> 4;
    for (int idx = blockIdx.x * 256 + threadIdx.x; idx < total; idx += gridDim.x * 256) {
        int m = idx / per;
        int rem = idx - m * per;
        int k = rem / N, n = rem - k * N;
        int off = ((k >> 5) * NT + (n >> 4)) * 512 + (((k >> 3) & 3) * 16 + (n & 15)) * 8 + (k & 7);
        dst[(size_t)m * per + off] = f2b(src[idx]);
    }
}

// src is [N][K] (row n, col k) -> fragged [K][N]
__global__ __launch_bounds__(256) void k_prep_t(
    const float* __restrict__ src, bf16* __restrict__ dst, int N, int K)
{
    const int total = N * K;
    const int NT = N >> 4;
    for (int idx = blockIdx.x * 256 + threadIdx.x; idx < total; idx += gridDim.x * 256) {
        int n = idx / K, k = idx - n * K;
        int off = ((k >> 5) * NT + (n >> 4)) * 512 + (((k >> 3) & 3) * 16 + (n & 15)) * 8 + (k & 7);
        dst[off] = f2b(src[idx]);
    }
}

// conv weights OIHW (Cout,Cin,3,3) -> 9 fragged [Cin][Cout] matrices (tap-major)
__global__ __launch_bounds__(256) void k_prep_conv(
    const float* __restrict__ src, bf16* __restrict__ dst, int Cin, int Cout)
{
    const int total = Cout * Cin * 9;
    const int NT = Cout >> 4;
    for (int idx = blockIdx.x * 256 + threadIdx.x; idx < total; idx += gridDim.x * 256) {
        int oc = idx / (Cin * 9);
        int rem = idx - oc * (Cin * 9);
        int ic = rem / 9, tap = rem - ic * 9;
        int off = tap * (Cin * Cout)
                + ((ic >> 5) * NT + (oc >> 4)) * 512
                + (((ic >> 3) & 3) * 16 + (oc & 15)) * 8 + (ic & 7);
        dst[off] = f2b(src[idx]);
    }
}

// ---------------- NCHW fp32 -> NHWC bf16 (one (b,y) row per block) ----------------
__global__ __launch_bounds__(256) void k_tohwc(const float* __restrict__ x, bf16* __restrict__ xh)
{
    __shared__ bf16 L[64][136];
    const int br = blockIdx.x;           // b*64 + y
    const int b = br >> 6, y = br & 63;
    for (int idx = threadIdx.x; idx < 8192; idx += 256) {
        int ch = idx >> 6, xc = idx & 63;
        L[xc][ch] = f2b(x[(((size_t)b * 128 + ch) * 64 + y) * 64 + xc]);
    }
    __syncthreads();
    for (int idx = threadIdx.x; idx < 1024; idx += 256) {
        int px = idx >> 4, q = idx & 15;
        *(short8*)(void*)(xh + ((size_t)br * 64 + px) * 128 + q * 8) =
            *(const short8*)(const void*)(&L[px][q * 8]);
    }
}

// ---------------- conv1 3x3 via MFMA (implicit GEMM, NHWC bf16 in/out) + BN + SiLU ----------------
__global__ __launch_bounds__(256) void k_conv1_mfma(
    const bf16* __restrict__ xh, const bf16* __restrict__ wf,
    const float* __restrict__ gamma, const float* __restrict__ beta,
    bf16* __restrict__ h1h)
{
    __shared__ __align__(16) bf16 outL[64][136];
    const int br = blockIdx.x;
    const int b = br >> 6, y = br & 63;
    const int lane = threadIdx.x & 63, w = threadIdx.x >> 6;
    const int m0 = w * 16, kg = lane >> 4, ln16 = lane & 15;
    float4v acc[8];
    #pragma unroll
    for (int i = 0; i < 8; ++i) acc[i] = (float4v)0.f;
    #pragma unroll
    for (int tap = 0; tap < 9; ++tap) {
        const int ky = tap / 3 - 1, kx = tap % 3 - 1;
        const int yy = y + ky;
        if (yy < 0 || yy > 63) continue;
        const int px = m0 + ln16 + kx;
        const bool valid = (px >= 0) && (px < 64);
        const bf16* wt = wf + tap * 16384;
        #pragma unroll
        for (int kc = 0; kc < 4; ++kc) {
            short8 a = {0, 0, 0, 0, 0, 0, 0, 0};
            if (valid)
                a = *(const short8*)(const void*)(xh + (((size_t)(b * 64 + yy) * 64 + px) * 128) + kc * 32 + kg * 8);
            const bf16* wb = wt + (kc * 8) * 512 + lane * 8;
            #pragma unroll
            for (int nt = 0; nt < 8; ++nt) {
                short8 bfrag = *(const short8*)(const void*)(wb + nt * 512);
                acc[nt] = __builtin_amdgcn_mfma_f32_16x16x32_bf16(a, bfrag, acc[nt], 0, 0, 0);
            }
        }
    }
    #pragma unroll
    for (int nt = 0; nt < 8; ++nt) {
        int c = nt * 16 + ln16;
        float g = gamma[c], be = beta[c];
        #pragma unroll
        for (int r = 0; r < 4; ++r)
            outL[m0 + kg * 4 + r][c] = f2b(siluf(g * acc[nt][r] + be));
    }
    __syncthreads();
    for (int idx = threadIdx.x; idx < 1024; idx += 256) {
        int px = idx >> 4, q = idx & 15;
        *(short8*)(void*)(h1h + ((size_t)br * 64 + px) * 128 + q * 8) =
            *(const short8*)(const void*)(&outL[px][q * 8]);
    }
}

// ---------------- fusion conv 3x3 (K=256 from xh + ph) + BN + SiLU -> NCHW fp32 ----------------
__global__ __launch_bounds__(256) void k_convf_mfma(
    const bf16* __restrict__ xh, const bf16* __restrict__ ph,
    const bf16* __restrict__ wf,
    const float* __restrict__ gamma, const float* __restrict__ beta,
    float* __restrict__ out)
{
    __shared__ float outF[64][129];
    const int br = blockIdx.x;
    const int b = br >> 6, y = br & 63;
    const int lane = threadIdx.x & 63, w = threadIdx.x >> 6;
    const int m0 = w * 16, kg = lane >> 4, ln16 = lane & 15;
    float4v acc[8];
    #pragma unroll
    for (int i = 0; i < 8; ++i) acc[i] = (float4v)0.f;
    #pragma unroll
    for (int tap = 0; tap < 9; ++tap) {
        const int ky = tap / 3 - 1, kx = tap % 3 - 1;
        const int yy = y + ky;
        if (yy < 0 || yy > 63) continue;
        const int px = m0 + ln16 + kx;
        const bool valid = (px >= 0) && (px < 64);
        const size_t rowoff = ((size_t)(b * 64 + yy) * 64 + px) * 128;
        const bf16* wt = wf + tap * 32768;
        #pragma unroll
        for (int kc = 0; kc < 8; ++kc) {
            const bf16* src = (kc < 4) ? xh : ph;
            short8 a = {0, 0, 0, 0, 0, 0, 0, 0};
            if (valid)
                a = *(const short8*)(const void*)(src + rowoff + (kc & 3) * 32 + kg * 8);
            const bf16* wb = wt + (kc * 8) * 512 + lane * 8;
            #pragma unroll
            for (int nt = 0; nt < 8; ++nt) {
                short8 bfrag = *(const short8*)(const void*)(wb + nt * 512);
                acc[nt] = __builtin_amdgcn_mfma_f32_16x16x32_bf16(a, bfrag, acc[nt], 0, 0, 0);
            }
        }
    }
    #pragma unroll
    for (int nt = 0; nt < 8; ++nt) {
        int c = nt * 16 + ln16;
        float g = gamma[c], be = beta[c];
        #pragma unroll
        for (int r = 0; r < 4; ++r)
            outF[m0 + kg * 4 + r][c] = siluf(g * acc[nt][r] + be);
    }
    __syncthreads();
    for (int idx = threadIdx.x; idx < 8192; idx += 256) {
        int oc = idx >> 6, xcol = idx & 63;
        out[(((size_t)b * 128 + oc) * 64 + y) * 64 + xcol] = outF[xcol][oc];
    }
}

// ---------------- patchify + 1x1 (128->192) via MFMA, NHWC input ----------------
__global__ __launch_bounds__(256) void k_patch1x1_mfma(
    const bf16* __restrict__ h1h, const bf16* __restrict__ wf, bf16* __restrict__ tok)
{
    __shared__ __align__(16) bf16 outL[64][200];
    const int br = blockIdx.x;
    const int b = br >> 6, y = br & 63;
    const int lane = threadIdx.x & 63, w = threadIdx.x >> 6;
    const int m0 = w * 16, kg = lane >> 4, ln16 = lane & 15;
    float4v acc[12];
    #pragma unroll
    for (int i = 0; i < 12; ++i) acc[i] = (float4v)0.f;
    #pragma unroll
    for (int kc = 0; kc < 4; ++kc) {
        short8 a = *(const short8*)(const void*)(h1h + ((size_t)br * 64 + m0 + ln16) * 128 + kc * 32 + kg * 8);
        const bf16* wb = wf + (kc * 12) * 512 + lane * 8;
        #pragma unroll
        for (int nt = 0; nt < 12; ++nt) {
            short8 bfrag = *(const short8*)(const void*)(wb + nt * 512);
            acc[nt] = __builtin_amdgcn_mfma_f32_16x16x32_bf16(a, bfrag, acc[nt], 0, 0, 0);
        }
    }
    #pragma unroll
    for (int nt = 0; nt < 12; ++nt) {
        #pragma unroll
        for (int r = 0; r < 4; ++r)
            outL[m0 + kg * 4 + r][nt * 16 + ln16] = f2b(acc[nt][r]);
    }
    __syncthreads();
    const int pab = (y & 7) * 8, npb = (y >> 3) * 8;
    for (int idx = threadIdx.x; idx < 1536; idx += 256) {
        int x = idx / 24, q = idx - x * 24;
        int row = (b * 64 + pab + (x & 7)) * 64 + npb + (x >> 3);
        *(short8*)(void*)(tok + (size_t)row * 192 + q * 8) =
            *(const short8*)(const void*)(&outL[x][q * 8]);
    }
}

// ---------------- gating ----------------
__global__ __launch_bounds__(256) void k_gate(
    const bf16* __restrict__ tok, const float* __restrict__ gate_w_all,
    const int* __restrict__ task, float* __restrict__ dense,
    float* __restrict__ part)
{
    __shared__ float gwL[768];
    for (int i = threadIdx.x; i < 768; i += 256) gwL[i] = gate_w_all[(size_t)task[0] * 768 + i];
    __syncthreads();
    const int r = blockIdx.x * 256 + threadIdx.x;
    const bf16* tb = tok + (size_t)r * 192;
    float L0 = 0.f, L1 = 0.f, L2 = 0.f, L3 = 0.f;
    for (int c4 = 0; c4 < 48; ++c4) {
        float xv[4]; ld4(tb + c4 * 4, xv);
        #pragma unroll
        for (int j = 0; j < 4; ++j) {
            int c = c4 * 4 + j;
            L0 += xv[j] * gwL[c*4+0]; L1 += xv[j] * gwL[c*4+1];
            L2 += xv[j] * gwL[c*4+2]; L3 += xv[j] * gwL[c*4+3];
        }
    }
    float m = fmaxf(fmaxf(L0, L1), fmaxf(L2, L3));
    float e0 = expf(L0 - m), e1 = expf(L1 - m), e2 = expf(L2 - m), e3 = expf(L3 - m);
    float s = e0 + e1 + e2 + e3;
    float p[4] = {e0 / s, e1 / s, e2 / s, e3 / s};
    int i1 = 0; float v1 = p[0];
    #pragma unroll
    for (int e = 1; e < 4; ++e) if (p[e] > v1) { v1 = p[e]; i1 = e; }
    int i2 = -1; float v2 = -1.f;
    #pragma unroll
    for (int e = 0; e < 4; ++e) if (e != i1 && p[e] > v2) { v2 = p[e]; i2 = e; }
    float gs = v1 + v2;
    float d[4] = {0.f, 0.f, 0.f, 0.f};
    d[i1] = v1 / gs; d[i2] = v2 / gs;
    ((float4*)dense)[r] = make_float4(d[0], d[1], d[2], d[3]);

    float vals[8] = {p[0], p[1], p[2], p[3],
                     d[0] > 0.f ? 1.f : 0.f, d[1] > 0.f ? 1.f : 0.f,
                     d[2] > 0.f ? 1.f : 0.f, d[3] > 0.f ? 1.f : 0.f};
    #pragma unroll
    for (int off = 32; off; off >>= 1)
        #pragma unroll
        for (int i = 0; i < 8; ++i) vals[i] += __shfl_down(vals[i], off);
    __shared__ float sm[4][8];
    const int lane = threadIdx.x & 63, wv = threadIdx.x >> 6;
    if (lane == 0)
        #pragma unroll
        for (int i = 0; i < 8; ++i) sm[wv][i] = vals[i];
    __syncthreads();
    if (threadIdx.x < 8)
        part[blockIdx.x * 8 + threadIdx.x] =
            sm[0][threadIdx.x] + sm[1][threadIdx.x] + sm[2][threadIdx.x] + sm[3][threadIdx.x];
}

// ---------------- MoE via MFMA ----------------
template <typename TT>
__global__ __launch_bounds__(256) void k_moe_mfma(
    const bf16* __restrict__ tok, const float* __restrict__ dense,
    const bf16* __restrict__ w1f, const float* __restrict__ b1,
    const bf16* __restrict__ w2f, const float* __restrict__ b2,
    TT* __restrict__ tout)
{
    __shared__ __align__(16) bf16 hL[64][200];
    const int rbase = blockIdx.x * 64;
    const int lane = threadIdx.x & 63, w = threadIdx.x >> 6;
    const int m0 = w * 16;
    const int kg = lane >> 4;
    const int ln16 = lane & 15;
    const int arow = rbase + m0 + ln16;

    float4v accT[12];
    #pragma unroll
    for (int i = 0; i < 12; ++i) accT[i] = (float4v)0.f;

    for (int e = 0; e < 4; ++e) {
        float g4[4];
        #pragma unroll
        for (int r = 0; r < 4; ++r)
            g4[r] = dense[(size_t)(rbase + m0 + kg * 4 + r) * 4 + e];

        float4v acc[12];
        #pragma unroll
        for (int i = 0; i < 12; ++i) acc[i] = (float4v)0.f;
        for (int kc = 0; kc < 6; ++kc) {
            short8 a = *(const short8*)(const void*)(tok + (size_t)arow * 192 + kc * 32 + kg * 8);
            const bf16* wb = w1f + (size_t)e * 36864 + (kc * 12) * 512 + lane * 8;
            #pragma unroll
            for (int nt = 0; nt < 12; ++nt) {
                short8 bfrag = *(const short8*)(const void*)(wb + nt * 512);
                acc[nt] = __builtin_amdgcn_mfma_f32_16x16x32_bf16(a, bfrag, acc[nt], 0, 0, 0);
            }
        }
        #pragma unroll
        for (int nt = 0; nt < 12; ++nt) {
            int c = nt * 16 + ln16;
            float bias = b1[e * 192 + c];
            #pragma unroll
            for (int r = 0; r < 4; ++r)
                hL[m0 + kg * 4 + r][c] = f2b(geluf(acc[nt][r] + bias));
        }
        __syncthreads();
        #pragma unroll
        for (int i = 0; i < 12; ++i) acc[i] = (float4v)0.f;
        for (int kc = 0; kc < 6; ++kc) {
            short8 a = *(const short8*)(const void*)(&hL[m0 + ln16][kc * 32 + kg * 8]);
            const bf16* wb = w2f + (size_t)e * 36864 + (kc * 12) * 512 + lane * 8;
            #pragma unroll
            for (int nt = 0; nt < 12; ++nt) {
                short8 bfrag = *(const short8*)(const void*)(wb + nt * 512);
                acc[nt] = __builtin_amdgcn_mfma_f32_16x16x32_bf16(a, bfrag, acc[nt], 0, 0, 0);
            }
        }
        #pragma unroll
        for (int nt = 0; nt < 12; ++nt) {
            int c = nt * 16 + ln16;
            float bias = b2[e * 192 + c];
            #pragma unroll
            for (int r = 0; r < 4; ++r)
                accT[nt][r] += g4[r] * (acc[nt][r] + bias);
        }
        __syncthreads();
    }
    #pragma unroll
    for (int nt = 0; nt < 12; ++nt) {
        int c = nt * 16 + ln16;
        #pragma unroll
        for (int r = 0; r < 4; ++r)
            stv(&tout[(size_t)(rbase + m0 + kg * 4 + r) * 192 + c], accT[nt][r]);
    }
}

// ---------------- proj via MFMA ----------------
template <typename TT>
__global__ __launch_bounds__(256) void k_proj_mfma(
    const bf16* __restrict__ y2, const bf16* __restrict__ pwf,
    const float* __restrict__ pb, TT* __restrict__ t)
{
    const int rbase = blockIdx.x * 64;
    const int lane = threadIdx.x & 63, w = threadIdx.x >> 6;
    const int m0 = w * 16;
    const int kg = lane >> 4, ln16 = lane & 15;
    const int arow = rbase + m0 + ln16;
    float4v acc[12];
    #pragma unroll
    for (int i = 0; i < 12; ++i) acc[i] = (float4v)0.f;
    for (int kc = 0; kc < 6; ++kc) {
        short8 a = *(const short8*)(const void*)(y2 + (size_t)arow * 192 + kc * 32 + kg * 8);
        const bf16* wb = pwf + (kc * 12) * 512 + lane * 8;
        #pragma unroll
        for (int nt = 0; nt < 12; ++nt) {
            short8 bfrag = *(const short8*)(const void*)(wb + nt * 512);
            acc[nt] = __builtin_amdgcn_mfma_f32_16x16x32_bf16(a, bfrag, acc[nt], 0, 0, 0);
        }
    }
    #pragma unroll
    for (int nt = 0; nt < 12; ++nt) {
        int c = nt * 16 + ln16;
        float bias = pb[c];
        #pragma unroll
        for (int r = 0; r < 4; ++r) {
            TT* p = &t[(size_t)(rbase + m0 + kg * 4 + r) * 192 + c];
            stv(p, ldv(p) + acc[nt][r] + bias);
        }
    }
}

// ---------------- fused LN2 + MLP via MFMA ----------------
template <typename TT>
__global__ __launch_bounds__(256) void k_mlp_mfma(
    TT* __restrict__ t, const float* __restrict__ lg, const float* __restrict__ lb,
    const bf16* __restrict__ w1f, const float* __restrict__ b1,
    const bf16* __restrict__ w2f, const float* __restrict__ b2)
{
    __shared__ __align__(16) bf16 yL[64][200];
    __shared__ __align__(16) bf16 hL[64][200];
    const int rbase = blockIdx.x * 64;
    const int tid = threadIdx.x;
    {
        const int row = tid >> 2, qg = tid & 3;
        float v[48];
        const TT* tr_ = t + (size_t)(rbase + row) * 192 + qg * 48;
        float s = 0.f, sq = 0.f;
        #pragma unroll
        for (int i = 0; i < 12; ++i) {
            float tmp[4]; ld4(tr_ + i * 4, tmp);
            #pragma unroll
            for (int j = 0; j < 4; ++j) { v[i*4+j] = tmp[j]; s += tmp[j]; sq += tmp[j]*tmp[j]; }
        }
        s  += __shfl_xor(s, 1);  s  += __shfl_xor(s, 2);
        sq += __shfl_xor(sq, 1); sq += __shfl_xor(sq, 2);
        float m = s * (1.f/192.f), var = sq * (1.f/192.f) - m*m;
        float rs = rsqrtf(var + 1e-5f);
        #pragma unroll
        for (int i = 0; i < 48; ++i) {
            int d = qg * 48 + i;
            yL[row][d] = f2b((v[i] - m) * rs * lg[d] + lb[d]);
        }
    }
    __syncthreads();
    const int lane = tid & 63, w = tid >> 6;
    const int m0 = w * 16;
    const int kg = lane >> 4, ln16 = lane & 15;
    float4v accT[12];
    #pragma unroll
    for (int i = 0; i < 12; ++i) accT[i] = (float4v)0.f;
    for (int ch = 0; ch < 2; ++ch) {
        float4v acc[12];
        #pragma unroll
        for (int i = 0; i < 12; ++i) acc[i] = (float4v)0.f;
        for (int kc = 0; kc < 6; ++kc) {
            short8 a = *(const short8*)(const void*)(&yL[m0 + ln16][kc * 32 + kg * 8]);
            const bf16* wb = w1f + (size_t)(kc * 24 + ch * 12) * 512 + lane * 8;
            #pragma unroll
            for (int nt = 0; nt < 12; ++nt) {
                short8 bfrag = *(const short8*)(const void*)(wb + nt * 512);
                acc[nt] = __builtin_amdgcn_mfma_f32_16x16x32_bf16(a, bfrag, acc[nt], 0, 0, 0);
            }
        }
        #pragma unroll
        for (int nt = 0; nt < 12; ++nt) {
            int c = nt * 16 + ln16;
            float bias = b1[ch * 192 + c];
            #pragma unroll
            for (int r = 0; r < 4; ++r)
                hL[m0 + kg * 4 + r][c] = f2b(geluf(acc[nt][r] + bias));
        }
        __syncthreads();
        for (int kc = 0; kc < 6; ++kc) {
            short8 a = *(const short8*)(const void*)(&hL[m0 + ln16][kc * 32 + kg * 8]);
            const bf16* wb = w2f + (size_t)((ch * 6 + kc) * 12) * 512 + lane * 8;
            #pragma unroll
            for (int nt = 0; nt < 12; ++nt) {
                short8 bfrag = *(const short8*)(const void*)(wb + nt * 512);
                accT[nt] = __builtin_amdgcn_mfma_f32_16x16x32_bf16(a, bfrag, accT[nt], 0, 0, 0);
            }
        }
        __syncthreads();
    }
    #pragma unroll
    for (int nt = 0; nt < 12; ++nt) {
        int c = nt * 16 + ln16;
        float bias = b2[c];
        #pragma unroll
        for (int r = 0; r < 4; ++r) {
            TT* p = &t[(size_t)(rbase + m0 + kg * 4 + r) * 192 + c];
            stv(p, ldv(p) + accT[nt][r] + bias);
        }
    }
}

// ---------------- fused LN1 + QKV + attention, all-MFMA, one block per sequence ----------------
// grid 2048, block 256 (4 waves); wave w handles head w in the attention phase.
// LDS: qkL [64][520] (Q at h*64+d, K at 256+h*64+d; d 48..63 zero) | vT [4][48][72] | pL [4][64][72]
template <typename TT>
__global__ __launch_bounds__(256) void k_attn_mfma(
    const TT* __restrict__ t, const float* __restrict__ lg, const float* __restrict__ lb,
    const bf16* __restrict__ qkvwf, const float* __restrict__ qkvb, bf16* __restrict__ y2)
{
    __shared__ __align__(16) char smem[131072];
    bf16* qkL = (bf16*)smem;                    // 64*520*2 = 66560 B
    bf16* vT  = (bf16*)(smem + 66560);          // 4*48*72*2 = 27648 B
    bf16* pL  = (bf16*)(smem + 94208);          // 4*64*72*2 = 36864 B
    const int n = blockIdx.x;
    const int tid = threadIdx.x;
    const int w = tid >> 6, lane = tid & 63;
    const int kg = lane >> 4, ln16 = lane & 15;
    const int row = w * 16 + ln16;

    // zero-fill Q/K pad columns d=48..63 (8 strips of 16 cols x 64 rows)
    for (int idx = tid; idx < 1024; idx += 256) {
        int s = idx >> 7, rem = idx & 127;
        int r = rem >> 1, half = rem & 1;
        *(short8*)(void*)(qkL + r * 520 + s * 64 + 48 + half * 8) = (short8){0,0,0,0,0,0,0,0};
    }

    // LN in registers, producing A-fragments directly
    short8 afr[6];
    {
        float v[48];
        float s = 0.f, sq = 0.f;
        const TT* tp = t + (size_t)n * 12288 + row * 192 + kg * 8;
        #pragma unroll
        for (int c = 0; c < 6; ++c) {
            float tmp[8]; ld8(tp + c * 32, tmp);
            #pragma unroll
            for (int j = 0; j < 8; ++j) { v[c*8+j] = tmp[j]; s += tmp[j]; sq += tmp[j]*tmp[j]; }
        }
        s  += __shfl_xor(s, 16);  s  += __shfl_xor(s, 32);
        sq += __shfl_xor(sq, 16); sq += __shfl_xor(sq, 32);
        float m = s * (1.f/192.f), var = sq * (1.f/192.f) - m * m;
        float rs = rsqrtf(var + 1e-5f);
        #pragma unroll
        for (int c = 0; c < 6; ++c) {
            float g8[8], b8[8];
            ld8(lg + kg * 8 + c * 32, g8);
            ld8(lb + kg * 8 + c * 32, b8);
            bf16 pk[8];
            #pragma unroll
            for (int j = 0; j < 8; ++j)
                pk[j] = f2b((v[c*8+j] - m) * rs * g8[j] + b8[j]);
            afr[c] = *(const short8*)(const void*)pk;
        }
    }

    // QKV GEMM: wave w computes rows w*16..w*16+15 for all 576 cols
    const float qscale = 0.14433756729740644f;  // 1/sqrt(48)
    for (int nt = 0; nt < 36; ++nt) {
        float4v acc = (float4v)0.f;
        const bf16* wb = qkvwf + nt * 512 + lane * 8;
        #pragma unroll
        for (int kc = 0; kc < 6; ++kc) {
            short8 bfrag = *(const short8*)(const void*)(wb + kc * 36 * 512);
            acc = __builtin_amdgcn_mfma_f32_16x16x32_bf16(afr[kc], bfrag, acc, 0, 0, 0);
        }
        const int which = nt / 12, h = (nt % 12) / 3, dt = nt % 3;
        const int d = dt * 16 + ln16;
        const float bias = qkvb[nt * 16 + ln16];
        if (which == 0) {
            #pragma unroll
            for (int r = 0; r < 4; ++r)
                qkL[(w * 16 + kg * 4 + r) * 520 + h * 64 + d] = f2b((acc[r] + bias) * qscale);
        } else if (which == 1) {
            #pragma unroll
            for (int r = 0; r < 4; ++r)
                qkL[(w * 16 + kg * 4 + r) * 520 + 256 + h * 64 + d] = f2b(acc[r] + bias);
        } else {
            #pragma unroll
            for (int r = 0; r < 4; ++r)
                vT[h * 3456 + d * 72 + (w * 16 + kg * 4 + r)] = f2b(acc[r] + bias);
        }
    }
    __syncthreads();

    // attention: wave w = head w
    const bf16* Qb = qkL + w * 64;
    const bf16* Kb = qkL + 256 + w * 64;
    float4v sacc[4][4];
    #pragma unroll
    for (int mt = 0; mt < 4; ++mt)
        #pragma unroll
        for (int nt = 0; nt < 4; ++nt) sacc[mt][nt] = (float4v)0.f;
    #pragma unroll
    for (int kc = 0; kc < 2; ++kc) {
        short8 aq[4], bk[4];
        #pragma unroll
        for (int mt = 0; mt < 4; ++mt)
            aq[mt] = *(const short8*)(const void*)(Qb + (mt * 16 + ln16) * 520 + kc * 32 + kg * 8);
        #pragma unroll
        for (int nt = 0; nt < 4; ++nt)
            bk[nt] = *(const short8*)(const void*)(Kb + (nt * 16 + ln16) * 520 + kc * 32 + kg * 8);
        #pragma unroll
        for (int mt = 0; mt < 4; ++mt)
            #pragma unroll
            for (int nt = 0; nt < 4; ++nt)
                sacc[mt][nt] = __builtin_amdgcn_mfma_f32_16x16x32_bf16(aq[mt], bk[nt], sacc[mt][nt], 0, 0, 0);
    }
    // softmax per row (row = mt*16 + kg*4 + r; cols nt*16 + ln16)
    #pragma unroll
    for (int mt = 0; mt < 4; ++mt) {
        #pragma unroll
        for (int r = 0; r < 4; ++r) {
            float mx = sacc[mt][0][r];
            #pragma unroll
            for (int nt = 1; nt < 4; ++nt) mx = fmaxf(mx, sacc[mt][nt][r]);
            mx = fmaxf(mx, __shfl_xor(mx, 1)); mx = fmaxf(mx, __shfl_xor(mx, 2));
            mx = fmaxf(mx, __shfl_xor(mx, 4)); mx = fmaxf(mx, __shfl_xor(mx, 8));
            float e[4], sum = 0.f;
            #pragma unroll
            for (int nt = 0; nt < 4; ++nt) { e[nt] = expf(sacc[mt][nt][r] - mx); sum += e[nt]; }
            sum += __shfl_xor(sum, 1); sum += __shfl_xor(sum, 2);
            sum += __shfl_xor(sum, 4); sum += __shfl_xor(sum, 8);
            float inv = 1.f / sum;
            #pragma unroll
            for (int nt = 0; nt < 4; ++nt)
                pL[w * 4608 + (mt * 16 + kg * 4 + r) * 72 + nt * 16 + ln16] = f2b(e[nt] * inv);
        }
    }
    // PV: out[token][d] = sum_j P[token][j] V[j][d]
    float4v oacc[4][3];
    #pragma unroll
    for (int mt = 0; mt < 4; ++mt)
        #pragma unroll
        for (int nt = 0; nt < 3; ++nt) oacc[mt][nt] = (float4v)0.f;
    #pragma unroll
    for (int kc = 0; kc < 2; ++kc) {
        short8 ap[4], bv[3];
        #pragma unroll
        for (int mt = 0; mt < 4; ++mt)
            ap[mt] = *(const short8*)(const void*)(pL + w * 4608 + (mt * 16 + ln16) * 72 + kc * 32 + kg * 8);
        #pragma unroll
        for (int nt = 0; nt < 3; ++nt)
            bv[nt] = *(const short8*)(const void*)(vT + w * 3456 + (nt * 16 + ln16) * 72 + kc * 32 + kg * 8);
        #pragma unroll
        for (int mt = 0; mt < 4; ++mt)
            #pragma unroll
            for (int nt = 0; nt < 3; ++nt)
                oacc[mt][nt] = __builtin_amdgcn_mfma_f32_16x16x32_bf16(ap[mt], bv[nt], oacc[mt][nt], 0, 0, 0);
    }
    #pragma unroll
    for (int mt = 0; mt < 4; ++mt)
        #pragma unroll
        for (int nt = 0; nt < 3; ++nt)
            #pragma unroll
            for (int r = 0; r < 4; ++r)
                y2[((size_t)n * 64 + mt * 16 + kg * 4 + r) * 192 + w * 48 + nt * 16 + ln16] =
                    f2b(oacc[mt][nt][r]);
}

// ---------------- fused final LN + unpatchify + 1x1 (192->128) + BN + SiLU -> ph NHWC bf16 ----------------
template <typename TT>
__global__ __launch_bounds__(256) void k_unpatch(
    const TT* __restrict__ t, const float* __restrict__ ng, const float* __restrict__ nb,
    const float* __restrict__ wp, const float* __restrict__ gamma, const float* __restrict__ beta,
    bf16* __restrict__ ph)
{
    const int np = blockIdx.x, b = blockIdx.y;
    const int pi = np >> 3, pj = np & 7;
    __shared__ float tL[64][193];
    __shared__ float oL[64][129];
    for (int idx = threadIdx.x * 4; idx < 64 * 192; idx += 1024) {
        int pa = idx / 192, d = idx % 192;
        float tmp[4]; ld4(t + ((size_t)(b * 64 + pa) * 64 + np) * 192 + d, tmp);
        tL[pa][d] = tmp[0]; tL[pa][d+1] = tmp[1]; tL[pa][d+2] = tmp[2]; tL[pa][d+3] = tmp[3];
    }
    __syncthreads();
    ln_rows193(tL, ng, nb, threadIdx.x);
    __syncthreads();
    const int lane = threadIdx.x & 63, wv = threadIdx.x >> 6;
    for (int k = 0; k < 32; ++k) {
        int o = wv * 32 + k;
        float acc = 0.f;
        for (int d4 = 0; d4 < 48; ++d4) {
            float wq[4]; ld4(wp + (size_t)o * 192 + d4 * 4, wq);
            acc += tL[lane][d4*4+0] * wq[0] + tL[lane][d4*4+1] * wq[1]
                 + tL[lane][d4*4+2] * wq[2] + tL[lane][d4*4+3] * wq[3];
        }
        float v = gamma[o] * acc + beta[o];
        oL[lane][o] = siluf(v);
    }
    __syncthreads();
    for (int idx = threadIdx.x; idx < 1024; idx += 256) {
        int pa = idx >> 4, q = idx & 15;
        int yy = pi * 8 + (pa >> 3), xx = pj * 8 + (pa & 7);
        bf16 tmp8[8];
        #pragma unroll
        for (int j = 0; j < 8; ++j) tmp8[j] = f2b(oL[pa][q * 8 + j]);
        *(short8*)(void*)(ph + ((size_t)(b * 64 + yy) * 64 + xx) * 128 + q * 8) =
            *(const short8*)(const void*)tmp8;
    }
}

// ---------------- moe loss ----------------
__global__ void k_loss(const float* __restrict__ part, float* __restrict__ out)
{
    if (threadIdx.x == 0 && blockIdx.x == 0) {
        float L = 0.f;
        for (int e = 0; e < 4; ++e) {
            float imp = 0.f, ld = 0.f;
            for (int i = 0; i < 512; ++i) { imp += part[i * 8 + e]; ld += part[i * 8 + 4 + e]; }
            L += (imp / 131072.f) * (ld / 131072.f);
        }
        out[16777216] = 4.f * L;
    }
}

template <typename TT>
static void run_pipeline(const float* x, const float* w_kxk, const float* bn1_g, const float* bn1_b,
                         const float* w_1x1, const float* gate_w,
                         const float* moe_w1, const float* moe_b1, const float* moe_w2, const float* moe_b2,
                         const float* ln1_g, const float* ln1_b, const float* qkv_w, const float* qkv_b,
                         const float* proj_w, const float* proj_b, const float* ln2_g, const float* ln2_b,
                         const float* fc1_w, const float* fc1_b, const float* fc2_w, const float* fc2_b,
                         const float* nrm_g, const float* nrm_b, const float* w_proj, const float* bn2_g,
                         const float* bn2_b, const float* w_fus, const float* bn3_g, const float* bn3_b,
                         const int* task, float* out, bf16* xh, bf16* tok, TT* t, float* dense, float* part,
                         bf16* wprep, hipStream_t stream)
{
    // prep fragments
    bf16* moeW1f = wprep;                 // 147456
    bf16* moeW2f = wprep + 147456;        // 147456
    bf16* fc1f   = wprep + 294912;        // 147456
    bf16* fc2f   = wprep + 442368;        // 147456
    bf16* projWf = wprep + 589824;        // 73728
    bf16* w1x1f  = wprep + 663552;        // 24576
    bf16* convW1f= wprep + 688128;        // 147456
    bf16* convWFf= wprep + 835584;        // 294912
    bf16* qkvWf  = wprep + 1130496;       // 221184 -> total 1351680 elems
    hipLaunchKernelGGL(k_prep, dim3(576), dim3(256), 0, stream, moe_w1, moeW1f, 192, 192, 4);
    hipLaunchKernelGGL(k_prep, dim3(576), dim3(256), 0, stream, moe_w2, moeW2f, 192, 192, 4);
    hipLaunchKernelGGL(k_prep, dim3(576), dim3(256), 0, stream, fc1_w, fc1f, 192, 384, 2);
    hipLaunchKernelGGL(k_prep, dim3(576), dim3(256), 0, stream, fc2_w, fc2f, 384, 192, 2);
    hipLaunchKernelGGL(k_prep, dim3(288), dim3(256), 0, stream, proj_w, projWf, 192, 192, 2);
    hipLaunchKernelGGL(k_prep_t, dim3(96), dim3(256), 0, stream, w_1x1, w1x1f, 192, 128);
    hipLaunchKernelGGL(k_prep_conv, dim3(576), dim3(256), 0, stream, w_kxk, convW1f, 128, 128);
    hipLaunchKernelGGL(k_prep_conv, dim3(1152), dim3(256), 0, stream, w_fus, convWFf, 256, 128);
    hipLaunchKernelGGL(k_prep, dim3(864), dim3(256), 0, stream, qkv_w, qkvWf, 192, 576, 2);

    bf16* h1h = (bf16*)out;  // d_out used as NHWC bf16 scratch; fully rewritten by final conv
    hipLaunchKernelGGL(k_tohwc, dim3(2048), dim3(256), 0, stream, x, xh);
    hipLaunchKernelGGL(k_conv1_mfma, dim3(2048), dim3(256), 0, stream, xh, convW1f, bn1_g, bn1_b, h1h);
    hipLaunchKernelGGL(k_patch1x1_mfma, dim3(2048), dim3(256), 0, stream, h1h, w1x1f, tok);
    hipLaunchKernelGGL(k_gate, dim3(512), dim3(256), 0, stream, tok, gate_w, task, dense, part);
    hipLaunchKernelGGL(k_moe_mfma<TT>, dim3(2048), dim3(256), 0, stream,
                       tok, dense, moeW1f, moe_b1, moeW2f, moe_b2, t);
    bf16* y2 = tok;  // tok dead after MoE
    for (int l = 0; l < 2; ++l) {
        hipLaunchKernelGGL(k_attn_mfma<TT>, dim3(2048), dim3(256), 0, stream,
                           t, ln1_g + l * 192, ln1_b + l * 192,
                           qkvWf + (size_t)l * 110592, qkv_b + l * 576, y2);
        hipLaunchKernelGGL(k_proj_mfma<TT>, dim3(2048), dim3(256), 0, stream,
                           y2, projWf + (size_t)l * 36864, proj_b + l * 192, t);
        hipLaunchKernelGGL(k_mlp_mfma<TT>, dim3(2048), dim3(256), 0, stream,
                           t, ln2_g + l * 192, ln2_b + l * 192,
                           fc1f + (size_t)l * 73728, fc1_b + l * 384,
                           fc2f + (size_t)l * 73728, fc2_b + l * 192);
    }
    bf16* ph = tok;  // y2 dead after last proj; reuse region as NHWC p
    hipLaunchKernelGGL(k_unpatch<TT>, dim3(64, 32), dim3(256), 0, stream,
                       t, nrm_g, nrm_b, w_proj, bn2_g, bn2_b, ph);
    hipLaunchKernelGGL(k_convf_mfma, dim3(2048), dim3(256), 0, stream,
                       xh, ph, convWFf, bn3_g, bn3_b, out);
    hipLaunchKernelGGL(k_loss, dim3(1), dim3(64), 0, stream, part, out);
}

extern "C" void kernel_launch(void* const* d_in, const int* in_sizes, int n_in,
                              void* d_out, int out_size, void* d_ws, size_t ws_size,
                              hipStream_t stream) {
    const float* x      = (const float*)d_in[0];
    const float* w_kxk  = (const float*)d_in[1];
    const float* bn1_g  = (const float*)d_in[2];
    const float* bn1_b  = (const float*)d_in[3];
    const float* w_1x1  = (const float*)d_in[4];
    const float* gate_w = (const float*)d_in[5];
    const float* moe_w1 = (const float*)d_in[6];
    const float* moe_b1 = (const float*)d_in[7];
    const float* moe_w2 = (const float*)d_in[8];
    const float* moe_b2 = (const float*)d_in[9];
    const float* ln1_g  = (const float*)d_in[10];
    const float* ln1_b  = (const float*)d_in[11];
    const float* qkv_w  = (const float*)d_in[12];
    const float* qkv_b  = (const float*)d_in[13];
    const float* proj_w = (const float*)d_in[14];
    const float* proj_b = (const float*)d_in[15];
    const float* ln2_g  = (const float*)d_in[16];
    const float* ln2_b  = (const float*)d_in[17];
    const float* fc1_w  = (const float*)d_in[18];
    const float* fc1_b  = (const float*)d_in[19];
    const float* fc2_w  = (const float*)d_in[20];
    const float* fc2_b  = (const float*)d_in[21];
    const float* nrm_g  = (const float*)d_in[22];
    const float* nrm_b  = (const float*)d_in[23];
    const float* w_proj = (const float*)d_in[24];
    const float* bn2_g  = (const float*)d_in[25];
    const float* bn2_b  = (const float*)d_in[26];
    const float* w_fus  = (const float*)d_in[27];
    const float* bn3_g  = (const float*)d_in[28];
    const float* bn3_b  = (const float*)d_in[29];
    const int*  task    = (const int*)d_in[30];

    char* wsb = (char*)d_ws;
    const size_t XHB   = 33554432ull;    // NHWC bf16 x
    const size_t TOKB  = 50331648ull;    // tok / y2 / ph region
    const size_t T32B  = 100663296ull;
    const size_t T16B  = 50331648ull;
    const size_t DENB  = 2097152ull;
    const size_t PARB  = 16384ull;
    const size_t WPB   = 2703360ull;
    bf16* xh  = (bf16*)wsb;
    bf16* tok = (bf16*)(wsb + XHB);
    float* out = (float*)d_out;

    if (ws_size >= XHB + TOKB + T32B + DENB + PARB + WPB) {
        float* t     = (float*)(wsb + XHB + TOKB);
        float* dense = (float*)(wsb + XHB + TOKB + T32B);
        float* part  = (float*)(wsb + XHB + TOKB + T32B + DENB);
        bf16*  wprep = (bf16*)(wsb + XHB + TOKB + T32B + DENB + PARB);
        run_pipeline<float>(x, w_kxk, bn1_g, bn1_b, w_1x1, gate_w, moe_w1, moe_b1, moe_w2, moe_b2,
                            ln1_g, ln1_b, qkv_w, qkv_b, proj_w, proj_b, ln2_g, ln2_b,
                            fc1_w, fc1_b, fc2_w, fc2_b, nrm_g, nrm_b, w_proj, bn2_g, bn2_b,
                            w_fus, bn3_g, bn3_b, task, out, xh, tok, t, dense, part, wprep, stream);
    } else {
        bf16*  t     = (bf16*)(wsb + XHB + TOKB);
        float* dense = (float*)(wsb + XHB + TOKB + T16B);
        float* part  = (float*)(wsb + XHB + TOKB + T16B + DENB);
        bf16*  wprep = (bf16*)(wsb + XHB + TOKB + T16B + DENB + PARB);
        run_pipeline<bf16>(x, w_kxk, bn1_g, bn1_b, w_1x1, gate_w, moe_w1, moe_b1, moe_w2, moe_b2,
                           ln1_g, ln1_b, qkv_w, qkv_b, proj_w, proj_b, ln2_g, ln2_b,
                           fc1_w, fc1_b, fc2_w, fc2_b, nrm_g, nrm_b, w_proj, bn2_g, bn2_b,
                           w_fus, bn3_g, bn3_b, task, out, xh, tok, t, dense, part, wprep, stream);
    }
}

// Round 7
// 1488.216 us; speedup vs baseline: 14.4029x; 1.3439x over previous
//
#include <hip/hip_runtime.h>
#include <hip/hip_bf16.h>
#include <cmath>

typedef __hip_bfloat16 bf16;
typedef __attribute__((ext_vector_type(8))) short short8;
typedef __attribute__((ext_vector_type(4))) float float4v;

__device__ __forceinline__ float b2f(bf16 v) { return __bfloat162float(v); }
__device__ __forceinline__ bf16  f2b(float v) { return __float2bfloat16(v); }
__device__ __forceinline__ float bfr(unsigned int u) { union { float f; unsigned int i; } c; c.i = u << 16; return c.f; }
__device__ __forceinline__ void ld4(const float* p, float* o) {
    float4 q = *(const float4*)p; o[0]=q.x; o[1]=q.y; o[2]=q.z; o[3]=q.w;
}
__device__ __forceinline__ void ld4(const bf16* p, float* o) {
    const uint2 q = *(const uint2*)p;
    o[0] = bfr(q.x & 0xffffu); o[1] = bfr(q.x >> 16);
    o[2] = bfr(q.y & 0xffffu); o[3] = bfr(q.y >> 16);
}
template <typename T>
__device__ __forceinline__ void ld8(const T* p, float* o) { ld4(p, o); ld4(p + 4, o + 4); }
__device__ __forceinline__ float ldv(const float* p) { return *p; }
__device__ __forceinline__ float ldv(const bf16* p)  { return b2f(*p); }
__device__ __forceinline__ void  stv(float* p, float v) { *p = v; }
__device__ __forceinline__ void  stv(bf16* p, float v)  { *p = f2b(v); }

__device__ __forceinline__ float siluf(float x) { return x / (1.f + expf(-x)); }
__device__ __forceinline__ float geluf(float x) { return 0.5f * x * (1.f + erff(x * 0.70710678118654752f)); }

// ---------------- weight prep: fp32 [k][n] -> bf16 MFMA-fragment order ----------------
__global__ __launch_bounds__(256) void k_prep(
    const float* __restrict__ src, bf16* __restrict__ dst, int K, int N, int nmat)
{
    const int per = K * N;
    const int total = per * nmat;
    const int NT = N >> 4;
    for (int idx = blockIdx.x * 256 + threadIdx.x; idx < total; idx += gridDim.x * 256) {
        int m = idx / per;
        int rem = idx - m * per;
        int k = rem / N, n = rem - k * N;
        int off = ((k >> 5) * NT + (n >> 4)) * 512 + (((k >> 3) & 3) * 16 + (n & 15)) * 8 + (k & 7);
        dst[(size_t)m * per + off] = f2b(src[idx]);
    }
}

// src is [N][K] (row n, col k) -> fragged [K][N]
__global__ __launch_bounds__(256) void k_prep_t(
    const float* __restrict__ src, bf16* __restrict__ dst, int N, int K)
{
    const int total = N * K;
    const int NT = N >> 4;
    for (int idx = blockIdx.x * 256 + threadIdx.x; idx < total; idx += gridDim.x * 256) {
        int n = idx / K, k = idx - n * K;
        int off = ((k >> 5) * NT + (n >> 4)) * 512 + (((k >> 3) & 3) * 16 + (n & 15)) * 8 + (k & 7);
        dst[off] = f2b(src[idx]);
    }
}

// conv weights OIHW (Cout,Cin,3,3) -> 9 fragged [Cin][Cout] matrices (tap-major)
__global__ __launch_bounds__(256) void k_prep_conv(
    const float* __restrict__ src, bf16* __restrict__ dst, int Cin, int Cout)
{
    const int total = Cout * Cin * 9;
    const int NT = Cout >> 4;
    for (int idx = blockIdx.x * 256 + threadIdx.x; idx < total; idx += gridDim.x * 256) {
        int oc = idx / (Cin * 9);
        int rem = idx - oc * (Cin * 9);
        int ic = rem / 9, tap = rem - ic * 9;
        int off = tap * (Cin * Cout)
                + ((ic >> 5) * NT + (oc >> 4)) * 512
                + (((ic >> 3) & 3) * 16 + (oc & 15)) * 8 + (ic & 7);
        dst[off] = f2b(src[idx]);
    }
}

// ---------------- NCHW fp32 -> NHWC bf16 (one (b,y) row per block) ----------------
__global__ __launch_bounds__(256) void k_tohwc(const float* __restrict__ x, bf16* __restrict__ xh)
{
    __shared__ bf16 L[64][136];
    const int br = blockIdx.x;           // b*64 + y
    const int b = br >> 6, y = br & 63;
    for (int idx = threadIdx.x; idx < 8192; idx += 256) {
        int ch = idx >> 6, xc = idx & 63;
        L[xc][ch] = f2b(x[(((size_t)b * 128 + ch) * 64 + y) * 64 + xc]);
    }
    __syncthreads();
    for (int idx = threadIdx.x; idx < 1024; idx += 256) {
        int px = idx >> 4, q = idx & 15;
        *(short8*)(void*)(xh + ((size_t)br * 64 + px) * 128 + q * 8) =
            *(const short8*)(const void*)(&L[px][q * 8]);
    }
}

// ---------------- conv1 3x3 via MFMA (implicit GEMM, NHWC bf16 in/out) + BN + SiLU ----------------
__global__ __launch_bounds__(256) void k_conv1_mfma(
    const bf16* __restrict__ xh, const bf16* __restrict__ wf,
    const float* __restrict__ gamma, const float* __restrict__ beta,
    bf16* __restrict__ h1h)
{
    __shared__ __align__(16) bf16 outL[64][136];
    const int br = blockIdx.x;
    const int b = br >> 6, y = br & 63;
    const int lane = threadIdx.x & 63, w = threadIdx.x >> 6;
    const int m0 = w * 16, kg = lane >> 4, ln16 = lane & 15;
    float4v acc[8];
    #pragma unroll
    for (int i = 0; i < 8; ++i) acc[i] = (float4v)0.f;
    #pragma unroll
    for (int tap = 0; tap < 9; ++tap) {
        const int ky = tap / 3 - 1, kx = tap % 3 - 1;
        const int yy = y + ky;
        if (yy < 0 || yy > 63) continue;
        const int px = m0 + ln16 + kx;
        const bool valid = (px >= 0) && (px < 64);
        const bf16* wt = wf + tap * 16384;
        #pragma unroll
        for (int kc = 0; kc < 4; ++kc) {
            short8 a = {0, 0, 0, 0, 0, 0, 0, 0};
            if (valid)
                a = *(const short8*)(const void*)(xh + (((size_t)(b * 64 + yy) * 64 + px) * 128) + kc * 32 + kg * 8);
            const bf16* wb = wt + (kc * 8) * 512 + lane * 8;
            #pragma unroll
            for (int nt = 0; nt < 8; ++nt) {
                short8 bfrag = *(const short8*)(const void*)(wb + nt * 512);
                acc[nt] = __builtin_amdgcn_mfma_f32_16x16x32_bf16(a, bfrag, acc[nt], 0, 0, 0);
            }
        }
    }
    #pragma unroll
    for (int nt = 0; nt < 8; ++nt) {
        int c = nt * 16 + ln16;
        float g = gamma[c], be = beta[c];
        #pragma unroll
        for (int r = 0; r < 4; ++r)
            outL[m0 + kg * 4 + r][c] = f2b(siluf(g * acc[nt][r] + be));
    }
    __syncthreads();
    for (int idx = threadIdx.x; idx < 1024; idx += 256) {
        int px = idx >> 4, q = idx & 15;
        *(short8*)(void*)(h1h + ((size_t)br * 64 + px) * 128 + q * 8) =
            *(const short8*)(const void*)(&outL[px][q * 8]);
    }
}

// ---------------- fusion conv 3x3 (K=256 from xh + ph) + BN + SiLU -> NCHW fp32 ----------------
__global__ __launch_bounds__(256) void k_convf_mfma(
    const bf16* __restrict__ xh, const bf16* __restrict__ ph,
    const bf16* __restrict__ wf,
    const float* __restrict__ gamma, const float* __restrict__ beta,
    float* __restrict__ out)
{
    __shared__ float outF[64][129];
    const int br = blockIdx.x;
    const int b = br >> 6, y = br & 63;
    const int lane = threadIdx.x & 63, w = threadIdx.x >> 6;
    const int m0 = w * 16, kg = lane >> 4, ln16 = lane & 15;
    float4v acc[8];
    #pragma unroll
    for (int i = 0; i < 8; ++i) acc[i] = (float4v)0.f;
    #pragma unroll
    for (int tap = 0; tap < 9; ++tap) {
        const int ky = tap / 3 - 1, kx = tap % 3 - 1;
        const int yy = y + ky;
        if (yy < 0 || yy > 63) continue;
        const int px = m0 + ln16 + kx;
        const bool valid = (px >= 0) && (px < 64);
        const size_t rowoff = ((size_t)(b * 64 + yy) * 64 + px) * 128;
        const bf16* wt = wf + tap * 32768;
        #pragma unroll
        for (int kc = 0; kc < 8; ++kc) {
            const bf16* src = (kc < 4) ? xh : ph;
            short8 a = {0, 0, 0, 0, 0, 0, 0, 0};
            if (valid)
                a = *(const short8*)(const void*)(src + rowoff + (kc & 3) * 32 + kg * 8);
            const bf16* wb = wt + (kc * 8) * 512 + lane * 8;
            #pragma unroll
            for (int nt = 0; nt < 8; ++nt) {
                short8 bfrag = *(const short8*)(const void*)(wb + nt * 512);
                acc[nt] = __builtin_amdgcn_mfma_f32_16x16x32_bf16(a, bfrag, acc[nt], 0, 0, 0);
            }
        }
    }
    #pragma unroll
    for (int nt = 0; nt < 8; ++nt) {
        int c = nt * 16 + ln16;
        float g = gamma[c], be = beta[c];
        #pragma unroll
        for (int r = 0; r < 4; ++r)
            outF[m0 + kg * 4 + r][c] = siluf(g * acc[nt][r] + be);
    }
    __syncthreads();
    for (int idx = threadIdx.x; idx < 8192; idx += 256) {
        int oc = idx >> 6, xcol = idx & 63;
        out[(((size_t)b * 128 + oc) * 64 + y) * 64 + xcol] = outF[xcol][oc];
    }
}

// ---------------- patchify + 1x1 (128->192) via MFMA, NHWC input ----------------
__global__ __launch_bounds__(256) void k_patch1x1_mfma(
    const bf16* __restrict__ h1h, const bf16* __restrict__ wf, bf16* __restrict__ tok)
{
    __shared__ __align__(16) bf16 outL[64][200];
    const int br = blockIdx.x;
    const int b = br >> 6, y = br & 63;
    const int lane = threadIdx.x & 63, w = threadIdx.x >> 6;
    const int m0 = w * 16, kg = lane >> 4, ln16 = lane & 15;
    float4v acc[12];
    #pragma unroll
    for (int i = 0; i < 12; ++i) acc[i] = (float4v)0.f;
    #pragma unroll
    for (int kc = 0; kc < 4; ++kc) {
        short8 a = *(const short8*)(const void*)(h1h + ((size_t)br * 64 + m0 + ln16) * 128 + kc * 32 + kg * 8);
        const bf16* wb = wf + (kc * 12) * 512 + lane * 8;
        #pragma unroll
        for (int nt = 0; nt < 12; ++nt) {
            short8 bfrag = *(const short8*)(const void*)(wb + nt * 512);
            acc[nt] = __builtin_amdgcn_mfma_f32_16x16x32_bf16(a, bfrag, acc[nt], 0, 0, 0);
        }
    }
    #pragma unroll
    for (int nt = 0; nt < 12; ++nt) {
        #pragma unroll
        for (int r = 0; r < 4; ++r)
            outL[m0 + kg * 4 + r][nt * 16 + ln16] = f2b(acc[nt][r]);
    }
    __syncthreads();
    const int pab = (y & 7) * 8, npb = (y >> 3) * 8;
    for (int idx = threadIdx.x; idx < 1536; idx += 256) {
        int x = idx / 24, q = idx - x * 24;
        int row = (b * 64 + pab + (x & 7)) * 64 + npb + (x >> 3);
        *(short8*)(void*)(tok + (size_t)row * 192 + q * 8) =
            *(const short8*)(const void*)(&outL[x][q * 8]);
    }
}

// ---------------- gating ----------------
__global__ __launch_bounds__(256) void k_gate(
    const bf16* __restrict__ tok, const float* __restrict__ gate_w_all,
    const int* __restrict__ task, float* __restrict__ dense,
    float* __restrict__ part)
{
    __shared__ float gwL[768];
    for (int i = threadIdx.x; i < 768; i += 256) gwL[i] = gate_w_all[(size_t)task[0] * 768 + i];
    __syncthreads();
    const int r = blockIdx.x * 256 + threadIdx.x;
    const bf16* tb = tok + (size_t)r * 192;
    float L0 = 0.f, L1 = 0.f, L2 = 0.f, L3 = 0.f;
    for (int c4 = 0; c4 < 48; ++c4) {
        float xv[4]; ld4(tb + c4 * 4, xv);
        #pragma unroll
        for (int j = 0; j < 4; ++j) {
            int c = c4 * 4 + j;
            L0 += xv[j] * gwL[c*4+0]; L1 += xv[j] * gwL[c*4+1];
            L2 += xv[j] * gwL[c*4+2]; L3 += xv[j] * gwL[c*4+3];
        }
    }
    float m = fmaxf(fmaxf(L0, L1), fmaxf(L2, L3));
    float e0 = expf(L0 - m), e1 = expf(L1 - m), e2 = expf(L2 - m), e3 = expf(L3 - m);
    float s = e0 + e1 + e2 + e3;
    float p[4] = {e0 / s, e1 / s, e2 / s, e3 / s};
    int i1 = 0; float v1 = p[0];
    #pragma unroll
    for (int e = 1; e < 4; ++e) if (p[e] > v1) { v1 = p[e]; i1 = e; }
    int i2 = -1; float v2 = -1.f;
    #pragma unroll
    for (int e = 0; e < 4; ++e) if (e != i1 && p[e] > v2) { v2 = p[e]; i2 = e; }
    float gs = v1 + v2;
    float d[4] = {0.f, 0.f, 0.f, 0.f};
    d[i1] = v1 / gs; d[i2] = v2 / gs;
    ((float4*)dense)[r] = make_float4(d[0], d[1], d[2], d[3]);

    float vals[8] = {p[0], p[1], p[2], p[3],
                     d[0] > 0.f ? 1.f : 0.f, d[1] > 0.f ? 1.f : 0.f,
                     d[2] > 0.f ? 1.f : 0.f, d[3] > 0.f ? 1.f : 0.f};
    #pragma unroll
    for (int off = 32; off; off >>= 1)
        #pragma unroll
        for (int i = 0; i < 8; ++i) vals[i] += __shfl_down(vals[i], off);
    __shared__ float sm[4][8];
    const int lane = threadIdx.x & 63, wv = threadIdx.x >> 6;
    if (lane == 0)
        #pragma unroll
        for (int i = 0; i < 8; ++i) sm[wv][i] = vals[i];
    __syncthreads();
    if (threadIdx.x < 8)
        part[blockIdx.x * 8 + threadIdx.x] =
            sm[0][threadIdx.x] + sm[1][threadIdx.x] + sm[2][threadIdx.x] + sm[3][threadIdx.x];
}

// ---------------- MoE via MFMA ----------------
template <typename TT>
__global__ __launch_bounds__(256) void k_moe_mfma(
    const bf16* __restrict__ tok, const float* __restrict__ dense,
    const bf16* __restrict__ w1f, const float* __restrict__ b1,
    const bf16* __restrict__ w2f, const float* __restrict__ b2,
    TT* __restrict__ tout)
{
    __shared__ __align__(16) bf16 hL[64][200];
    const int rbase = blockIdx.x * 64;
    const int lane = threadIdx.x & 63, w = threadIdx.x >> 6;
    const int m0 = w * 16;
    const int kg = lane >> 4;
    const int ln16 = lane & 15;
    const int arow = rbase + m0 + ln16;

    float4v accT[12];
    #pragma unroll
    for (int i = 0; i < 12; ++i) accT[i] = (float4v)0.f;

    for (int e = 0; e < 4; ++e) {
        float g4[4];
        #pragma unroll
        for (int r = 0; r < 4; ++r)
            g4[r] = dense[(size_t)(rbase + m0 + kg * 4 + r) * 4 + e];

        float4v acc[12];
        #pragma unroll
        for (int i = 0; i < 12; ++i) acc[i] = (float4v)0.f;
        for (int kc = 0; kc < 6; ++kc) {
            short8 a = *(const short8*)(const void*)(tok + (size_t)arow * 192 + kc * 32 + kg * 8);
            const bf16* wb = w1f + (size_t)e * 36864 + (kc * 12) * 512 + lane * 8;
            #pragma unroll
            for (int nt = 0; nt < 12; ++nt) {
                short8 bfrag = *(const short8*)(const void*)(wb + nt * 512);
                acc[nt] = __builtin_amdgcn_mfma_f32_16x16x32_bf16(a, bfrag, acc[nt], 0, 0, 0);
            }
        }
        #pragma unroll
        for (int nt = 0; nt < 12; ++nt) {
            int c = nt * 16 + ln16;
            float bias = b1[e * 192 + c];
            #pragma unroll
            for (int r = 0; r < 4; ++r)
                hL[m0 + kg * 4 + r][c] = f2b(geluf(acc[nt][r] + bias));
        }
        __syncthreads();
        #pragma unroll
        for (int i = 0; i < 12; ++i) acc[i] = (float4v)0.f;
        for (int kc = 0; kc < 6; ++kc) {
            short8 a = *(const short8*)(const void*)(&hL[m0 + ln16][kc * 32 + kg * 8]);
            const bf16* wb = w2f + (size_t)e * 36864 + (kc * 12) * 512 + lane * 8;
            #pragma unroll
            for (int nt = 0; nt < 12; ++nt) {
                short8 bfrag = *(const short8*)(const void*)(wb + nt * 512);
                acc[nt] = __builtin_amdgcn_mfma_f32_16x16x32_bf16(a, bfrag, acc[nt], 0, 0, 0);
            }
        }
        #pragma unroll
        for (int nt = 0; nt < 12; ++nt) {
            int c = nt * 16 + ln16;
            float bias = b2[e * 192 + c];
            #pragma unroll
            for (int r = 0; r < 4; ++r)
                accT[nt][r] += g4[r] * (acc[nt][r] + bias);
        }
        __syncthreads();
    }
    #pragma unroll
    for (int nt = 0; nt < 12; ++nt) {
        int c = nt * 16 + ln16;
        #pragma unroll
        for (int r = 0; r < 4; ++r)
            stv(&tout[(size_t)(rbase + m0 + kg * 4 + r) * 192 + c], accT[nt][r]);
    }
}

// ---------------- proj via MFMA ----------------
template <typename TT>
__global__ __launch_bounds__(256) void k_proj_mfma(
    const bf16* __restrict__ y2, const bf16* __restrict__ pwf,
    const float* __restrict__ pb, TT* __restrict__ t)
{
    const int rbase = blockIdx.x * 64;
    const int lane = threadIdx.x & 63, w = threadIdx.x >> 6;
    const int m0 = w * 16;
    const int kg = lane >> 4, ln16 = lane & 15;
    const int arow = rbase + m0 + ln16;
    float4v acc[12];
    #pragma unroll
    for (int i = 0; i < 12; ++i) acc[i] = (float4v)0.f;
    for (int kc = 0; kc < 6; ++kc) {
        short8 a = *(const short8*)(const void*)(y2 + (size_t)arow * 192 + kc * 32 + kg * 8);
        const bf16* wb = pwf + (kc * 12) * 512 + lane * 8;
        #pragma unroll
        for (int nt = 0; nt < 12; ++nt) {
            short8 bfrag = *(const short8*)(const void*)(wb + nt * 512);
            acc[nt] = __builtin_amdgcn_mfma_f32_16x16x32_bf16(a, bfrag, acc[nt], 0, 0, 0);
        }
    }
    #pragma unroll
    for (int nt = 0; nt < 12; ++nt) {
        int c = nt * 16 + ln16;
        float bias = pb[c];
        #pragma unroll
        for (int r = 0; r < 4; ++r) {
            TT* p = &t[(size_t)(rbase + m0 + kg * 4 + r) * 192 + c];
            stv(p, ldv(p) + acc[nt][r] + bias);
        }
    }
}

// ---------------- fused LN2 + MLP via MFMA ----------------
template <typename TT>
__global__ __launch_bounds__(256) void k_mlp_mfma(
    TT* __restrict__ t, const float* __restrict__ lg, const float* __restrict__ lb,
    const bf16* __restrict__ w1f, const float* __restrict__ b1,
    const bf16* __restrict__ w2f, const float* __restrict__ b2)
{
    __shared__ __align__(16) bf16 yL[64][200];
    __shared__ __align__(16) bf16 hL[64][200];
    const int rbase = blockIdx.x * 64;
    const int tid = threadIdx.x;
    {
        const int row = tid >> 2, qg = tid & 3;
        float v[48];
        const TT* tr_ = t + (size_t)(rbase + row) * 192 + qg * 48;
        float s = 0.f, sq = 0.f;
        #pragma unroll
        for (int i = 0; i < 12; ++i) {
            float tmp[4]; ld4(tr_ + i * 4, tmp);
            #pragma unroll
            for (int j = 0; j < 4; ++j) { v[i*4+j] = tmp[j]; s += tmp[j]; sq += tmp[j]*tmp[j]; }
        }
        s  += __shfl_xor(s, 1);  s  += __shfl_xor(s, 2);
        sq += __shfl_xor(sq, 1); sq += __shfl_xor(sq, 2);
        float m = s * (1.f/192.f), var = sq * (1.f/192.f) - m*m;
        float rs = rsqrtf(var + 1e-5f);
        #pragma unroll
        for (int i = 0; i < 48; ++i) {
            int d = qg * 48 + i;
            yL[row][d] = f2b((v[i] - m) * rs * lg[d] + lb[d]);
        }
    }
    __syncthreads();
    const int lane = tid & 63, w = tid >> 6;
    const int m0 = w * 16;
    const int kg = lane >> 4, ln16 = lane & 15;
    float4v accT[12];
    #pragma unroll
    for (int i = 0; i < 12; ++i) accT[i] = (float4v)0.f;
    for (int ch = 0; ch < 2; ++ch) {
        float4v acc[12];
        #pragma unroll
        for (int i = 0; i < 12; ++i) acc[i] = (float4v)0.f;
        for (int kc = 0; kc < 6; ++kc) {
            short8 a = *(const short8*)(const void*)(&yL[m0 + ln16][kc * 32 + kg * 8]);
            const bf16* wb = w1f + (size_t)(kc * 24 + ch * 12) * 512 + lane * 8;
            #pragma unroll
            for (int nt = 0; nt < 12; ++nt) {
                short8 bfrag = *(const short8*)(const void*)(wb + nt * 512);
                acc[nt] = __builtin_amdgcn_mfma_f32_16x16x32_bf16(a, bfrag, acc[nt], 0, 0, 0);
            }
        }
        #pragma unroll
        for (int nt = 0; nt < 12; ++nt) {
            int c = nt * 16 + ln16;
            float bias = b1[ch * 192 + c];
            #pragma unroll
            for (int r = 0; r < 4; ++r)
                hL[m0 + kg * 4 + r][c] = f2b(geluf(acc[nt][r] + bias));
        }
        __syncthreads();
        for (int kc = 0; kc < 6; ++kc) {
            short8 a = *(const short8*)(const void*)(&hL[m0 + ln16][kc * 32 + kg * 8]);
            const bf16* wb = w2f + (size_t)((ch * 6 + kc) * 12) * 512 + lane * 8;
            #pragma unroll
            for (int nt = 0; nt < 12; ++nt) {
                short8 bfrag = *(const short8*)(const void*)(wb + nt * 512);
                accT[nt] = __builtin_amdgcn_mfma_f32_16x16x32_bf16(a, bfrag, accT[nt], 0, 0, 0);
            }
        }
        __syncthreads();
    }
    #pragma unroll
    for (int nt = 0; nt < 12; ++nt) {
        int c = nt * 16 + ln16;
        float bias = b2[c];
        #pragma unroll
        for (int r = 0; r < 4; ++r) {
            TT* p = &t[(size_t)(rbase + m0 + kg * 4 + r) * 192 + c];
            stv(p, ldv(p) + accT[nt][r] + bias);
        }
    }
}

// ---------------- fused LN1 + QKV + attention, all-MFMA, one block per sequence ----------------
template <typename TT>
__global__ __launch_bounds__(256) void k_attn_mfma(
    const TT* __restrict__ t, const float* __restrict__ lg, const float* __restrict__ lb,
    const bf16* __restrict__ qkvwf, const float* __restrict__ qkvb, bf16* __restrict__ y2)
{
    __shared__ __align__(16) char smem[131072];
    bf16* qkL = (bf16*)smem;                    // 64*520*2 = 66560 B
    bf16* vT  = (bf16*)(smem + 66560);          // 4*48*72*2 = 27648 B
    bf16* pL  = (bf16*)(smem + 94208);          // 4*64*72*2 = 36864 B
    const int n = blockIdx.x;
    const int tid = threadIdx.x;
    const int w = tid >> 6, lane = tid & 63;
    const int kg = lane >> 4, ln16 = lane & 15;
    const int row = w * 16 + ln16;

    for (int idx = tid; idx < 1024; idx += 256) {
        int s = idx >> 7, rem = idx & 127;
        int r = rem >> 1, half = rem & 1;
        *(short8*)(void*)(qkL + r * 520 + s * 64 + 48 + half * 8) = (short8){0,0,0,0,0,0,0,0};
    }

    // LN in registers, producing A-fragments directly
    short8 afr[6];
    {
        float v[48];
        float s = 0.f, sq = 0.f;
        const TT* tp = t + (size_t)n * 12288 + row * 192 + kg * 8;
        #pragma unroll
        for (int c = 0; c < 6; ++c) {
            float tmp[8]; ld8(tp + c * 32, tmp);
            #pragma unroll
            for (int j = 0; j < 8; ++j) { v[c*8+j] = tmp[j]; s += tmp[j]; sq += tmp[j]*tmp[j]; }
        }
        s  += __shfl_xor(s, 16);  s  += __shfl_xor(s, 32);
        sq += __shfl_xor(sq, 16); sq += __shfl_xor(sq, 32);
        float m = s * (1.f/192.f), var = sq * (1.f/192.f) - m * m;
        float rs = rsqrtf(var + 1e-5f);
        #pragma unroll
        for (int c = 0; c < 6; ++c) {
            float g8[8], b8[8];
            ld8(lg + kg * 8 + c * 32, g8);
            ld8(lb + kg * 8 + c * 32, b8);
            bf16 pk[8];
            #pragma unroll
            for (int j = 0; j < 8; ++j)
                pk[j] = f2b((v[c*8+j] - m) * rs * g8[j] + b8[j]);
            afr[c] = *(const short8*)(const void*)pk;
        }
    }

    const float qscale = 0.14433756729740644f;  // 1/sqrt(48)
    for (int nt = 0; nt < 36; ++nt) {
        float4v acc = (float4v)0.f;
        const bf16* wb = qkvwf + nt * 512 + lane * 8;
        #pragma unroll
        for (int kc = 0; kc < 6; ++kc) {
            short8 bfrag = *(const short8*)(const void*)(wb + kc * 36 * 512);
            acc = __builtin_amdgcn_mfma_f32_16x16x32_bf16(afr[kc], bfrag, acc, 0, 0, 0);
        }
        const int which = nt / 12, h = (nt % 12) / 3, dt = nt % 3;
        const int d = dt * 16 + ln16;
        const float bias = qkvb[nt * 16 + ln16];
        if (which == 0) {
            #pragma unroll
            for (int r = 0; r < 4; ++r)
                qkL[(w * 16 + kg * 4 + r) * 520 + h * 64 + d] = f2b((acc[r] + bias) * qscale);
        } else if (which == 1) {
            #pragma unroll
            for (int r = 0; r < 4; ++r)
                qkL[(w * 16 + kg * 4 + r) * 520 + 256 + h * 64 + d] = f2b(acc[r] + bias);
        } else {
            #pragma unroll
            for (int r = 0; r < 4; ++r)
                vT[h * 3456 + d * 72 + (w * 16 + kg * 4 + r)] = f2b(acc[r] + bias);
        }
    }
    __syncthreads();

    const bf16* Qb = qkL + w * 64;
    const bf16* Kb = qkL + 256 + w * 64;
    float4v sacc[4][4];
    #pragma unroll
    for (int mt = 0; mt < 4; ++mt)
        #pragma unroll
        for (int nt = 0; nt < 4; ++nt) sacc[mt][nt] = (float4v)0.f;
    #pragma unroll
    for (int kc = 0; kc < 2; ++kc) {
        short8 aq[4], bk[4];
        #pragma unroll
        for (int mt = 0; mt < 4; ++mt)
            aq[mt] = *(const short8*)(const void*)(Qb + (mt * 16 + ln16) * 520 + kc * 32 + kg * 8);
        #pragma unroll
        for (int nt = 0; nt < 4; ++nt)
            bk[nt] = *(const short8*)(const void*)(Kb + (nt * 16 + ln16) * 520 + kc * 32 + kg * 8);
        #pragma unroll
        for (int mt = 0; mt < 4; ++mt)
            #pragma unroll
            for (int nt = 0; nt < 4; ++nt)
                sacc[mt][nt] = __builtin_amdgcn_mfma_f32_16x16x32_bf16(aq[mt], bk[nt], sacc[mt][nt], 0, 0, 0);
    }
    #pragma unroll
    for (int mt = 0; mt < 4; ++mt) {
        #pragma unroll
        for (int r = 0; r < 4; ++r) {
            float mx = sacc[mt][0][r];
            #pragma unroll
            for (int nt = 1; nt < 4; ++nt) mx = fmaxf(mx, sacc[mt][nt][r]);
            mx = fmaxf(mx, __shfl_xor(mx, 1)); mx = fmaxf(mx, __shfl_xor(mx, 2));
            mx = fmaxf(mx, __shfl_xor(mx, 4)); mx = fmaxf(mx, __shfl_xor(mx, 8));
            float e[4], sum = 0.f;
            #pragma unroll
            for (int nt = 0; nt < 4; ++nt) { e[nt] = expf(sacc[mt][nt][r] - mx); sum += e[nt]; }
            sum += __shfl_xor(sum, 1); sum += __shfl_xor(sum, 2);
            sum += __shfl_xor(sum, 4); sum += __shfl_xor(sum, 8);
            float inv = 1.f / sum;
            #pragma unroll
            for (int nt = 0; nt < 4; ++nt)
                pL[w * 4608 + (mt * 16 + kg * 4 + r) * 72 + nt * 16 + ln16] = f2b(e[nt] * inv);
        }
    }
    float4v oacc[4][3];
    #pragma unroll
    for (int mt = 0; mt < 4; ++mt)
        #pragma unroll
        for (int nt = 0; nt < 3; ++nt) oacc[mt][nt] = (float4v)0.f;
    #pragma unroll
    for (int kc = 0; kc < 2; ++kc) {
        short8 ap[4], bv[3];
        #pragma unroll
        for (int mt = 0; mt < 4; ++mt)
            ap[mt] = *(const short8*)(const void*)(pL + w * 4608 + (mt * 16 + ln16) * 72 + kc * 32 + kg * 8);
        #pragma unroll
        for (int nt = 0; nt < 3; ++nt)
            bv[nt] = *(const short8*)(const void*)(vT + w * 3456 + (nt * 16 + ln16) * 72 + kc * 32 + kg * 8);
        #pragma unroll
        for (int mt = 0; mt < 4; ++mt)
            #pragma unroll
            for (int nt = 0; nt < 3; ++nt)
                oacc[mt][nt] = __builtin_amdgcn_mfma_f32_16x16x32_bf16(ap[mt], bv[nt], oacc[mt][nt], 0, 0, 0);
    }
    #pragma unroll
    for (int mt = 0; mt < 4; ++mt)
        #pragma unroll
        for (int nt = 0; nt < 3; ++nt)
            #pragma unroll
            for (int r = 0; r < 4; ++r)
                y2[((size_t)n * 64 + mt * 16 + kg * 4 + r) * 192 + w * 48 + nt * 16 + ln16] =
                    f2b(oacc[mt][nt][r]);
}

// ---------------- fused final LN + unpatchify + 1x1 (192->128) + BN + SiLU via MFMA ----------------
// grid 2048 (one (b,pa) token block; np = 0..63), block 256
template <typename TT>
__global__ __launch_bounds__(256) void k_unpatch_mfma(
    const TT* __restrict__ t, const float* __restrict__ ng, const float* __restrict__ nb,
    const bf16* __restrict__ wpf, const float* __restrict__ gamma, const float* __restrict__ beta,
    bf16* __restrict__ ph)
{
    __shared__ __align__(16) bf16 outL[64][136];
    const int blk = blockIdx.x;          // = b*64 + pa
    const int b = blk >> 6, pa = blk & 63;
    const int tid = threadIdx.x;
    const int w = tid >> 6, lane = tid & 63;
    const int kg = lane >> 4, ln16 = lane & 15;
    const int row = w * 16 + ln16;       // np index

    // LN in registers, producing A-fragments directly
    short8 afr[6];
    {
        float v[48];
        float s = 0.f, sq = 0.f;
        const TT* tp = t + ((size_t)blk * 64 + row) * 192 + kg * 8;
        #pragma unroll
        for (int c = 0; c < 6; ++c) {
            float tmp[8]; ld8(tp + c * 32, tmp);
            #pragma unroll
            for (int j = 0; j < 8; ++j) { v[c*8+j] = tmp[j]; s += tmp[j]; sq += tmp[j]*tmp[j]; }
        }
        s  += __shfl_xor(s, 16);  s  += __shfl_xor(s, 32);
        sq += __shfl_xor(sq, 16); sq += __shfl_xor(sq, 32);
        float m = s * (1.f/192.f), var = sq * (1.f/192.f) - m * m;
        float rs = rsqrtf(var + 1e-5f);
        #pragma unroll
        for (int c = 0; c < 6; ++c) {
            float g8[8], b8[8];
            ld8(ng + kg * 8 + c * 32, g8);
            ld8(nb + kg * 8 + c * 32, b8);
            bf16 pk[8];
            #pragma unroll
            for (int j = 0; j < 8; ++j)
                pk[j] = f2b((v[c*8+j] - m) * rs * g8[j] + b8[j]);
            afr[c] = *(const short8*)(const void*)pk;
        }
    }

    // GEMM K=192 -> N=128 (wave w owns rows w*16..w*16+15)
    float4v acc[8];
    #pragma unroll
    for (int i = 0; i < 8; ++i) acc[i] = (float4v)0.f;
    #pragma unroll
    for (int kc = 0; kc < 6; ++kc) {
        const bf16* wb = wpf + (kc * 8) * 512 + lane * 8;
        #pragma unroll
        for (int nt = 0; nt < 8; ++nt) {
            short8 bfrag = *(const short8*)(const void*)(wb + nt * 512);
            acc[nt] = __builtin_amdgcn_mfma_f32_16x16x32_bf16(afr[kc], bfrag, acc[nt], 0, 0, 0);
        }
    }
    #pragma unroll
    for (int nt = 0; nt < 8; ++nt) {
        int c = nt * 16 + ln16;
        float g = gamma[c], be = beta[c];
        #pragma unroll
        for (int r = 0; r < 4; ++r)
            outL[w * 16 + kg * 4 + r][c] = f2b(siluf(g * acc[nt][r] + be));
    }
    __syncthreads();
    // scatter: token np -> pixel (y,x) = (pi*8 + pa>>3, pj*8 + (pa&7)), np = pi*8+pj
    for (int idx = tid; idx < 1024; idx += 256) {
        int np = idx >> 4, q = idx & 15;
        int yy = (np >> 3) * 8 + (pa >> 3), xx = (np & 7) * 8 + (pa & 7);
        *(short8*)(void*)(ph + ((size_t)(b * 64 + yy) * 64 + xx) * 128 + q * 8) =
            *(const short8*)(const void*)(&outL[np][q * 8]);
    }
}

// ---------------- moe loss ----------------
__global__ void k_loss(const float* __restrict__ part, float* __restrict__ out)
{
    if (threadIdx.x == 0 && blockIdx.x == 0) {
        float L = 0.f;
        for (int e = 0; e < 4; ++e) {
            float imp = 0.f, ld = 0.f;
            for (int i = 0; i < 512; ++i) { imp += part[i * 8 + e]; ld += part[i * 8 + 4 + e]; }
            L += (imp / 131072.f) * (ld / 131072.f);
        }
        out[16777216] = 4.f * L;
    }
}

template <typename TT>
static void run_pipeline(const float* x, const float* w_kxk, const float* bn1_g, const float* bn1_b,
                         const float* w_1x1, const float* gate_w,
                         const float* moe_w1, const float* moe_b1, const float* moe_w2, const float* moe_b2,
                         const float* ln1_g, const float* ln1_b, const float* qkv_w, const float* qkv_b,
                         const float* proj_w, const float* proj_b, const float* ln2_g, const float* ln2_b,
                         const float* fc1_w, const float* fc1_b, const float* fc2_w, const float* fc2_b,
                         const float* nrm_g, const float* nrm_b, const float* w_proj, const float* bn2_g,
                         const float* bn2_b, const float* w_fus, const float* bn3_g, const float* bn3_b,
                         const int* task, float* out, bf16* xh, bf16* tok, TT* t, float* dense, float* part,
                         bf16* wprep, hipStream_t stream)
{
    // prep fragments
    bf16* moeW1f = wprep;                 // 147456
    bf16* moeW2f = wprep + 147456;        // 147456
    bf16* fc1f   = wprep + 294912;        // 147456
    bf16* fc2f   = wprep + 442368;        // 147456
    bf16* projWf = wprep + 589824;        // 73728
    bf16* w1x1f  = wprep + 663552;        // 24576
    bf16* convW1f= wprep + 688128;        // 147456
    bf16* convWFf= wprep + 835584;        // 294912
    bf16* qkvWf  = wprep + 1130496;       // 221184
    bf16* wpjf   = wprep + 1351680;       // 24576 -> total 1376256 elems
    hipLaunchKernelGGL(k_prep, dim3(576), dim3(256), 0, stream, moe_w1, moeW1f, 192, 192, 4);
    hipLaunchKernelGGL(k_prep, dim3(576), dim3(256), 0, stream, moe_w2, moeW2f, 192, 192, 4);
    hipLaunchKernelGGL(k_prep, dim3(576), dim3(256), 0, stream, fc1_w, fc1f, 192, 384, 2);
    hipLaunchKernelGGL(k_prep, dim3(576), dim3(256), 0, stream, fc2_w, fc2f, 384, 192, 2);
    hipLaunchKernelGGL(k_prep, dim3(288), dim3(256), 0, stream, proj_w, projWf, 192, 192, 2);
    hipLaunchKernelGGL(k_prep_t, dim3(96), dim3(256), 0, stream, w_1x1, w1x1f, 192, 128);
    hipLaunchKernelGGL(k_prep_conv, dim3(576), dim3(256), 0, stream, w_kxk, convW1f, 128, 128);
    hipLaunchKernelGGL(k_prep_conv, dim3(1152), dim3(256), 0, stream, w_fus, convWFf, 256, 128);
    hipLaunchKernelGGL(k_prep, dim3(864), dim3(256), 0, stream, qkv_w, qkvWf, 192, 576, 2);
    hipLaunchKernelGGL(k_prep_t, dim3(96), dim3(256), 0, stream, w_proj, wpjf, 128, 192);

    bf16* h1h = (bf16*)out;  // d_out used as NHWC bf16 scratch; fully rewritten by final conv
    hipLaunchKernelGGL(k_tohwc, dim3(2048), dim3(256), 0, stream, x, xh);
    hipLaunchKernelGGL(k_conv1_mfma, dim3(2048), dim3(256), 0, stream, xh, convW1f, bn1_g, bn1_b, h1h);
    hipLaunchKernelGGL(k_patch1x1_mfma, dim3(2048), dim3(256), 0, stream, h1h, w1x1f, tok);
    hipLaunchKernelGGL(k_gate, dim3(512), dim3(256), 0, stream, tok, gate_w, task, dense, part);
    hipLaunchKernelGGL(k_moe_mfma<TT>, dim3(2048), dim3(256), 0, stream,
                       tok, dense, moeW1f, moe_b1, moeW2f, moe_b2, t);
    bf16* y2 = tok;  // tok dead after MoE
    for (int l = 0; l < 2; ++l) {
        hipLaunchKernelGGL(k_attn_mfma<TT>, dim3(2048), dim3(256), 0, stream,
                           t, ln1_g + l * 192, ln1_b + l * 192,
                           qkvWf + (size_t)l * 110592, qkv_b + l * 576, y2);
        hipLaunchKernelGGL(k_proj_mfma<TT>, dim3(2048), dim3(256), 0, stream,
                           y2, projWf + (size_t)l * 36864, proj_b + l * 192, t);
        hipLaunchKernelGGL(k_mlp_mfma<TT>, dim3(2048), dim3(256), 0, stream,
                           t, ln2_g + l * 192, ln2_b + l * 192,
                           fc1f + (size_t)l * 73728, fc1_b + l * 384,
                           fc2f + (size_t)l * 73728, fc2_b + l * 192);
    }
    bf16* ph = tok;  // y2 dead after last proj; reuse region as NHWC p
    hipLaunchKernelGGL(k_unpatch_mfma<TT>, dim3(2048), dim3(256), 0, stream,
                       t, nrm_g, nrm_b, wpjf, bn2_g, bn2_b, ph);
    hipLaunchKernelGGL(k_convf_mfma, dim3(2048), dim3(256), 0, stream,
                       xh, ph, convWFf, bn3_g, bn3_b, out);
    hipLaunchKernelGGL(k_loss, dim3(1), dim3(64), 0, stream, part, out);
}

extern "C" void kernel_launch(void* const* d_in, const int* in_sizes, int n_in,
                              void* d_out, int out_size, void* d_ws, size_t ws_size,
                              hipStream_t stream) {
    const float* x      = (const float*)d_in[0];
    const float* w_kxk  = (const float*)d_in[1];
    const float* bn1_g  = (const float*)d_in[2];
    const float* bn1_b  = (const float*)d_in[3];
    const float* w_1x1  = (const float*)d_in[4];
    const float* gate_w = (const float*)d_in[5];
    const float* moe_w1 = (const float*)d_in[6];
    const float* moe_b1 = (const float*)d_in[7];
    const float* moe_w2 = (const float*)d_in[8];
    const float* moe_b2 = (const float*)d_in[9];
    const float* ln1_g  = (const float*)d_in[10];
    const float* ln1_b  = (const float*)d_in[11];
    const float* qkv_w  = (const float*)d_in[12];
    const float* qkv_b  = (const float*)d_in[13];
    const float* proj_w = (const float*)d_in[14];
    const float* proj_b = (const float*)d_in[15];
    const float* ln2_g  = (const float*)d_in[16];
    const float* ln2_b  = (const float*)d_in[17];
    const float* fc1_w  = (const float*)d_in[18];
    const float* fc1_b  = (const float*)d_in[19];
    const float* fc2_w  = (const float*)d_in[20];
    const float* fc2_b  = (const float*)d_in[21];
    const float* nrm_g  = (const float*)d_in[22];
    const float* nrm_b  = (const float*)d_in[23];
    const float* w_proj = (const float*)d_in[24];
    const float* bn2_g  = (const float*)d_in[25];
    const float* bn2_b  = (const float*)d_in[26];
    const float* w_fus  = (const float*)d_in[27];
    const float* bn3_g  = (const float*)d_in[28];
    const float* bn3_b  = (const float*)d_in[29];
    const int*  task    = (const int*)d_in[30];

    char* wsb = (char*)d_ws;
    const size_t XHB   = 33554432ull;    // NHWC bf16 x
    const size_t TOKB  = 50331648ull;    // tok / y2 / ph region
    const size_t T32B  = 100663296ull;
    const size_t T16B  = 50331648ull;
    const size_t DENB  = 2097152ull;
    const size_t PARB  = 16384ull;
    const size_t WPB   = 2752512ull;
    bf16* xh  = (bf16*)wsb;
    bf16* tok = (bf16*)(wsb + XHB);
    float* out = (float*)d_out;

    if (ws_size >= XHB + TOKB + T32B + DENB + PARB + WPB) {
        float* t     = (float*)(wsb + XHB + TOKB);
        float* dense = (float*)(wsb + XHB + TOKB + T32B);
        float* part  = (float*)(wsb + XHB + TOKB + T32B + DENB);
        bf16*  wprep = (bf16*)(wsb + XHB + TOKB + T32B + DENB + PARB);
        run_pipeline<float>(x, w_kxk, bn1_g, bn1_b, w_1x1, gate_w, moe_w1, moe_b1, moe_w2, moe_b2,
                            ln1_g, ln1_b, qkv_w, qkv_b, proj_w, proj_b, ln2_g, ln2_b,
                            fc1_w, fc1_b, fc2_w, fc2_b, nrm_g, nrm_b, w_proj, bn2_g, bn2_b,
                            w_fus, bn3_g, bn3_b, task, out, xh, tok, t, dense, part, wprep, stream);
    } else {
        bf16*  t     = (bf16*)(wsb + XHB + TOKB);
        float* dense = (float*)(wsb + XHB + TOKB + T16B);
        float* part  = (float*)(wsb + XHB + TOKB + T16B + DENB);
        bf16*  wprep = (bf16*)(wsb + XHB + TOKB + T16B + DENB + PARB);
        run_pipeline<bf16>(x, w_kxk, bn1_g, bn1_b, w_1x1, gate_w, moe_w1, moe_b1, moe_w2, moe_b2,
                           ln1_g, ln1_b, qkv_w, qkv_b, proj_w, proj_b, ln2_g, ln2_b,
                           fc1_w, fc1_b, fc2_w, fc2_b, nrm_g, nrm_b, w_proj, bn2_g, bn2_b,
                           w_fus, bn3_g, bn3_b, task, out, xh, tok, t, dense, part, wprep, stream);
    }
}